// Round 11
// baseline (408.560 us; speedup 1.0000x reference)
//
#include <hip/hip_runtime.h>
#include <math.h>

// Sizes: b=4, t=12 (BT=48), n=512, c=64, heads=8, hd=8, FF hidden=256, depth=2
#define LDSP 68   // padded LDS row stride in floats (17 float4s -> odd quad stride, conflict-free)

typedef __fp16 half_t;
typedef __attribute__((ext_vector_type(2))) __fp16 half2v;
typedef __attribute__((ext_vector_type(4))) __fp16 half4v;
typedef __attribute__((ext_vector_type(4))) float f32x4;

// ---------------- init: h[(bt*512+v)*64+c] = x[b,c,v,t] + pos[v,c] ----------------
__global__ __launch_bounds__(256) void k_init(const float* __restrict__ x,
                                              const float* __restrict__ pos,
                                              float* __restrict__ h) {
    int i = blockIdx.x * 256 + threadIdx.x;          // over 1572864 h elements
    int c = i & 63;
    int v = (i >> 6) & 511;
    int bt = i >> 15;
    int b = bt / 12, t = bt - b * 12;
    h[i] = x[(((size_t)(b * 64 + c) * 512) + v) * 12 + t] + pos[v * 64 + c];
}

// ---------------- transpose h -> rbuf[(v*48+bt)*64+c]  (residual snapshot) ----------------
__global__ __launch_bounds__(256) void k_trans(const float* __restrict__ h,
                                               float* __restrict__ rb) {
    int f = blockIdx.x * 256 + threadIdx.x;          // float4 idx over 393216
    int c4 = f & 15;
    int row = f >> 4;                                 // v*48+bt
    int v = row / 48, bt = row - v * 48;
    ((float4*)rb)[f] = ((const float4*)h)[((size_t)(bt * 512 + v)) * 16 + c4];
}

// ---------------- adj -> adjTh[w][v] (f16 transposed), once per launch ----------------
__global__ __launch_bounds__(256) void k_adjt(const float* __restrict__ adj,
                                              half_t* __restrict__ adjTh) {
    __shared__ float t[64 * 65];
    int tid = threadIdx.x;
    int v0 = blockIdx.x * 64, w0 = blockIdx.y * 64;
#pragma unroll
    for (int i = 0; i < 4; ++i) {
        int g = tid + i * 256;
        int r = g >> 4, q = g & 15;                   // r = v-local, 4q = w-local
        float4 a = *(const float4*)(adj + (size_t)(v0 + r) * 512 + w0 + 4 * q);
        t[(4 * q + 0) * 65 + r] = a.x;
        t[(4 * q + 1) * 65 + r] = a.y;
        t[(4 * q + 2) * 65 + r] = a.z;
        t[(4 * q + 3) * 65 + r] = a.w;
    }
    __syncthreads();
    union PU { half2v h2[2]; half4v h4; };
#pragma unroll
    for (int i = 0; i < 4; ++i) {
        int g = tid + i * 256;
        int rw = g >> 4, q = g & 15;                  // rw = w-local, 4q = v-local
        const float* src = &t[rw * 65 + 4 * q];
        PU u;
        u.h2[0] = __builtin_amdgcn_cvt_pkrtz(src[0], src[1]);
        u.h2[1] = __builtin_amdgcn_cvt_pkrtz(src[2], src[3]);
        *(half4v*)(adjTh + (size_t)(w0 + rw) * 512 + v0 + 4 * q) = u.h4;
    }
}

// ---------------- MFMA qkv: block = 16 tokens / 4 waves; wave w does nt = 3w..3w+2 ----------------
// B-frag = h row per-lane; A-frag = qkv_w rows (L2). D[o][token]: lane (lg,lm) holds
// o = nt*16+lg*4+r, token = lm -> consecutive d => float4 store.
__global__ __launch_bounds__(256) void k_qkv(const float* __restrict__ h,
                                             const float* __restrict__ W,
                                             float* __restrict__ qb,
                                             float* __restrict__ kb,
                                             float* __restrict__ vb) {
    int wave = threadIdx.x >> 6;
    int lane = threadIdx.x & 63;
    int lm = lane & 15, lg = lane >> 4;
    int row = blockIdx.x * 16 + lm;                   // grid 1536
    union PU { half2v h2[2]; half4v h4; };

    half4v xf[4];
#pragma unroll
    for (int kc = 0; kc < 4; ++kc) {
        float4 a = *(const float4*)(h + (size_t)row * 64 + kc * 16 + lg * 4);
        PU u;
        u.h2[0] = __builtin_amdgcn_cvt_pkrtz(a.x, a.y);
        u.h2[1] = __builtin_amdgcn_cvt_pkrtz(a.z, a.w);
        xf[kc] = u.h4;
    }

    const f32x4 zc = {0.f, 0.f, 0.f, 0.f};
    int bt = row >> 9, v = row & 511;
#pragma unroll
    for (int j = 0; j < 3; ++j) {
        int nt = wave * 3 + j;
        f32x4 acc = zc;
#pragma unroll
        for (int kc = 0; kc < 4; ++kc) {
            float4 a = *(const float4*)(W + (size_t)(nt * 16 + lm) * 64 + kc * 16 + lg * 4);
            PU u;
            u.h2[0] = __builtin_amdgcn_cvt_pkrtz(a.x, a.y);
            u.h2[1] = __builtin_amdgcn_cvt_pkrtz(a.z, a.w);
            acc = __builtin_amdgcn_mfma_f32_16x16x16f16(u.h4, xf[kc], acc, 0, 0, 0);
        }
        int s = nt >> 2;
        int head = ((nt & 3) << 1) + (lg >> 1);
        int d0 = (lg & 1) * 4;
        float* dst = (s == 0) ? qb : ((s == 1) ? kb : vb);
        *(float4*)(dst + ((size_t)(bt * 8 + head) * 512 + v) * 8 + d0) =
            make_float4(acc[0], acc[1], acc[2], acc[3]);
    }
}

// ---------------- MFMA attention (fixed-max softmax; 512 thr = 8 waves x 2 strips) ----------------
#define KLS 20    // kl row stride, f16 (40 B rows -> b64-aligned reads)
#define QLS 20
#define VTS 516   // vt row stride, f16 (even bank spread, b64-aligned)

__global__ __launch_bounds__(512) void k_attn(const float* __restrict__ qb,
                                              const float* __restrict__ kb,
                                              const float* __restrict__ vb,
                                              float* __restrict__ ob) {
    __shared__ half_t kl[512 * KLS];   // [key][kd0..15], kd 8..15 zero
    __shared__ half_t vt[16 * VTS];    // [d][key], d 8..15 zeroed (unused C rows)
    __shared__ half_t ql[256 * QLS];   // [row][kd0..15], kd 8..15 zero
    int bh = blockIdx.x >> 1;
    int half_ = blockIdx.x & 1;
    int tid = threadIdx.x;
    const float* kbase = kb + (size_t)bh * 4096;
    const float* vbase = vb + (size_t)bh * 4096;
    const float* qbase = qb + (size_t)bh * 4096 + half_ * 2048;

    union PU { half2v h2[2]; half4v h4; };
    const half4v zero4 = {(__fp16)0.f, (__fp16)0.f, (__fp16)0.f, (__fp16)0.f};

    if (tid < 256) {
#pragma unroll
        for (int kk = 0; kk < 2; ++kk) {
            int key = tid * 2 + kk;
            float4 a = *(const float4*)(kbase + key * 8);
            float4 b = *(const float4*)(kbase + key * 8 + 4);
            PU u0, u1;
            u0.h2[0] = __builtin_amdgcn_cvt_pkrtz(a.x, a.y);
            u0.h2[1] = __builtin_amdgcn_cvt_pkrtz(a.z, a.w);
            u1.h2[0] = __builtin_amdgcn_cvt_pkrtz(b.x, b.y);
            u1.h2[1] = __builtin_amdgcn_cvt_pkrtz(b.z, b.w);
            half4v* rowp = (half4v*)&kl[key * KLS];
            rowp[0] = u0.h4;
            rowp[1] = u1.h4;
            rowp[2] = zero4;
            rowp[3] = zero4;
        }
        {
            const float SC = 0.35355339059327373f * 1.4426950408889634f;
            float4 a = *(const float4*)(qbase + tid * 8);
            float4 b = *(const float4*)(qbase + tid * 8 + 4);
            PU u0, u1;
            u0.h2[0] = __builtin_amdgcn_cvt_pkrtz(a.x * SC, a.y * SC);
            u0.h2[1] = __builtin_amdgcn_cvt_pkrtz(a.z * SC, a.w * SC);
            u1.h2[0] = __builtin_amdgcn_cvt_pkrtz(b.x * SC, b.y * SC);
            u1.h2[1] = __builtin_amdgcn_cvt_pkrtz(b.z * SC, b.w * SC);
            half4v* rowp = (half4v*)&ql[tid * QLS];
            rowp[0] = u0.h4;
            rowp[1] = u1.h4;
            rowp[2] = zero4;
            rowp[3] = zero4;
        }
        {
            int k0 = tid * 2;
            float4 a0 = *(const float4*)(vbase + k0 * 8);
            float4 a1 = *(const float4*)(vbase + k0 * 8 + 4);
            float4 b0 = *(const float4*)(vbase + k0 * 8 + 8);
            float4 b1 = *(const float4*)(vbase + k0 * 8 + 12);
            *(half2v*)&vt[0 * VTS + k0] = __builtin_amdgcn_cvt_pkrtz(a0.x, b0.x);
            *(half2v*)&vt[1 * VTS + k0] = __builtin_amdgcn_cvt_pkrtz(a0.y, b0.y);
            *(half2v*)&vt[2 * VTS + k0] = __builtin_amdgcn_cvt_pkrtz(a0.z, b0.z);
            *(half2v*)&vt[3 * VTS + k0] = __builtin_amdgcn_cvt_pkrtz(a0.w, b0.w);
            *(half2v*)&vt[4 * VTS + k0] = __builtin_amdgcn_cvt_pkrtz(a1.x, b1.x);
            *(half2v*)&vt[5 * VTS + k0] = __builtin_amdgcn_cvt_pkrtz(a1.y, b1.y);
            *(half2v*)&vt[6 * VTS + k0] = __builtin_amdgcn_cvt_pkrtz(a1.z, b1.z);
            *(half2v*)&vt[7 * VTS + k0] = __builtin_amdgcn_cvt_pkrtz(a1.w, b1.w);
        }
    }
    for (int i = tid; i < 1032; i += 512)
        ((half4v*)(vt + 8 * VTS))[i] = zero4;
    __syncthreads();

    int wave = tid >> 6, lane = tid & 63;
    int lm = lane & 15, lg = lane >> 4;
    int bt = bh >> 3, head = bh & 7;

#pragma unroll 1
    for (int st = 0; st < 2; ++st) {
        int qrow0 = wave * 32 + st * 16;
        half4v qf = *(const half4v*)&ql[(qrow0 + lm) * QLS + lg * 4];
        f32x4 acc = {0.f, 0.f, 0.f, 0.f};
        float l0 = 0.f, l1 = 0.f, l2 = 0.f, l3 = 0.f;
        f32x4 zc = {0.f, 0.f, 0.f, 0.f};
#pragma unroll 4
        for (int kt = 0; kt < 32; ++kt) {
            int key0 = kt * 16;
            half4v ka = *(const half4v*)&kl[(key0 + lm) * KLS + lg * 4];
            f32x4 c1 = __builtin_amdgcn_mfma_f32_16x16x16f16(ka, qf, zc, 0, 0, 0);
            float p0 = exp2f(fminf(c1[0], 12.f));
            float p1 = exp2f(fminf(c1[1], 12.f));
            float p2 = exp2f(fminf(c1[2], 12.f));
            float p3 = exp2f(fminf(c1[3], 12.f));
            l0 += p0; l1 += p1; l2 += p2; l3 += p3;
            PU pu;
            pu.h2[0] = __builtin_amdgcn_cvt_pkrtz(p0, p1);
            pu.h2[1] = __builtin_amdgcn_cvt_pkrtz(p2, p3);
            half4v va = *(const half4v*)&vt[lm * VTS + key0 + lg * 4];
            acc = __builtin_amdgcn_mfma_f32_16x16x16f16(va, pu.h4, acc, 0, 0, 0);
        }
        float lsum = (l0 + l1) + (l2 + l3);
        lsum += __shfl_xor(lsum, 16);
        lsum += __shfl_xor(lsum, 32);
        if (lg < 2) {
            float inv = 1.f / lsum;
            int rowg = half_ * 256 + qrow0 + lm;
            float* op = ob + ((size_t)(bt * 512 + rowg)) * 64 + head * 8 + lg * 4;
            *(float4*)op = make_float4(acc[0] * inv, acc[1] * inv, acc[2] * inv, acc[3] * inv);
        }
    }
}

// ---------------- fused proj + LayerNorm + FF (MFMA), ht-split across 4 waves ----------------
// Block = 16 tokens / 256 thr. All waves redundantly compute proj+LN (mfma pipe idle anyway);
// wave w runs ht = 4w..4w+3; partial FF2 acc reduced via LDS (stride 20 -> conflict-free).
__global__ __launch_bounds__(256) void k_plf(const float* __restrict__ ob,
                                             const float* __restrict__ pw,
                                             const float* __restrict__ pb,
                                             const float* __restrict__ g,
                                             const float* __restrict__ bln,
                                             const float* __restrict__ w1,
                                             const float* __restrict__ b1,
                                             const float* __restrict__ w2,
                                             const float* __restrict__ b2,
                                             float* __restrict__ h) {
    __shared__ float red[3 * 64 * 20];                // 15 KB
    int wave = threadIdx.x >> 6;
    int lane = threadIdx.x & 63;
    int lm = lane & 15, lg = lane >> 4;
    int row = blockIdx.x * 16 + lm;                   // grid 1536
    union PU { half2v h2[2]; half4v h4; };
    const f32x4 zc = {0.f, 0.f, 0.f, 0.f};

    // ---- attention-output B-frags ----
    half4v of[4];
#pragma unroll
    for (int kc = 0; kc < 4; ++kc) {
        float4 a = *(const float4*)(ob + (size_t)row * 64 + kc * 16 + lg * 4);
        PU u;
        u.h2[0] = __builtin_amdgcn_cvt_pkrtz(a.x, a.y);
        u.h2[1] = __builtin_amdgcn_cvt_pkrtz(a.z, a.w);
        of[kc] = u.h4;
    }

    // ---- proj + residual: h1[nt] = h_old + projD + pb  (redundant across waves) ----
    f32x4 hp[4];
#pragma unroll
    for (int nt = 0; nt < 4; ++nt) {
        f32x4 c = zc;
#pragma unroll
        for (int kc = 0; kc < 4; ++kc) {
            float4 a = *(const float4*)(pw + (size_t)(nt * 16 + lm) * 64 + kc * 16 + lg * 4);
            PU u;
            u.h2[0] = __builtin_amdgcn_cvt_pkrtz(a.x, a.y);
            u.h2[1] = __builtin_amdgcn_cvt_pkrtz(a.z, a.w);
            c = __builtin_amdgcn_mfma_f32_16x16x16f16(u.h4, of[kc], c, 0, 0, 0);
        }
        float4 ho = *(const float4*)(h + (size_t)row * 64 + nt * 16 + lg * 4);
        float4 bb = *(const float4*)(pb + nt * 16 + lg * 4);
        hp[nt][0] = c[0] + ho.x + bb.x;
        hp[nt][1] = c[1] + ho.y + bb.y;
        hp[nt][2] = c[2] + ho.z + bb.z;
        hp[nt][3] = c[3] + ho.w + bb.w;
    }

    // ---- LayerNorm over the token ----
    float s = 0.f, s2 = 0.f;
#pragma unroll
    for (int nt = 0; nt < 4; ++nt)
#pragma unroll
        for (int r = 0; r < 4; ++r) {
            s += hp[nt][r];
            s2 += hp[nt][r] * hp[nt][r];
        }
    s += __shfl_xor(s, 16);  s2 += __shfl_xor(s2, 16);
    s += __shfl_xor(s, 32);  s2 += __shfl_xor(s2, 32);
    float mean = s * (1.f / 64.f);
    float var = s2 * (1.f / 64.f) - mean * mean;
    float rstd = rsqrtf(var + 1e-5f);

    half4v xf[4];
#pragma unroll
    for (int nt = 0; nt < 4; ++nt) {
        float4 gg = *(const float4*)(g + nt * 16 + lg * 4);
        float4 bb = *(const float4*)(bln + nt * 16 + lg * 4);
        float y0 = (hp[nt][0] - mean) * rstd * gg.x + bb.x;
        float y1 = (hp[nt][1] - mean) * rstd * gg.y + bb.y;
        float y2 = (hp[nt][2] - mean) * rstd * gg.z + bb.z;
        float y3 = (hp[nt][3] - mean) * rstd * gg.w + bb.w;
        PU u;
        u.h2[0] = __builtin_amdgcn_cvt_pkrtz(y0, y1);
        u.h2[1] = __builtin_amdgcn_cvt_pkrtz(y2, y3);
        xf[nt] = u.h4;
    }

    // ---- FF over this wave's 4 ht tiles ----
    f32x4 acc[4] = {zc, zc, zc, zc};
#pragma unroll
    for (int hh = 0; hh < 4; ++hh) {
        int ht = wave * 4 + hh;
        f32x4 c1 = zc;
#pragma unroll
        for (int kc = 0; kc < 4; ++kc) {
            float4 a = *(const float4*)(w1 + (size_t)(ht * 16 + lm) * 64 + kc * 16 + lg * 4);
            PU u;
            u.h2[0] = __builtin_amdgcn_cvt_pkrtz(a.x, a.y);
            u.h2[1] = __builtin_amdgcn_cvt_pkrtz(a.z, a.w);
            c1 = __builtin_amdgcn_mfma_f32_16x16x16f16(u.h4, xf[kc], c1, 0, 0, 0);
        }
        float4 bb = *(const float4*)(b1 + ht * 16 + lg * 4);
        float y0 = c1[0] + bb.x;
        float y1 = c1[1] + bb.y;
        float y2 = c1[2] + bb.z;
        float y3 = c1[3] + bb.w;
        y0 = 0.5f * y0 * (1.0f + erff(y0 * 0.70710678118654752f));
        y1 = 0.5f * y1 * (1.0f + erff(y1 * 0.70710678118654752f));
        y2 = 0.5f * y2 * (1.0f + erff(y2 * 0.70710678118654752f));
        y3 = 0.5f * y3 * (1.0f + erff(y3 * 0.70710678118654752f));
        PU p;
        p.h2[0] = __builtin_amdgcn_cvt_pkrtz(y0, y1);
        p.h2[1] = __builtin_amdgcn_cvt_pkrtz(y2, y3);
#pragma unroll
        for (int ot = 0; ot < 4; ++ot) {
            float4 a = *(const float4*)(w2 + (size_t)(ot * 16 + lm) * 256 + ht * 16 + lg * 4);
            PU u;
            u.h2[0] = __builtin_amdgcn_cvt_pkrtz(a.x, a.y);
            u.h2[1] = __builtin_amdgcn_cvt_pkrtz(a.z, a.w);
            acc[ot] = __builtin_amdgcn_mfma_f32_16x16x16f16(u.h4, p.h4, acc[ot], 0, 0, 0);
        }
    }

    // ---- cross-wave reduction of acc, wave 0 writes h ----
    if (wave != 0) {
        float* dst = &red[((wave - 1) * 64 + lane) * 20];
#pragma unroll
        for (int ot = 0; ot < 4; ++ot)
            *(float4*)(dst + ot * 4) = make_float4(acc[ot][0], acc[ot][1], acc[ot][2], acc[ot][3]);
    }
    __syncthreads();
    if (wave == 0) {
#pragma unroll
        for (int w = 0; w < 3; ++w) {
            const float* src = &red[(w * 64 + lane) * 20];
#pragma unroll
            for (int ot = 0; ot < 4; ++ot) {
                float4 r = *(const float4*)(src + ot * 4);
                acc[ot][0] += r.x; acc[ot][1] += r.y; acc[ot][2] += r.z; acc[ot][3] += r.w;
            }
        }
#pragma unroll
        for (int ot = 0; ot < 4; ++ot) {
            float4 bb = *(const float4*)(b2 + ot * 16 + lg * 4);
            *(float4*)(h + (size_t)row * 64 + ot * 16 + lg * 4) =
                make_float4(hp[ot][0] + acc[ot][0] + bb.x,
                            hp[ot][1] + acc[ot][1] + bb.y,
                            hp[ot][2] + acc[ot][2] + bb.z,
                            hp[ot][3] + acc[ot][3] + bb.w);
        }
    }
}

// ---------------- MFMA diffusion: out[w][p] = sum_v adjTh[w][v]*in[v][p] ----------------
#define ATS 72    // a_t stride halves: 144B rows (16B-aligned staging; 2-way read alias = free)
#define BTS 68    // b_t stride halves: conflict-free b64 frag reads

__global__ __launch_bounds__(256) void k_diff(const half_t* __restrict__ adjTh,
                                              const float* __restrict__ in,
                                              float* __restrict__ outb) {
    __shared__ half_t a_t[64 * ATS];   // [w-local][v-local]
    __shared__ half_t b_t[64 * BTS];   // [p-local][v-local]
    int tid = threadIdx.x;
    int wave = tid >> 6, lane = tid & 63;
    int lm = lane & 15, lg = lane >> 4;
    int w0 = blockIdx.x * 64, p0 = blockIdx.y * 64;
    const f32x4 zc = {0.f, 0.f, 0.f, 0.f};
    f32x4 acc[4] = {zc, zc, zc, zc};

    for (int kc = 0; kc < 8; ++kc) {
#pragma unroll
        for (int i = 0; i < 2; ++i) {
            int g = tid + i * 256;
            int r = g >> 3, s = g & 7;
            *(float4*)&a_t[r * ATS + s * 8] =
                *(const float4*)(adjTh + (size_t)(w0 + r) * 512 + kc * 64 + s * 8);
        }
#pragma unroll
        for (int i = 0; i < 4; ++i) {
            int g = tid + i * 256;
            int vr = g >> 4, q = g & 15;
            float4 a = *(const float4*)(in + (size_t)(kc * 64 + vr) * 3072 + p0 + 4 * q);
            b_t[(4 * q + 0) * BTS + vr] = (half_t)a.x;
            b_t[(4 * q + 1) * BTS + vr] = (half_t)a.y;
            b_t[(4 * q + 2) * BTS + vr] = (half_t)a.z;
            b_t[(4 * q + 3) * BTS + vr] = (half_t)a.w;
        }
        __syncthreads();
#pragma unroll
        for (int k16 = 0; k16 < 4; ++k16) {
            half4v af = *(const half4v*)&a_t[(wave * 16 + lm) * ATS + k16 * 16 + lg * 4];
#pragma unroll
            for (int nt = 0; nt < 4; ++nt) {
                half4v bf = *(const half4v*)&b_t[(nt * 16 + lm) * BTS + k16 * 16 + lg * 4];
                acc[nt] = __builtin_amdgcn_mfma_f32_16x16x16f16(af, bf, acc[nt], 0, 0, 0);
            }
        }
        __syncthreads();
    }
#pragma unroll
    for (int nt = 0; nt < 4; ++nt)
#pragma unroll
        for (int r = 0; r < 4; ++r)
            outb[(size_t)(w0 + wave * 16 + lg * 4 + r) * 3072 + p0 + nt * 16 + lm] = acc[nt][r];
}

// ---------------- MFMA gcn ----------------
__global__ __launch_bounds__(256) void k_gcn(const float* __restrict__ rb,
                                             const float* __restrict__ x1b,
                                             const float* __restrict__ x2b,
                                             const float* __restrict__ W,
                                             const float* __restrict__ bias,
                                             float* __restrict__ h) {
    __shared__ half_t a_t[64 * ATS];   // [row-local][c]
    __shared__ half_t b_t[64 * BTS];   // [o][c]
    int tid = threadIdx.x;
    int wave = tid >> 6, lane = tid & 63;
    int lm = lane & 15, lg = lane >> 4;
    int row0 = blockIdx.x * 64;                       // row = v*48+bt
    const float* bases[3] = {rb, x1b, x2b};
    union PU { half2v h2[2]; half4v h4; };
    const f32x4 zc = {0.f, 0.f, 0.f, 0.f};
    f32x4 acc[4] = {zc, zc, zc, zc};

    for (int ch = 0; ch < 3; ++ch) {
        const float* A = bases[ch];
#pragma unroll
        for (int i = 0; i < 4; ++i) {
            int g = tid + i * 256;
            int r = g >> 4, q = g & 15;
            float4 a = *(const float4*)(A + (size_t)(row0 + r) * 64 + 4 * q);
            PU ua;
            ua.h2[0] = __builtin_amdgcn_cvt_pkrtz(a.x, a.y);
            ua.h2[1] = __builtin_amdgcn_cvt_pkrtz(a.z, a.w);
            *(half4v*)&a_t[r * ATS + 4 * q] = ua.h4;
            float4 w = *(const float4*)(W + (size_t)r * 192 + ch * 64 + 4 * q);
            PU uw;
            uw.h2[0] = __builtin_amdgcn_cvt_pkrtz(w.x, w.y);
            uw.h2[1] = __builtin_amdgcn_cvt_pkrtz(w.z, w.w);
            *(half4v*)&b_t[r * BTS + 4 * q] = uw.h4;
        }
        __syncthreads();
#pragma unroll
        for (int k16 = 0; k16 < 4; ++k16) {
            half4v af = *(const half4v*)&a_t[(wave * 16 + lm) * ATS + k16 * 16 + lg * 4];
#pragma unroll
            for (int nt = 0; nt < 4; ++nt) {
                half4v bf = *(const half4v*)&b_t[(nt * 16 + lm) * BTS + k16 * 16 + lg * 4];
                acc[nt] = __builtin_amdgcn_mfma_f32_16x16x16f16(bf, af, acc[nt], 0, 0, 0);
            }
        }
        __syncthreads();
    }
    int row = row0 + wave * 16 + lm;
    int v = row / 48, bt = row - v * 48;
    float* hp = h + ((size_t)(bt * 512 + v)) * 64;
#pragma unroll
    for (int nt = 0; nt < 4; ++nt)
#pragma unroll
        for (int r = 0; r < 4; ++r) {
            int o = nt * 16 + lg * 4 + r;
            hp[o] += acc[nt][r] + bias[o];
        }
}

// ---------------- final: out[b,c,v,t] = h[(b*12+t)*512+v][c] ----------------
__global__ __launch_bounds__(256) void k_out(const float* __restrict__ h,
                                             float* __restrict__ out) {
    int i = blockIdx.x * 256 + threadIdx.x;
    int t = i % 12;
    int r = i / 12;
    int v = r & 511;
    int r2 = r >> 9;
    int c = r2 & 63;
    int b = r2 >> 6;
    out[i] = h[(((size_t)(b * 12 + t) * 512) + v) * 64 + c];
}

extern "C" void kernel_launch(void* const* d_in, const int* in_sizes, int n_in,
                              void* d_out, int out_size, void* d_ws, size_t ws_size,
                              hipStream_t stream) {
    const float* x      = (const float*)d_in[0];
    const float* adj    = (const float*)d_in[1];
    const float* pos    = (const float*)d_in[2];
    const float* qkv_w  = (const float*)d_in[3];
    const float* proj_w = (const float*)d_in[4];
    const float* proj_b = (const float*)d_in[5];
    const float* ln_g   = (const float*)d_in[6];
    const float* ln_b   = (const float*)d_in[7];
    const float* ff_w1  = (const float*)d_in[8];
    const float* ff_b1  = (const float*)d_in[9];
    const float* ff_w2  = (const float*)d_in[10];
    const float* ff_b2  = (const float*)d_in[11];
    const float* gcn_w  = (const float*)d_in[12];
    const float* gcn_b  = (const float*)d_in[13];
    float* out = (float*)d_out;

    const size_t SZ = 1572864;  // 48*512*64
    float* h  = (float*)d_ws;
    float* rb = h  + SZ;
    float* x1 = rb + SZ;
    float* x2 = x1 + SZ;
    float* qb = x2 + SZ;
    float* kb = qb + SZ;
    float* vb = kb + SZ;
    float* ob = vb + SZ;
    half_t* adjTh = (half_t*)(ob + SZ);   // 512KB

    k_init<<<6144, 256, 0, stream>>>(x, pos, h);
    k_adjt<<<dim3(8, 8), 256, 0, stream>>>(adj, adjTh);
    for (int l = 0; l < 2; ++l) {
        k_trans<<<1536, 256, 0, stream>>>(h, rb);
        k_qkv<<<1536, 256, 0, stream>>>(h, qkv_w + l * 12288, qb, kb, vb);
        k_attn<<<768, 512, 0, stream>>>(qb, kb, vb, ob);
        k_plf<<<1536, 256, 0, stream>>>(ob, proj_w + l * 4096, proj_b + l * 64,
                                        ln_g + l * 64, ln_b + l * 64,
                                        ff_w1 + l * 16384, ff_b1 + l * 256,
                                        ff_w2 + l * 16384, ff_b2 + l * 64, h);
        k_diff<<<dim3(8, 48), 256, 0, stream>>>(adjTh, rb, x1);
        k_diff<<<dim3(8, 48), 256, 0, stream>>>(adjTh, x1, x2);
        k_gcn<<<384, 256, 0, stream>>>(rb, x1, x2, gcn_w + l * 12288, gcn_b + l * 64, h);
    }
    k_out<<<6144, 256, 0, stream>>>(h, out);
}

// Round 12
// 367.822 us; speedup vs baseline: 1.1108x; 1.1108x over previous
//
#include <hip/hip_runtime.h>
#include <math.h>

// Sizes: b=4, t=12 (BT=48), n=512, c=64, heads=8, hd=8, FF hidden=256, depth=2
#define LDSP 68

typedef __fp16 half_t;
typedef __attribute__((ext_vector_type(2))) __fp16 half2v;
typedef __attribute__((ext_vector_type(4))) __fp16 half4v;
typedef __attribute__((ext_vector_type(4))) float f32x4;

// ---------------- init: h[(bt*512+v)*64+c] = x[b,c,v,t] + pos[v,c] ----------------
__global__ __launch_bounds__(256) void k_init(const float* __restrict__ x,
                                              const float* __restrict__ pos,
                                              float* __restrict__ h) {
    int i = blockIdx.x * 256 + threadIdx.x;
    int c = i & 63;
    int v = (i >> 6) & 511;
    int bt = i >> 15;
    int b = bt / 12, t = bt - b * 12;
    h[i] = x[(((size_t)(b * 64 + c) * 512) + v) * 12 + t] + pos[v * 64 + c];
}

// ---------------- transpose h -> rbuf[(v*48+bt)*64+c] ----------------
__global__ __launch_bounds__(256) void k_trans(const float* __restrict__ h,
                                               float* __restrict__ rb) {
    int f = blockIdx.x * 256 + threadIdx.x;
    int c4 = f & 15;
    int row = f >> 4;
    int v = row / 48, bt = row - v * 48;
    ((float4*)rb)[f] = ((const float4*)h)[((size_t)(bt * 512 + v)) * 16 + c4];
}

// ---------------- one-time: all weights fp32 -> f16 (both layers) ----------------
// layout: qkv[24576] | proj[8192] | w1[32768] | w2[32768] | gcn[24576]  = 122880
__global__ __launch_bounds__(256) void k_prep(const float* __restrict__ qkv_w,
                                              const float* __restrict__ proj_w,
                                              const float* __restrict__ ff_w1,
                                              const float* __restrict__ ff_w2,
                                              const float* __restrict__ gcn_w,
                                              half_t* __restrict__ dst) {
    int i = blockIdx.x * 256 + threadIdx.x;   // 480 blocks
    float v;
    if (i < 24576) v = qkv_w[i];
    else if (i < 32768) v = proj_w[i - 24576];
    else if (i < 65536) v = ff_w1[i - 32768];
    else if (i < 98304) v = ff_w2[i - 65536];
    else v = gcn_w[i - 98304];
    dst[i] = (half_t)v;
}

// ---------------- adj -> adjTh[w][v] (f16 transposed), once per launch ----------------
__global__ __launch_bounds__(256) void k_adjt(const float* __restrict__ adj,
                                              half_t* __restrict__ adjTh) {
    __shared__ float t[64 * 65];
    int tid = threadIdx.x;
    int v0 = blockIdx.x * 64, w0 = blockIdx.y * 64;
#pragma unroll
    for (int i = 0; i < 4; ++i) {
        int g = tid + i * 256;
        int r = g >> 4, q = g & 15;
        float4 a = *(const float4*)(adj + (size_t)(v0 + r) * 512 + w0 + 4 * q);
        t[(4 * q + 0) * 65 + r] = a.x;
        t[(4 * q + 1) * 65 + r] = a.y;
        t[(4 * q + 2) * 65 + r] = a.z;
        t[(4 * q + 3) * 65 + r] = a.w;
    }
    __syncthreads();
    union PU { half2v h2[2]; half4v h4; };
#pragma unroll
    for (int i = 0; i < 4; ++i) {
        int g = tid + i * 256;
        int rw = g >> 4, q = g & 15;
        const float* src = &t[rw * 65 + 4 * q];
        PU u;
        u.h2[0] = __builtin_amdgcn_cvt_pkrtz(src[0], src[1]);
        u.h2[1] = __builtin_amdgcn_cvt_pkrtz(src[2], src[3]);
        *(half4v*)(adjTh + (size_t)(w0 + rw) * 512 + v0 + 4 * q) = u.h4;
    }
}

// ---------------- MFMA qkv: wave = 16 tokens, 12 nt serial, f16 weights + prefetch ----------------
__global__ __launch_bounds__(128) void k_qkv(const float* __restrict__ h,
                                             const half_t* __restrict__ Wh,
                                             float* __restrict__ qb,
                                             float* __restrict__ kb,
                                             float* __restrict__ vb) {
    int wid = blockIdx.x * 2 + (threadIdx.x >> 6);    // 0..1535
    int lane = threadIdx.x & 63;
    int lm = lane & 15, lg = lane >> 4;
    int row = wid * 16 + lm;
    union PU { half2v h2[2]; half4v h4; };

    half4v xf[4];
#pragma unroll
    for (int kc = 0; kc < 4; ++kc) {
        float4 a = *(const float4*)(h + (size_t)row * 64 + kc * 16 + lg * 4);
        PU u;
        u.h2[0] = __builtin_amdgcn_cvt_pkrtz(a.x, a.y);
        u.h2[1] = __builtin_amdgcn_cvt_pkrtz(a.z, a.w);
        xf[kc] = u.h4;
    }

    const f32x4 zc = {0.f, 0.f, 0.f, 0.f};
    int bt = row >> 9, v = row & 511;

    half4v wf[4];
#pragma unroll
    for (int kc = 0; kc < 4; ++kc)
        wf[kc] = *(const half4v*)(Wh + (size_t)lm * 64 + kc * 16 + lg * 4);

#pragma unroll
    for (int nt = 0; nt < 12; ++nt) {
        half4v cw[4];
#pragma unroll
        for (int kc = 0; kc < 4; ++kc) cw[kc] = wf[kc];
        if (nt < 11) {
#pragma unroll
            for (int kc = 0; kc < 4; ++kc)
                wf[kc] = *(const half4v*)(Wh + (size_t)((nt + 1) * 16 + lm) * 64 + kc * 16 + lg * 4);
        }
        f32x4 acc = zc;
#pragma unroll
        for (int kc = 0; kc < 4; ++kc)
            acc = __builtin_amdgcn_mfma_f32_16x16x16f16(cw[kc], xf[kc], acc, 0, 0, 0);
        int s = nt >> 2;
        int head = ((nt & 3) << 1) + (lg >> 1);
        int d0 = (lg & 1) * 4;
        float* dst = (s == 0) ? qb : ((s == 1) ? kb : vb);
        *(float4*)(dst + ((size_t)(bt * 8 + head) * 512 + v) * 8 + d0) =
            make_float4(acc[0], acc[1], acc[2], acc[3]);
    }
}

// ---------------- MFMA attention (fixed-max softmax; 512 thr = 8 waves x 2 strips) ----------------
#define KLS 20
#define QLS 20
#define VTS 516

__global__ __launch_bounds__(512) void k_attn(const float* __restrict__ qb,
                                              const float* __restrict__ kb,
                                              const float* __restrict__ vb,
                                              float* __restrict__ ob) {
    __shared__ half_t kl[512 * KLS];
    __shared__ half_t vt[16 * VTS];
    __shared__ half_t ql[256 * QLS];
    int bh = blockIdx.x >> 1;
    int half_ = blockIdx.x & 1;
    int tid = threadIdx.x;
    const float* kbase = kb + (size_t)bh * 4096;
    const float* vbase = vb + (size_t)bh * 4096;
    const float* qbase = qb + (size_t)bh * 4096 + half_ * 2048;

    union PU { half2v h2[2]; half4v h4; };
    const half4v zero4 = {(__fp16)0.f, (__fp16)0.f, (__fp16)0.f, (__fp16)0.f};

    if (tid < 256) {
#pragma unroll
        for (int kk = 0; kk < 2; ++kk) {
            int key = tid * 2 + kk;
            float4 a = *(const float4*)(kbase + key * 8);
            float4 b = *(const float4*)(kbase + key * 8 + 4);
            PU u0, u1;
            u0.h2[0] = __builtin_amdgcn_cvt_pkrtz(a.x, a.y);
            u0.h2[1] = __builtin_amdgcn_cvt_pkrtz(a.z, a.w);
            u1.h2[0] = __builtin_amdgcn_cvt_pkrtz(b.x, b.y);
            u1.h2[1] = __builtin_amdgcn_cvt_pkrtz(b.z, b.w);
            half4v* rowp = (half4v*)&kl[key * KLS];
            rowp[0] = u0.h4;
            rowp[1] = u1.h4;
            rowp[2] = zero4;
            rowp[3] = zero4;
        }
        {
            const float SC = 0.35355339059327373f * 1.4426950408889634f;
            float4 a = *(const float4*)(qbase + tid * 8);
            float4 b = *(const float4*)(qbase + tid * 8 + 4);
            PU u0, u1;
            u0.h2[0] = __builtin_amdgcn_cvt_pkrtz(a.x * SC, a.y * SC);
            u0.h2[1] = __builtin_amdgcn_cvt_pkrtz(a.z * SC, a.w * SC);
            u1.h2[0] = __builtin_amdgcn_cvt_pkrtz(b.x * SC, b.y * SC);
            u1.h2[1] = __builtin_amdgcn_cvt_pkrtz(b.z * SC, b.w * SC);
            half4v* rowp = (half4v*)&ql[tid * QLS];
            rowp[0] = u0.h4;
            rowp[1] = u1.h4;
            rowp[2] = zero4;
            rowp[3] = zero4;
        }
        {
            int k0 = tid * 2;
            float4 a0 = *(const float4*)(vbase + k0 * 8);
            float4 a1 = *(const float4*)(vbase + k0 * 8 + 4);
            float4 b0 = *(const float4*)(vbase + k0 * 8 + 8);
            float4 b1 = *(const float4*)(vbase + k0 * 8 + 12);
            *(half2v*)&vt[0 * VTS + k0] = __builtin_amdgcn_cvt_pkrtz(a0.x, b0.x);
            *(half2v*)&vt[1 * VTS + k0] = __builtin_amdgcn_cvt_pkrtz(a0.y, b0.y);
            *(half2v*)&vt[2 * VTS + k0] = __builtin_amdgcn_cvt_pkrtz(a0.z, b0.z);
            *(half2v*)&vt[3 * VTS + k0] = __builtin_amdgcn_cvt_pkrtz(a0.w, b0.w);
            *(half2v*)&vt[4 * VTS + k0] = __builtin_amdgcn_cvt_pkrtz(a1.x, b1.x);
            *(half2v*)&vt[5 * VTS + k0] = __builtin_amdgcn_cvt_pkrtz(a1.y, b1.y);
            *(half2v*)&vt[6 * VTS + k0] = __builtin_amdgcn_cvt_pkrtz(a1.z, b1.z);
            *(half2v*)&vt[7 * VTS + k0] = __builtin_amdgcn_cvt_pkrtz(a1.w, b1.w);
        }
    }
    for (int i = tid; i < 1032; i += 512)
        ((half4v*)(vt + 8 * VTS))[i] = zero4;
    __syncthreads();

    int wave = tid >> 6, lane = tid & 63;
    int lm = lane & 15, lg = lane >> 4;
    int bt = bh >> 3, head = bh & 7;

#pragma unroll 1
    for (int st = 0; st < 2; ++st) {
        int qrow0 = wave * 32 + st * 16;
        half4v qf = *(const half4v*)&ql[(qrow0 + lm) * QLS + lg * 4];
        f32x4 acc = {0.f, 0.f, 0.f, 0.f};
        float l0 = 0.f, l1 = 0.f, l2 = 0.f, l3 = 0.f;
        f32x4 zc = {0.f, 0.f, 0.f, 0.f};
#pragma unroll 4
        for (int kt = 0; kt < 32; ++kt) {
            int key0 = kt * 16;
            half4v ka = *(const half4v*)&kl[(key0 + lm) * KLS + lg * 4];
            f32x4 c1 = __builtin_amdgcn_mfma_f32_16x16x16f16(ka, qf, zc, 0, 0, 0);
            float p0 = exp2f(fminf(c1[0], 12.f));
            float p1 = exp2f(fminf(c1[1], 12.f));
            float p2 = exp2f(fminf(c1[2], 12.f));
            float p3 = exp2f(fminf(c1[3], 12.f));
            l0 += p0; l1 += p1; l2 += p2; l3 += p3;
            PU pu;
            pu.h2[0] = __builtin_amdgcn_cvt_pkrtz(p0, p1);
            pu.h2[1] = __builtin_amdgcn_cvt_pkrtz(p2, p3);
            half4v va = *(const half4v*)&vt[lm * VTS + key0 + lg * 4];
            acc = __builtin_amdgcn_mfma_f32_16x16x16f16(va, pu.h4, acc, 0, 0, 0);
        }
        float lsum = (l0 + l1) + (l2 + l3);
        lsum += __shfl_xor(lsum, 16);
        lsum += __shfl_xor(lsum, 32);
        if (lg < 2) {
            float inv = 1.f / lsum;
            int rowg = half_ * 256 + qrow0 + lm;
            float* op = ob + ((size_t)(bt * 512 + rowg)) * 64 + head * 8 + lg * 4;
            *(float4*)op = make_float4(acc[0] * inv, acc[1] * inv, acc[2] * inv, acc[3] * inv);
        }
    }
}

// ---------------- fused proj + LayerNorm + FF (MFMA, f16 weights + rotating prefetch) ----------------
__global__ __launch_bounds__(128) void k_plf(const float* __restrict__ ob,
                                             const half_t* __restrict__ pwh,
                                             const float* __restrict__ pb,
                                             const float* __restrict__ g,
                                             const float* __restrict__ bln,
                                             const half_t* __restrict__ w1h,
                                             const float* __restrict__ b1,
                                             const half_t* __restrict__ w2h,
                                             const float* __restrict__ b2,
                                             float* __restrict__ h) {
    int wid = blockIdx.x * 2 + (threadIdx.x >> 6);    // 0..1535
    int lane = threadIdx.x & 63;
    int lm = lane & 15, lg = lane >> 4;
    int row = wid * 16 + lm;
    union PU { half2v h2[2]; half4v h4; };
    const f32x4 zc = {0.f, 0.f, 0.f, 0.f};

    // prefetch proj nt=0 weights immediately
    half4v pf[4];
#pragma unroll
    for (int kc = 0; kc < 4; ++kc)
        pf[kc] = *(const half4v*)(pwh + (size_t)lm * 64 + kc * 16 + lg * 4);

    // attention-output B-frags
    half4v of[4];
#pragma unroll
    for (int kc = 0; kc < 4; ++kc) {
        float4 a = *(const float4*)(ob + (size_t)row * 64 + kc * 16 + lg * 4);
        PU u;
        u.h2[0] = __builtin_amdgcn_cvt_pkrtz(a.x, a.y);
        u.h2[1] = __builtin_amdgcn_cvt_pkrtz(a.z, a.w);
        of[kc] = u.h4;
    }

    // proj + residual with prefetch
    f32x4 hp[4];
#pragma unroll
    for (int nt = 0; nt < 4; ++nt) {
        half4v cw[4];
#pragma unroll
        for (int kc = 0; kc < 4; ++kc) cw[kc] = pf[kc];
        if (nt < 3) {
#pragma unroll
            for (int kc = 0; kc < 4; ++kc)
                pf[kc] = *(const half4v*)(pwh + (size_t)((nt + 1) * 16 + lm) * 64 + kc * 16 + lg * 4);
        }
        f32x4 c = zc;
#pragma unroll
        for (int kc = 0; kc < 4; ++kc)
            c = __builtin_amdgcn_mfma_f32_16x16x16f16(cw[kc], of[kc], c, 0, 0, 0);
        float4 ho = *(const float4*)(h + (size_t)row * 64 + nt * 16 + lg * 4);
        float4 bb = *(const float4*)(pb + nt * 16 + lg * 4);
        hp[nt][0] = c[0] + ho.x + bb.x;
        hp[nt][1] = c[1] + ho.y + bb.y;
        hp[nt][2] = c[2] + ho.z + bb.z;
        hp[nt][3] = c[3] + ho.w + bb.w;
    }

    // LayerNorm
    float s = 0.f, s2 = 0.f;
#pragma unroll
    for (int nt = 0; nt < 4; ++nt)
#pragma unroll
        for (int r = 0; r < 4; ++r) {
            s += hp[nt][r];
            s2 += hp[nt][r] * hp[nt][r];
        }
    s += __shfl_xor(s, 16);  s2 += __shfl_xor(s2, 16);
    s += __shfl_xor(s, 32);  s2 += __shfl_xor(s2, 32);
    float mean = s * (1.f / 64.f);
    float var = s2 * (1.f / 64.f) - mean * mean;
    float rstd = rsqrtf(var + 1e-5f);

    half4v xf[4];
#pragma unroll
    for (int nt = 0; nt < 4; ++nt) {
        float4 gg = *(const float4*)(g + nt * 16 + lg * 4);
        float4 bb = *(const float4*)(bln + nt * 16 + lg * 4);
        float y0 = (hp[nt][0] - mean) * rstd * gg.x + bb.x;
        float y1 = (hp[nt][1] - mean) * rstd * gg.y + bb.y;
        float y2 = (hp[nt][2] - mean) * rstd * gg.z + bb.z;
        float y3 = (hp[nt][3] - mean) * rstd * gg.w + bb.w;
        PU u;
        u.h2[0] = __builtin_amdgcn_cvt_pkrtz(y0, y1);
        u.h2[1] = __builtin_amdgcn_cvt_pkrtz(y2, y3);
        xf[nt] = u.h4;
    }

    // FF: w1 prefetched one ht ahead; w2 frags issued before the mfma/gelu chain
    half4v w1f[4];
#pragma unroll
    for (int kc = 0; kc < 4; ++kc)
        w1f[kc] = *(const half4v*)(w1h + (size_t)lm * 64 + kc * 16 + lg * 4);

    f32x4 acc[4] = {zc, zc, zc, zc};
#pragma unroll 4
    for (int ht = 0; ht < 16; ++ht) {
        half4v cw[4];
#pragma unroll
        for (int kc = 0; kc < 4; ++kc) cw[kc] = w1f[kc];
        // issue current w2 loads now (in flight through the mfma+gelu chain)
        half4v w2f[4];
#pragma unroll
        for (int ot = 0; ot < 4; ++ot)
            w2f[ot] = *(const half4v*)(w2h + (size_t)(ot * 16 + lm) * 256 + ht * 16 + lg * 4);
        if (ht < 15) {
#pragma unroll
            for (int kc = 0; kc < 4; ++kc)
                w1f[kc] = *(const half4v*)(w1h + (size_t)((ht + 1) * 16 + lm) * 64 + kc * 16 + lg * 4);
        }
        f32x4 c1 = zc;
#pragma unroll
        for (int kc = 0; kc < 4; ++kc)
            c1 = __builtin_amdgcn_mfma_f32_16x16x16f16(cw[kc], xf[kc], c1, 0, 0, 0);
        float4 bb = *(const float4*)(b1 + ht * 16 + lg * 4);
        float y0 = c1[0] + bb.x;
        float y1 = c1[1] + bb.y;
        float y2 = c1[2] + bb.z;
        float y3 = c1[3] + bb.w;
        y0 = 0.5f * y0 * (1.0f + erff(y0 * 0.70710678118654752f));
        y1 = 0.5f * y1 * (1.0f + erff(y1 * 0.70710678118654752f));
        y2 = 0.5f * y2 * (1.0f + erff(y2 * 0.70710678118654752f));
        y3 = 0.5f * y3 * (1.0f + erff(y3 * 0.70710678118654752f));
        PU p;
        p.h2[0] = __builtin_amdgcn_cvt_pkrtz(y0, y1);
        p.h2[1] = __builtin_amdgcn_cvt_pkrtz(y2, y3);
#pragma unroll
        for (int ot = 0; ot < 4; ++ot)
            acc[ot] = __builtin_amdgcn_mfma_f32_16x16x16f16(w2f[ot], p.h4, acc[ot], 0, 0, 0);
    }

#pragma unroll
    for (int ot = 0; ot < 4; ++ot) {
        float4 bb = *(const float4*)(b2 + ot * 16 + lg * 4);
        *(float4*)(h + (size_t)row * 64 + ot * 16 + lg * 4) =
            make_float4(hp[ot][0] + acc[ot][0] + bb.x,
                        hp[ot][1] + acc[ot][1] + bb.y,
                        hp[ot][2] + acc[ot][2] + bb.z,
                        hp[ot][3] + acc[ot][3] + bb.w);
    }
}

// ---------------- MFMA diffusion: out[w][p] = sum_v adjTh[w][v]*in[v][p] ----------------
#define ATS 72
#define BTS 68

__global__ __launch_bounds__(256) void k_diff(const half_t* __restrict__ adjTh,
                                              const float* __restrict__ in,
                                              float* __restrict__ outb) {
    __shared__ half_t a_t[64 * ATS];
    __shared__ half_t b_t[64 * BTS];
    int tid = threadIdx.x;
    int wave = tid >> 6, lane = tid & 63;
    int lm = lane & 15, lg = lane >> 4;
    int w0 = blockIdx.x * 64, p0 = blockIdx.y * 64;
    const f32x4 zc = {0.f, 0.f, 0.f, 0.f};
    f32x4 acc[4] = {zc, zc, zc, zc};

    for (int kc = 0; kc < 8; ++kc) {
#pragma unroll
        for (int i = 0; i < 2; ++i) {
            int g = tid + i * 256;
            int r = g >> 3, s = g & 7;
            *(float4*)&a_t[r * ATS + s * 8] =
                *(const float4*)(adjTh + (size_t)(w0 + r) * 512 + kc * 64 + s * 8);
        }
#pragma unroll
        for (int i = 0; i < 4; ++i) {
            int g = tid + i * 256;
            int vr = g >> 4, q = g & 15;
            float4 a = *(const float4*)(in + (size_t)(kc * 64 + vr) * 3072 + p0 + 4 * q);
            b_t[(4 * q + 0) * BTS + vr] = (half_t)a.x;
            b_t[(4 * q + 1) * BTS + vr] = (half_t)a.y;
            b_t[(4 * q + 2) * BTS + vr] = (half_t)a.z;
            b_t[(4 * q + 3) * BTS + vr] = (half_t)a.w;
        }
        __syncthreads();
#pragma unroll
        for (int k16 = 0; k16 < 4; ++k16) {
            half4v af = *(const half4v*)&a_t[(wave * 16 + lm) * ATS + k16 * 16 + lg * 4];
#pragma unroll
            for (int nt = 0; nt < 4; ++nt) {
                half4v bf = *(const half4v*)&b_t[(nt * 16 + lm) * BTS + k16 * 16 + lg * 4];
                acc[nt] = __builtin_amdgcn_mfma_f32_16x16x16f16(af, bf, acc[nt], 0, 0, 0);
            }
        }
        __syncthreads();
    }
#pragma unroll
    for (int nt = 0; nt < 4; ++nt)
#pragma unroll
        for (int r = 0; r < 4; ++r)
            outb[(size_t)(w0 + wave * 16 + lg * 4 + r) * 3072 + p0 + nt * 16 + lm] = acc[nt][r];
}

// ---------------- MFMA gcn (f16 weights) ----------------
__global__ __launch_bounds__(256) void k_gcn(const float* __restrict__ rb,
                                             const float* __restrict__ x1b,
                                             const float* __restrict__ x2b,
                                             const half_t* __restrict__ Wh,
                                             const float* __restrict__ bias,
                                             float* __restrict__ h) {
    __shared__ half_t a_t[64 * ATS];
    __shared__ half_t b_t[64 * BTS];
    int tid = threadIdx.x;
    int wave = tid >> 6, lane = tid & 63;
    int lm = lane & 15, lg = lane >> 4;
    int row0 = blockIdx.x * 64;
    const float* bases[3] = {rb, x1b, x2b};
    union PU { half2v h2[2]; half4v h4; };
    const f32x4 zc = {0.f, 0.f, 0.f, 0.f};
    f32x4 acc[4] = {zc, zc, zc, zc};

    for (int ch = 0; ch < 3; ++ch) {
        const float* A = bases[ch];
#pragma unroll
        for (int i = 0; i < 4; ++i) {
            int g = tid + i * 256;
            int r = g >> 4, q = g & 15;
            float4 a = *(const float4*)(A + (size_t)(row0 + r) * 64 + 4 * q);
            PU ua;
            ua.h2[0] = __builtin_amdgcn_cvt_pkrtz(a.x, a.y);
            ua.h2[1] = __builtin_amdgcn_cvt_pkrtz(a.z, a.w);
            *(half4v*)&a_t[r * ATS + 4 * q] = ua.h4;
            *(half4v*)&b_t[r * BTS + 4 * q] =
                *(const half4v*)(Wh + (size_t)r * 192 + ch * 64 + 4 * q);
        }
        __syncthreads();
#pragma unroll
        for (int k16 = 0; k16 < 4; ++k16) {
            half4v af = *(const half4v*)&a_t[(wave * 16 + lm) * ATS + k16 * 16 + lg * 4];
#pragma unroll
            for (int nt = 0; nt < 4; ++nt) {
                half4v bf = *(const half4v*)&b_t[(nt * 16 + lm) * BTS + k16 * 16 + lg * 4];
                acc[nt] = __builtin_amdgcn_mfma_f32_16x16x16f16(bf, af, acc[nt], 0, 0, 0);
            }
        }
        __syncthreads();
    }
    int row = row0 + wave * 16 + lm;
    int v = row / 48, bt = row - v * 48;
    float* hp = h + ((size_t)(bt * 512 + v)) * 64;
#pragma unroll
    for (int nt = 0; nt < 4; ++nt)
#pragma unroll
        for (int r = 0; r < 4; ++r) {
            int o = nt * 16 + lg * 4 + r;
            hp[o] += acc[nt][r] + bias[o];
        }
}

// ---------------- final: out[b,c,v,t] = h[(b*12+t)*512+v][c] ----------------
__global__ __launch_bounds__(256) void k_out(const float* __restrict__ h,
                                             float* __restrict__ out) {
    int i = blockIdx.x * 256 + threadIdx.x;
    int t = i % 12;
    int r = i / 12;
    int v = r & 511;
    int r2 = r >> 9;
    int c = r2 & 63;
    int b = r2 >> 6;
    out[i] = h[(((size_t)(b * 12 + t) * 512) + v) * 64 + c];
}

extern "C" void kernel_launch(void* const* d_in, const int* in_sizes, int n_in,
                              void* d_out, int out_size, void* d_ws, size_t ws_size,
                              hipStream_t stream) {
    const float* x      = (const float*)d_in[0];
    const float* adj    = (const float*)d_in[1];
    const float* pos    = (const float*)d_in[2];
    const float* qkv_w  = (const float*)d_in[3];
    const float* proj_w = (const float*)d_in[4];
    const float* proj_b = (const float*)d_in[5];
    const float* ln_g   = (const float*)d_in[6];
    const float* ln_b   = (const float*)d_in[7];
    const float* ff_w1  = (const float*)d_in[8];
    const float* ff_b1  = (const float*)d_in[9];
    const float* ff_w2  = (const float*)d_in[10];
    const float* ff_b2  = (const float*)d_in[11];
    const float* gcn_w  = (const float*)d_in[12];
    const float* gcn_b  = (const float*)d_in[13];
    float* out = (float*)d_out;

    const size_t SZ = 1572864;  // 48*512*64
    float* h  = (float*)d_ws;
    float* rb = h  + SZ;
    float* x1 = rb + SZ;
    float* x2 = x1 + SZ;
    float* qb = x2 + SZ;
    float* kb = qb + SZ;
    float* vb = kb + SZ;
    float* ob = vb + SZ;
    half_t* adjTh = (half_t*)(ob + SZ);        // 512 KB
    half_t* wh     = adjTh + 262144;           // 246 KB of f16 weights
    half_t* qkv_wh  = wh;                      // [2][12288]
    half_t* proj_wh = wh + 24576;              // [2][4096]
    half_t* ff_w1h  = wh + 32768;              // [2][16384]
    half_t* ff_w2h  = wh + 65536;              // [2][16384]
    half_t* gcn_wh  = wh + 98304;              // [2][12288]

    k_init<<<6144, 256, 0, stream>>>(x, pos, h);
    k_adjt<<<dim3(8, 8), 256, 0, stream>>>(adj, adjTh);
    k_prep<<<480, 256, 0, stream>>>(qkv_w, proj_w, ff_w1, ff_w2, gcn_w, wh);
    for (int l = 0; l < 2; ++l) {
        k_trans<<<1536, 256, 0, stream>>>(h, rb);
        k_qkv<<<768, 128, 0, stream>>>(h, qkv_wh + l * 12288, qb, kb, vb);
        k_attn<<<768, 512, 0, stream>>>(qb, kb, vb, ob);
        k_plf<<<768, 128, 0, stream>>>(ob, proj_wh + l * 4096, proj_b + l * 64,
                                       ln_g + l * 64, ln_b + l * 64,
                                       ff_w1h + l * 16384, ff_b1 + l * 256,
                                       ff_w2h + l * 16384, ff_b2 + l * 64, h);
        k_diff<<<dim3(8, 48), 256, 0, stream>>>(adjTh, rb, x1);
        k_diff<<<dim3(8, 48), 256, 0, stream>>>(adjTh, x1, x2);
        k_gcn<<<384, 256, 0, stream>>>(rb, x1, x2, gcn_wh + l * 12288, gcn_b + l * 64, h);
    }
    k_out<<<6144, 256, 0, stream>>>(h, out);
}

// Round 13
// 320.620 us; speedup vs baseline: 1.2743x; 1.1472x over previous
//
#include <hip/hip_runtime.h>
#include <math.h>

// Sizes: b=4, t=12 (BT=48), n=512, c=64, heads=8, hd=8, FF hidden=256, depth=2

typedef __fp16 half_t;
typedef __attribute__((ext_vector_type(2))) __fp16 half2v;
typedef __attribute__((ext_vector_type(4))) __fp16 half4v;
typedef __attribute__((ext_vector_type(4))) float f32x4;

union PU  { half2v h2[2]; half4v h4; };
union F4H { float4 f; half4v h[2]; };
union F2H { float2 f2; half4v h4; };

// ---------------- init: h[(bt*512+v)*64+c] = x[b,c,v,t] + pos[v,c] ----------------
__global__ __launch_bounds__(256) void k_init(const float* __restrict__ x,
                                              const float* __restrict__ pos,
                                              float* __restrict__ h) {
    int i = blockIdx.x * 256 + threadIdx.x;
    int c = i & 63;
    int v = (i >> 6) & 511;
    int bt = i >> 15;
    int b = bt / 12, t = bt - b * 12;
    h[i] = x[(((size_t)(b * 64 + c) * 512) + v) * 12 + t] + pos[v * 64 + c];
}

// ---------------- one-time: all weights fp32 -> f16 (both layers) ----------------
// layout: qkv[24576] | proj[8192] | w1[32768] | w2[32768] | gcn[24576] = 122880
__global__ __launch_bounds__(256) void k_prep(const float* __restrict__ qkv_w,
                                              const float* __restrict__ proj_w,
                                              const float* __restrict__ ff_w1,
                                              const float* __restrict__ ff_w2,
                                              const float* __restrict__ gcn_w,
                                              half_t* __restrict__ dst) {
    int i = blockIdx.x * 256 + threadIdx.x;   // 480 blocks
    float v;
    if (i < 24576) v = qkv_w[i];
    else if (i < 32768) v = proj_w[i - 24576];
    else if (i < 65536) v = ff_w1[i - 32768];
    else if (i < 98304) v = ff_w2[i - 65536];
    else v = gcn_w[i - 98304];
    dst[i] = (half_t)v;
}

// ---------------- adj -> adjTh[w][v] (f16 transposed), once ----------------
__global__ __launch_bounds__(256) void k_adjt(const float* __restrict__ adj,
                                              half_t* __restrict__ adjTh) {
    __shared__ float t[64 * 65];
    int tid = threadIdx.x;
    int v0 = blockIdx.x * 64, w0 = blockIdx.y * 64;
#pragma unroll
    for (int i = 0; i < 4; ++i) {
        int g = tid + i * 256;
        int r = g >> 4, q = g & 15;
        float4 a = *(const float4*)(adj + (size_t)(v0 + r) * 512 + w0 + 4 * q);
        t[(4 * q + 0) * 65 + r] = a.x;
        t[(4 * q + 1) * 65 + r] = a.y;
        t[(4 * q + 2) * 65 + r] = a.z;
        t[(4 * q + 3) * 65 + r] = a.w;
    }
    __syncthreads();
#pragma unroll
    for (int i = 0; i < 4; ++i) {
        int g = tid + i * 256;
        int rw = g >> 4, q = g & 15;
        const float* src = &t[rw * 65 + 4 * q];
        PU u;
        u.h2[0] = __builtin_amdgcn_cvt_pkrtz(src[0], src[1]);
        u.h2[1] = __builtin_amdgcn_cvt_pkrtz(src[2], src[3]);
        *(half4v*)(adjTh + (size_t)(w0 + rw) * 512 + v0 + 4 * q) = u.h4;
    }
}

#define ATS 72    // 16B-aligned LDS row stride (halves)
#define BTS 68

// ---------------- one-time: adjT2h = adjTh @ adjTh  ((A^T)^2, f16) ----------------
__global__ __launch_bounds__(256) void k_adj2(const half_t* __restrict__ adjTh,
                                              half_t* __restrict__ adjT2h) {
    __shared__ half_t a_t[64 * ATS];   // [w-local][u]
    __shared__ half_t b_t[64 * BTS];   // [v-local][u]
    int tid = threadIdx.x;
    int wave = tid >> 6, lane = tid & 63;
    int lm = lane & 15, lg = lane >> 4;
    int w0 = blockIdx.x * 64, v0 = blockIdx.y * 64;
    const f32x4 zc = {0.f, 0.f, 0.f, 0.f};
    f32x4 acc[4] = {zc, zc, zc, zc};

    for (int kc = 0; kc < 8; ++kc) {
#pragma unroll
        for (int i = 0; i < 2; ++i) {
            int g = tid + i * 256;
            int r = g >> 3, s = g & 7;
            *(float4*)&a_t[r * ATS + s * 8] =
                *(const float4*)(adjTh + (size_t)(w0 + r) * 512 + kc * 64 + s * 8);
        }
#pragma unroll
        for (int i = 0; i < 2; ++i) {
            int g = tid + i * 256;
            int ur = g >> 3, s = g & 7;
            F4H u;
            u.f = *(const float4*)(adjTh + (size_t)(kc * 64 + ur) * 512 + v0 + s * 8);
#pragma unroll
            for (int e = 0; e < 8; ++e)
                b_t[(s * 8 + e) * BTS + ur] = u.h[e >> 2][e & 3];
        }
        __syncthreads();
#pragma unroll
        for (int k16 = 0; k16 < 4; ++k16) {
            half4v af = *(const half4v*)&a_t[(wave * 16 + lm) * ATS + k16 * 16 + lg * 4];
#pragma unroll
            for (int nt = 0; nt < 4; ++nt) {
                half4v bf = *(const half4v*)&b_t[(nt * 16 + lm) * BTS + k16 * 16 + lg * 4];
                acc[nt] = __builtin_amdgcn_mfma_f32_16x16x16f16(af, bf, acc[nt], 0, 0, 0);
            }
        }
        __syncthreads();
    }
#pragma unroll
    for (int nt = 0; nt < 4; ++nt)
#pragma unroll
        for (int r = 0; r < 4; ++r)
            adjT2h[(size_t)(w0 + wave * 16 + lg * 4 + r) * 512 + v0 + nt * 16 + lm] =
                (half_t)acc[nt][r];
}

// ---------------- MFMA qkv -> f16 q/k/v; q pre-scaled by scale*log2e ----------------
__global__ __launch_bounds__(128) void k_qkv(const float* __restrict__ h,
                                             const half_t* __restrict__ Wh,
                                             half_t* __restrict__ qh,
                                             half_t* __restrict__ kh,
                                             half_t* __restrict__ vh) {
    int wid = blockIdx.x * 2 + (threadIdx.x >> 6);    // 0..1535
    int lane = threadIdx.x & 63;
    int lm = lane & 15, lg = lane >> 4;
    int row = wid * 16 + lm;

    half4v xf[4];
#pragma unroll
    for (int kc = 0; kc < 4; ++kc) {
        float4 a = *(const float4*)(h + (size_t)row * 64 + kc * 16 + lg * 4);
        PU u;
        u.h2[0] = __builtin_amdgcn_cvt_pkrtz(a.x, a.y);
        u.h2[1] = __builtin_amdgcn_cvt_pkrtz(a.z, a.w);
        xf[kc] = u.h4;
    }

    const f32x4 zc = {0.f, 0.f, 0.f, 0.f};
    const float SC = 0.35355339059327373f * 1.4426950408889634f;
    int bt = row >> 9, v = row & 511;

    half4v wf[4];
#pragma unroll
    for (int kc = 0; kc < 4; ++kc)
        wf[kc] = *(const half4v*)(Wh + (size_t)lm * 64 + kc * 16 + lg * 4);

#pragma unroll
    for (int nt = 0; nt < 12; ++nt) {
        half4v cw[4];
#pragma unroll
        for (int kc = 0; kc < 4; ++kc) cw[kc] = wf[kc];
        if (nt < 11) {
#pragma unroll
            for (int kc = 0; kc < 4; ++kc)
                wf[kc] = *(const half4v*)(Wh + (size_t)((nt + 1) * 16 + lm) * 64 + kc * 16 + lg * 4);
        }
        f32x4 acc = zc;
#pragma unroll
        for (int kc = 0; kc < 4; ++kc)
            acc = __builtin_amdgcn_mfma_f32_16x16x16f16(cw[kc], xf[kc], acc, 0, 0, 0);
        int s = nt >> 2;
        if (s == 0) { acc[0] *= SC; acc[1] *= SC; acc[2] *= SC; acc[3] *= SC; }
        int head = ((nt & 3) << 1) + (lg >> 1);
        int d0 = (lg & 1) * 4;
        PU o2;
        o2.h2[0] = __builtin_amdgcn_cvt_pkrtz(acc[0], acc[1]);
        o2.h2[1] = __builtin_amdgcn_cvt_pkrtz(acc[2], acc[3]);
        half_t* dst = (s == 0) ? qh : ((s == 1) ? kh : vh);
        *(half4v*)(dst + ((size_t)(bt * 8 + head) * 512 + v) * 8 + d0) = o2.h4;
    }
}

// ---------------- MFMA attention (f16 in, f16 out; fixed-max softmax) ----------------
#define KLS 20
#define QLS 20
#define VTS 516

__global__ __launch_bounds__(512) void k_attn(const half_t* __restrict__ qh,
                                              const half_t* __restrict__ kh,
                                              const half_t* __restrict__ vh,
                                              half_t* __restrict__ obh) {
    __shared__ half_t kl[512 * KLS];
    __shared__ half_t vt[16 * VTS];
    __shared__ half_t ql[256 * QLS];
    int bh = blockIdx.x >> 1;
    int half_ = blockIdx.x & 1;
    int tid = threadIdx.x;
    const half_t* kbase = kh + (size_t)bh * 4096;
    const half_t* vbase = vh + (size_t)bh * 4096;
    const half_t* qbase = qh + (size_t)bh * 4096 + half_ * 2048;
    const half4v zero4 = {(__fp16)0.f, (__fp16)0.f, (__fp16)0.f, (__fp16)0.f};

    if (tid < 256) {
#pragma unroll
        for (int kk = 0; kk < 2; ++kk) {
            int key = tid * 2 + kk;
            F4H u;
            u.f = *(const float4*)(kbase + key * 8);
            half4v* rowp = (half4v*)&kl[key * KLS];
            rowp[0] = u.h[0];
            rowp[1] = u.h[1];
            rowp[2] = zero4;
            rowp[3] = zero4;
        }
        {
            F4H u;
            u.f = *(const float4*)(qbase + tid * 8);
            half4v* rowp = (half4v*)&ql[tid * QLS];
            rowp[0] = u.h[0];
            rowp[1] = u.h[1];
            rowp[2] = zero4;
            rowp[3] = zero4;
        }
        {
            int k0 = tid * 2;
            F4H a, b;
            a.f = *(const float4*)(vbase + k0 * 8);        // key k0
            b.f = *(const float4*)(vbase + k0 * 8 + 8);    // key k0+1
#pragma unroll
            for (int d = 0; d < 8; ++d) {
                half2v p = {a.h[d >> 2][d & 3], b.h[d >> 2][d & 3]};
                *(half2v*)&vt[d * VTS + k0] = p;
            }
        }
    }
    for (int i = tid; i < 1032; i += 512)
        ((half4v*)(vt + 8 * VTS))[i] = zero4;
    __syncthreads();

    int wave = tid >> 6, lane = tid & 63;
    int lm = lane & 15, lg = lane >> 4;
    int bt = bh >> 3, head = bh & 7;

#pragma unroll 1
    for (int st = 0; st < 2; ++st) {
        int qrow0 = wave * 32 + st * 16;
        half4v qf = *(const half4v*)&ql[(qrow0 + lm) * QLS + lg * 4];
        f32x4 acc = {0.f, 0.f, 0.f, 0.f};
        float l0 = 0.f, l1 = 0.f, l2 = 0.f, l3 = 0.f;
        f32x4 zc = {0.f, 0.f, 0.f, 0.f};
#pragma unroll 4
        for (int kt = 0; kt < 32; ++kt) {
            int key0 = kt * 16;
            half4v ka = *(const half4v*)&kl[(key0 + lm) * KLS + lg * 4];
            f32x4 c1 = __builtin_amdgcn_mfma_f32_16x16x16f16(ka, qf, zc, 0, 0, 0);
            float p0 = exp2f(fminf(c1[0], 12.f));
            float p1 = exp2f(fminf(c1[1], 12.f));
            float p2 = exp2f(fminf(c1[2], 12.f));
            float p3 = exp2f(fminf(c1[3], 12.f));
            l0 += p0; l1 += p1; l2 += p2; l3 += p3;
            PU pu;
            pu.h2[0] = __builtin_amdgcn_cvt_pkrtz(p0, p1);
            pu.h2[1] = __builtin_amdgcn_cvt_pkrtz(p2, p3);
            half4v va = *(const half4v*)&vt[lm * VTS + key0 + lg * 4];
            acc = __builtin_amdgcn_mfma_f32_16x16x16f16(va, pu.h4, acc, 0, 0, 0);
        }
        float lsum = (l0 + l1) + (l2 + l3);
        lsum += __shfl_xor(lsum, 16);
        lsum += __shfl_xor(lsum, 32);
        if (lg < 2) {
            float inv = 1.f / lsum;
            int rowg = half_ * 256 + qrow0 + lm;
            PU o2;
            o2.h2[0] = __builtin_amdgcn_cvt_pkrtz(acc[0] * inv, acc[1] * inv);
            o2.h2[1] = __builtin_amdgcn_cvt_pkrtz(acc[2] * inv, acc[3] * inv);
            *(half4v*)(obh + ((size_t)(bt * 512 + rowg)) * 64 + head * 8 + lg * 4) = o2.h4;
        }
    }
}

// ---------------- merged diffusion: z=0: x1=A^T r; z=1: x2=(A^T)^2 r  (reads h directly) ----------------
__global__ __launch_bounds__(256) void k_diffx2(const half_t* __restrict__ adjTh,
                                                const half_t* __restrict__ adjT2h,
                                                const float* __restrict__ h,
                                                half_t* __restrict__ x1h,
                                                half_t* __restrict__ x2h) {
    __shared__ half_t a_t[64 * ATS];   // [w-local][v-local]
    __shared__ half_t b_t[64 * BTS];   // [c-local][v-local]
    int tid = threadIdx.x;
    int wave = tid >> 6, lane = tid & 63;
    int lm = lane & 15, lg = lane >> 4;
    int w0 = blockIdx.x * 64;
    int bt = blockIdx.y;
    const half_t* A = blockIdx.z ? adjT2h : adjTh;
    half_t* outb = blockIdx.z ? x2h : x1h;
    const f32x4 zc = {0.f, 0.f, 0.f, 0.f};
    f32x4 acc[4] = {zc, zc, zc, zc};

    for (int kc = 0; kc < 8; ++kc) {
#pragma unroll
        for (int i = 0; i < 2; ++i) {
            int g = tid + i * 256;
            int r = g >> 3, s = g & 7;
            *(float4*)&a_t[r * ATS + s * 8] =
                *(const float4*)(A + (size_t)(w0 + r) * 512 + kc * 64 + s * 8);
        }
#pragma unroll
        for (int i = 0; i < 4; ++i) {
            int g = tid + i * 256;
            int vr = g >> 4, q = g & 15;
            float4 a = *(const float4*)(h + ((size_t)(bt * 512 + kc * 64 + vr)) * 64 + 4 * q);
            b_t[(4 * q + 0) * BTS + vr] = (half_t)a.x;
            b_t[(4 * q + 1) * BTS + vr] = (half_t)a.y;
            b_t[(4 * q + 2) * BTS + vr] = (half_t)a.z;
            b_t[(4 * q + 3) * BTS + vr] = (half_t)a.w;
        }
        __syncthreads();
#pragma unroll
        for (int k16 = 0; k16 < 4; ++k16) {
            half4v af = *(const half4v*)&a_t[(wave * 16 + lm) * ATS + k16 * 16 + lg * 4];
#pragma unroll
            for (int nt = 0; nt < 4; ++nt) {
                half4v bf = *(const half4v*)&b_t[(nt * 16 + lm) * BTS + k16 * 16 + lg * 4];
                acc[nt] = __builtin_amdgcn_mfma_f32_16x16x16f16(af, bf, acc[nt], 0, 0, 0);
            }
        }
        __syncthreads();
    }
    // out[(w*48+bt)*64 + c] = w*3072 + bt*64 + c
#pragma unroll
    for (int nt = 0; nt < 4; ++nt)
#pragma unroll
        for (int r = 0; r < 4; ++r)
            outb[(size_t)(w0 + wave * 16 + lg * 4 + r) * 3072 + bt * 64 + nt * 16 + lm] =
                (half_t)acc[nt][r];
}

// ---------------- MFMA gcn -> gout (incl. bias); reads h (residual) + f16 x1/x2 ----------------
__global__ __launch_bounds__(256) void k_gcn(const float* __restrict__ h,
                                             const half_t* __restrict__ x1h,
                                             const half_t* __restrict__ x2h,
                                             const half_t* __restrict__ Wh,
                                             const float* __restrict__ bias,
                                             float* __restrict__ gout) {
    __shared__ half_t a_t[64 * ATS];   // [row-local][c]
    __shared__ half_t b_t[64 * BTS];   // [o][c]
    int tid = threadIdx.x;
    int wave = tid >> 6, lane = tid & 63;
    int lm = lane & 15, lg = lane >> 4;
    int row0 = blockIdx.x * 64;                       // row = v*48+bt
    const f32x4 zc = {0.f, 0.f, 0.f, 0.f};
    f32x4 acc[4] = {zc, zc, zc, zc};

    for (int ch = 0; ch < 3; ++ch) {
        if (ch == 0) {
            // residual from h: row = v*48+bt -> h[(bt*512+v)*64+c]
#pragma unroll
            for (int i = 0; i < 4; ++i) {
                int g = tid + i * 256;
                int r = g >> 4, q = g & 15;
                int rowg = row0 + r;
                int v = rowg / 48, bt = rowg - v * 48;
                float4 a = *(const float4*)(h + ((size_t)(bt * 512 + v)) * 64 + 4 * q);
                PU ua;
                ua.h2[0] = __builtin_amdgcn_cvt_pkrtz(a.x, a.y);
                ua.h2[1] = __builtin_amdgcn_cvt_pkrtz(a.z, a.w);
                *(half4v*)&a_t[r * ATS + 4 * q] = ua.h4;
            }
        } else {
            const half_t* X = (ch == 1) ? x1h : x2h;
#pragma unroll
            for (int i = 0; i < 2; ++i) {
                int g = tid + i * 256;
                int r = g >> 3, s = g & 7;
                *(float4*)&a_t[r * ATS + s * 8] =
                    *(const float4*)(X + (size_t)(row0 + r) * 64 + s * 8);
            }
        }
#pragma unroll
        for (int i = 0; i < 4; ++i) {
            int g = tid + i * 256;
            int r = g >> 4, q = g & 15;
            *(half4v*)&b_t[r * BTS + 4 * q] =
                *(const half4v*)(Wh + (size_t)r * 192 + ch * 64 + 4 * q);
        }
        __syncthreads();
#pragma unroll
        for (int k16 = 0; k16 < 4; ++k16) {
            half4v af = *(const half4v*)&a_t[(wave * 16 + lm) * ATS + k16 * 16 + lg * 4];
#pragma unroll
            for (int nt = 0; nt < 4; ++nt) {
                half4v bf = *(const half4v*)&b_t[(nt * 16 + lm) * BTS + k16 * 16 + lg * 4];
                acc[nt] = __builtin_amdgcn_mfma_f32_16x16x16f16(bf, af, acc[nt], 0, 0, 0);
            }
        }
        __syncthreads();
    }
    int row = row0 + wave * 16 + lm;
    int v = row / 48, bt = row - v * 48;
    float* gp = gout + ((size_t)(bt * 512 + v)) * 64;
#pragma unroll
    for (int nt = 0; nt < 4; ++nt) {
        float4 bb = *(const float4*)(bias + nt * 16 + lg * 4);
        *(float4*)(gp + nt * 16 + lg * 4) =
            make_float4(acc[nt][0] + bb.x, acc[nt][1] + bb.y,
                        acc[nt][2] + bb.z, acc[nt][3] + bb.w);
    }
}

// ---------------- fused proj + LN + FF + gout add (MFMA, f16 weights + prefetch) ----------------
__global__ __launch_bounds__(128) void k_plf(const half_t* __restrict__ obh,
                                             const half_t* __restrict__ pwh,
                                             const float* __restrict__ pb,
                                             const float* __restrict__ g,
                                             const float* __restrict__ bln,
                                             const half_t* __restrict__ w1h,
                                             const float* __restrict__ b1,
                                             const half_t* __restrict__ w2h,
                                             const float* __restrict__ b2,
                                             const float* __restrict__ gout,
                                             float* __restrict__ h) {
    int wid = blockIdx.x * 2 + (threadIdx.x >> 6);    // 0..1535
    int lane = threadIdx.x & 63;
    int lm = lane & 15, lg = lane >> 4;
    int row = wid * 16 + lm;
    const f32x4 zc = {0.f, 0.f, 0.f, 0.f};

    half4v pf[4];
#pragma unroll
    for (int kc = 0; kc < 4; ++kc)
        pf[kc] = *(const half4v*)(pwh + (size_t)lm * 64 + kc * 16 + lg * 4);

    half4v of[4];
#pragma unroll
    for (int kc = 0; kc < 4; ++kc) {
        F2H u;
        u.f2 = *(const float2*)(obh + (size_t)row * 64 + kc * 16 + lg * 4);
        of[kc] = u.h4;
    }

    f32x4 hp[4];
#pragma unroll
    for (int nt = 0; nt < 4; ++nt) {
        half4v cw[4];
#pragma unroll
        for (int kc = 0; kc < 4; ++kc) cw[kc] = pf[kc];
        if (nt < 3) {
#pragma unroll
            for (int kc = 0; kc < 4; ++kc)
                pf[kc] = *(const half4v*)(pwh + (size_t)((nt + 1) * 16 + lm) * 64 + kc * 16 + lg * 4);
        }
        f32x4 c = zc;
#pragma unroll
        for (int kc = 0; kc < 4; ++kc)
            c = __builtin_amdgcn_mfma_f32_16x16x16f16(cw[kc], of[kc], c, 0, 0, 0);
        float4 ho = *(const float4*)(h + (size_t)row * 64 + nt * 16 + lg * 4);
        float4 bb = *(const float4*)(pb + nt * 16 + lg * 4);
        hp[nt][0] = c[0] + ho.x + bb.x;
        hp[nt][1] = c[1] + ho.y + bb.y;
        hp[nt][2] = c[2] + ho.z + bb.z;
        hp[nt][3] = c[3] + ho.w + bb.w;
    }

    float s = 0.f, s2 = 0.f;
#pragma unroll
    for (int nt = 0; nt < 4; ++nt)
#pragma unroll
        for (int r = 0; r < 4; ++r) {
            s += hp[nt][r];
            s2 += hp[nt][r] * hp[nt][r];
        }
    s += __shfl_xor(s, 16);  s2 += __shfl_xor(s2, 16);
    s += __shfl_xor(s, 32);  s2 += __shfl_xor(s2, 32);
    float mean = s * (1.f / 64.f);
    float var = s2 * (1.f / 64.f) - mean * mean;
    float rstd = rsqrtf(var + 1e-5f);

    half4v xf[4];
#pragma unroll
    for (int nt = 0; nt < 4; ++nt) {
        float4 gg = *(const float4*)(g + nt * 16 + lg * 4);
        float4 bb = *(const float4*)(bln + nt * 16 + lg * 4);
        float y0 = (hp[nt][0] - mean) * rstd * gg.x + bb.x;
        float y1 = (hp[nt][1] - mean) * rstd * gg.y + bb.y;
        float y2 = (hp[nt][2] - mean) * rstd * gg.z + bb.z;
        float y3 = (hp[nt][3] - mean) * rstd * gg.w + bb.w;
        PU u;
        u.h2[0] = __builtin_amdgcn_cvt_pkrtz(y0, y1);
        u.h2[1] = __builtin_amdgcn_cvt_pkrtz(y2, y3);
        xf[nt] = u.h4;
    }

    half4v w1f[4];
#pragma unroll
    for (int kc = 0; kc < 4; ++kc)
        w1f[kc] = *(const half4v*)(w1h + (size_t)lm * 64 + kc * 16 + lg * 4);

    f32x4 acc[4] = {zc, zc, zc, zc};
#pragma unroll 4
    for (int ht = 0; ht < 16; ++ht) {
        half4v cw[4];
#pragma unroll
        for (int kc = 0; kc < 4; ++kc) cw[kc] = w1f[kc];
        half4v w2f[4];
#pragma unroll
        for (int ot = 0; ot < 4; ++ot)
            w2f[ot] = *(const half4v*)(w2h + (size_t)(ot * 16 + lm) * 256 + ht * 16 + lg * 4);
        if (ht < 15) {
#pragma unroll
            for (int kc = 0; kc < 4; ++kc)
                w1f[kc] = *(const half4v*)(w1h + (size_t)((ht + 1) * 16 + lm) * 64 + kc * 16 + lg * 4);
        }
        f32x4 c1 = zc;
#pragma unroll
        for (int kc = 0; kc < 4; ++kc)
            c1 = __builtin_amdgcn_mfma_f32_16x16x16f16(cw[kc], xf[kc], c1, 0, 0, 0);
        float4 bb = *(const float4*)(b1 + ht * 16 + lg * 4);
        float y0 = c1[0] + bb.x;
        float y1 = c1[1] + bb.y;
        float y2 = c1[2] + bb.z;
        float y3 = c1[3] + bb.w;
        y0 = 0.5f * y0 * (1.0f + erff(y0 * 0.70710678118654752f));
        y1 = 0.5f * y1 * (1.0f + erff(y1 * 0.70710678118654752f));
        y2 = 0.5f * y2 * (1.0f + erff(y2 * 0.70710678118654752f));
        y3 = 0.5f * y3 * (1.0f + erff(y3 * 0.70710678118654752f));
        PU p;
        p.h2[0] = __builtin_amdgcn_cvt_pkrtz(y0, y1);
        p.h2[1] = __builtin_amdgcn_cvt_pkrtz(y2, y3);
#pragma unroll
        for (int ot = 0; ot < 4; ++ot)
            acc[ot] = __builtin_amdgcn_mfma_f32_16x16x16f16(w2f[ot], p.h4, acc[ot], 0, 0, 0);
    }

#pragma unroll
    for (int ot = 0; ot < 4; ++ot) {
        float4 bb = *(const float4*)(b2 + ot * 16 + lg * 4);
        float4 gv = *(const float4*)(gout + (size_t)row * 64 + ot * 16 + lg * 4);
        *(float4*)(h + (size_t)row * 64 + ot * 16 + lg * 4) =
            make_float4(hp[ot][0] + acc[ot][0] + bb.x + gv.x,
                        hp[ot][1] + acc[ot][1] + bb.y + gv.y,
                        hp[ot][2] + acc[ot][2] + bb.z + gv.z,
                        hp[ot][3] + acc[ot][3] + bb.w + gv.w);
    }
}

// ---------------- final: out[b,c,v,t] = h[(b*12+t)*512+v][c] ----------------
__global__ __launch_bounds__(256) void k_out(const float* __restrict__ h,
                                             float* __restrict__ out) {
    int i = blockIdx.x * 256 + threadIdx.x;
    int t = i % 12;
    int r = i / 12;
    int v = r & 511;
    int r2 = r >> 9;
    int c = r2 & 63;
    int b = r2 >> 6;
    out[i] = h[(((size_t)(b * 12 + t) * 512) + v) * 64 + c];
}

extern "C" void kernel_launch(void* const* d_in, const int* in_sizes, int n_in,
                              void* d_out, int out_size, void* d_ws, size_t ws_size,
                              hipStream_t stream) {
    const float* x      = (const float*)d_in[0];
    const float* adj    = (const float*)d_in[1];
    const float* pos    = (const float*)d_in[2];
    const float* qkv_w  = (const float*)d_in[3];
    const float* proj_w = (const float*)d_in[4];
    const float* proj_b = (const float*)d_in[5];
    const float* ln_g   = (const float*)d_in[6];
    const float* ln_b   = (const float*)d_in[7];
    const float* ff_w1  = (const float*)d_in[8];
    const float* ff_b1  = (const float*)d_in[9];
    const float* ff_w2  = (const float*)d_in[10];
    const float* ff_b2  = (const float*)d_in[11];
    const float* gcn_w  = (const float*)d_in[12];
    const float* gcn_b  = (const float*)d_in[13];
    float* out = (float*)d_out;

    const size_t SZ = 1572864;  // 48*512*64
    float* h    = (float*)d_ws;
    float* gout = h + SZ;
    half_t* x1h = (half_t*)(gout + SZ);
    half_t* x2h = x1h + SZ;
    half_t* qh  = x2h + SZ;
    half_t* kh  = qh + SZ;
    half_t* vh  = kh + SZ;
    half_t* obh = vh + SZ;
    half_t* adjTh  = obh + SZ;        // 262144
    half_t* adjT2h = adjTh + 262144;  // 262144
    half_t* wh     = adjT2h + 262144; // 122880
    half_t* qkv_wh  = wh;
    half_t* proj_wh = wh + 24576;
    half_t* ff_w1h  = wh + 32768;
    half_t* ff_w2h  = wh + 65536;
    half_t* gcn_wh  = wh + 98304;

    k_init<<<6144, 256, 0, stream>>>(x, pos, h);
    k_adjt<<<dim3(8, 8), 256, 0, stream>>>(adj, adjTh);
    k_prep<<<480, 256, 0, stream>>>(qkv_w, proj_w, ff_w1, ff_w2, gcn_w, wh);
    k_adj2<<<dim3(8, 8), 256, 0, stream>>>(adjTh, adjT2h);
    for (int l = 0; l < 2; ++l) {
        k_qkv<<<768, 128, 0, stream>>>(h, qkv_wh + l * 12288, qh, kh, vh);
        k_attn<<<768, 512, 0, stream>>>(qh, kh, vh, obh);
        k_diffx2<<<dim3(8, 48, 2), 256, 0, stream>>>(adjTh, adjT2h, h, x1h, x2h);
        k_gcn<<<384, 256, 0, stream>>>(h, x1h, x2h, gcn_wh + l * 12288, gcn_b + l * 64, gout);
        k_plf<<<768, 128, 0, stream>>>(obh, proj_wh + l * 4096, proj_b + l * 64,
                                       ln_g + l * 64, ln_b + l * 64,
                                       ff_w1h + l * 16384, ff_b1 + l * 256,
                                       ff_w2h + l * 16384, ff_b2 + l * 64, gout, h);
    }
    k_out<<<6144, 256, 0, stream>>>(h, out);
}

// Round 15
// 287.997 us; speedup vs baseline: 1.4186x; 1.1133x over previous
//
#include <hip/hip_runtime.h>
#include <math.h>

// Sizes: b=4, t=12 (BT=48), n=512, c=64, heads=8, hd=8, FF hidden=256, depth=2

typedef __fp16 half_t;
typedef __attribute__((ext_vector_type(2))) __fp16 half2v;
typedef __attribute__((ext_vector_type(4))) __fp16 half4v;
typedef __attribute__((ext_vector_type(4))) float f32x4;

union PU  { half2v h2[2]; half4v h4; };
union F4H { float4 f; half4v h[2]; };
union F2H { float2 f2; half4v h4; };

#define ATS 72
#define BTS 68
#define KLS 20
#define QLS 20
#define VTS 516

// ---------------- merged prologue: init-transpose | adjt | weight-prep ----------------
__global__ __launch_bounds__(256) void k_pre(const float* __restrict__ x,
                                             const float* __restrict__ pos,
                                             const float* __restrict__ adj,
                                             const float* __restrict__ qkv_w,
                                             const float* __restrict__ proj_w,
                                             const float* __restrict__ ff_w1,
                                             const float* __restrict__ ff_w2,
                                             const float* __restrict__ gcn_w,
                                             float* __restrict__ h,
                                             half_t* __restrict__ adjTh,
                                             half_t* __restrict__ wh) {
    __shared__ float t[64 * 65];
    int tid = threadIdx.x;
    int bidx = blockIdx.x;
    if (bidx < 384) {
        int b = bidx / 96, vt0 = (bidx % 96) * 64;
#pragma unroll
        for (int i = 0; i < 4; ++i) {
            int g = tid + i * 256;
            int r = g >> 4, q = g & 15;           // r = c-local, 4q = vt-local
            *(float4*)&t[r * 65 + 4 * q] =
                *(const float4*)(x + ((size_t)(b * 64 + r)) * 6144 + vt0 + 4 * q);
        }
        __syncthreads();
#pragma unroll
        for (int i = 0; i < 4; ++i) {
            int g = tid + i * 256;
            int r = g >> 4, q = g & 15;           // r = vt-local, 4q = c
            int vt = vt0 + r;
            int v = vt / 12, tt = vt - v * 12;
            float4 pv = *(const float4*)(pos + v * 64 + 4 * q);
            float4 o;
            o.x = t[(4 * q + 0) * 65 + r] + pv.x;
            o.y = t[(4 * q + 1) * 65 + r] + pv.y;
            o.z = t[(4 * q + 2) * 65 + r] + pv.z;
            o.w = t[(4 * q + 3) * 65 + r] + pv.w;
            *(float4*)(h + ((size_t)((b * 12 + tt) * 512 + v)) * 64 + 4 * q) = o;
        }
    } else if (bidx < 448) {
        int fb = bidx - 384;
        int v0 = (fb & 7) * 64, w0 = (fb >> 3) * 64;
#pragma unroll
        for (int i = 0; i < 4; ++i) {
            int g = tid + i * 256;
            int r = g >> 4, q = g & 15;
            float4 a = *(const float4*)(adj + (size_t)(v0 + r) * 512 + w0 + 4 * q);
            t[(4 * q + 0) * 65 + r] = a.x;
            t[(4 * q + 1) * 65 + r] = a.y;
            t[(4 * q + 2) * 65 + r] = a.z;
            t[(4 * q + 3) * 65 + r] = a.w;
        }
        __syncthreads();
#pragma unroll
        for (int i = 0; i < 4; ++i) {
            int g = tid + i * 256;
            int rw = g >> 4, q = g & 15;
            const float* src = &t[rw * 65 + 4 * q];
            PU u;
            u.h2[0] = __builtin_amdgcn_cvt_pkrtz(src[0], src[1]);
            u.h2[1] = __builtin_amdgcn_cvt_pkrtz(src[2], src[3]);
            *(half4v*)(adjTh + (size_t)(w0 + rw) * 512 + v0 + 4 * q) = u.h4;
        }
    } else {
        int i = (bidx - 448) * 256 + tid;
        float v;
        if (i < 24576) v = qkv_w[i];
        else if (i < 32768) v = proj_w[i - 24576];
        else if (i < 65536) v = ff_w1[i - 32768];
        else if (i < 98304) v = ff_w2[i - 65536];
        else v = gcn_w[i - 98304];
        wh[i] = (half_t)v;
    }
}

// ---------------- one-time: adjT2h = adjTh @ adjTh ----------------
__global__ __launch_bounds__(256) void k_adj2(const half_t* __restrict__ adjTh,
                                              half_t* __restrict__ adjT2h) {
    __shared__ half_t a_t[64 * ATS];
    __shared__ half_t b_t[64 * BTS];
    int tid = threadIdx.x;
    int wave = tid >> 6, lane = tid & 63;
    int lm = lane & 15, lg = lane >> 4;
    int w0 = blockIdx.x * 64, v0 = blockIdx.y * 64;
    const f32x4 zc = {0.f, 0.f, 0.f, 0.f};
    f32x4 acc[4] = {zc, zc, zc, zc};

    for (int kc = 0; kc < 8; ++kc) {
#pragma unroll
        for (int i = 0; i < 2; ++i) {
            int g = tid + i * 256;
            int r = g >> 3, s = g & 7;
            *(float4*)&a_t[r * ATS + s * 8] =
                *(const float4*)(adjTh + (size_t)(w0 + r) * 512 + kc * 64 + s * 8);
        }
#pragma unroll
        for (int i = 0; i < 2; ++i) {
            int g = tid + i * 256;
            int ur = g >> 3, s = g & 7;
            F4H u;
            u.f = *(const float4*)(adjTh + (size_t)(kc * 64 + ur) * 512 + v0 + s * 8);
#pragma unroll
            for (int e = 0; e < 8; ++e)
                b_t[(s * 8 + e) * BTS + ur] = u.h[e >> 2][e & 3];
        }
        __syncthreads();
#pragma unroll
        for (int k16 = 0; k16 < 4; ++k16) {
            half4v af = *(const half4v*)&a_t[(wave * 16 + lm) * ATS + k16 * 16 + lg * 4];
#pragma unroll
            for (int nt = 0; nt < 4; ++nt) {
                half4v bf = *(const half4v*)&b_t[(nt * 16 + lm) * BTS + k16 * 16 + lg * 4];
                acc[nt] = __builtin_amdgcn_mfma_f32_16x16x16f16(af, bf, acc[nt], 0, 0, 0);
            }
        }
        __syncthreads();
    }
#pragma unroll
    for (int nt = 0; nt < 4; ++nt)
#pragma unroll
        for (int r = 0; r < 4; ++r)
            adjT2h[(size_t)(w0 + wave * 16 + lg * 4 + r) * 512 + v0 + nt * 16 + lm] =
                (half_t)acc[nt][r];
}

// ---------------- merged: qkv (blocks 0..383) | diffx2 (blocks 384..1151) ----------------
__global__ __launch_bounds__(256) void k_qd(const float* __restrict__ h,
                                            const half_t* __restrict__ Wh,
                                            half_t* __restrict__ qh,
                                            half_t* __restrict__ kh,
                                            half_t* __restrict__ vh,
                                            const half_t* __restrict__ adjTh,
                                            const half_t* __restrict__ adjT2h,
                                            half_t* __restrict__ x1h,
                                            half_t* __restrict__ x2h) {
    __shared__ __align__(16) half_t sbuf[64 * ATS + 64 * BTS];
    int tid = threadIdx.x;
    int bidx = blockIdx.x;
    int wave = tid >> 6, lane = tid & 63;
    int lm = lane & 15, lg = lane >> 4;
    const f32x4 zc = {0.f, 0.f, 0.f, 0.f};

    if (bidx < 384) {
        int wid = bidx * 4 + wave;
        int row = wid * 16 + lm;
        half4v xf[4];
#pragma unroll
        for (int kc = 0; kc < 4; ++kc) {
            float4 a = *(const float4*)(h + (size_t)row * 64 + kc * 16 + lg * 4);
            PU u;
            u.h2[0] = __builtin_amdgcn_cvt_pkrtz(a.x, a.y);
            u.h2[1] = __builtin_amdgcn_cvt_pkrtz(a.z, a.w);
            xf[kc] = u.h4;
        }
        const float SC = 0.35355339059327373f * 1.4426950408889634f;
        int bt = row >> 9, v = row & 511;
        half4v wf[4];
#pragma unroll
        for (int kc = 0; kc < 4; ++kc)
            wf[kc] = *(const half4v*)(Wh + (size_t)lm * 64 + kc * 16 + lg * 4);
#pragma unroll
        for (int nt = 0; nt < 12; ++nt) {
            half4v cw[4];
#pragma unroll
            for (int kc = 0; kc < 4; ++kc) cw[kc] = wf[kc];
            if (nt < 11) {
#pragma unroll
                for (int kc = 0; kc < 4; ++kc)
                    wf[kc] = *(const half4v*)(Wh + (size_t)((nt + 1) * 16 + lm) * 64 + kc * 16 + lg * 4);
            }
            f32x4 acc = zc;
#pragma unroll
            for (int kc = 0; kc < 4; ++kc)
                acc = __builtin_amdgcn_mfma_f32_16x16x16f16(cw[kc], xf[kc], acc, 0, 0, 0);
            int s = nt >> 2;
            if (s == 0) { acc[0] *= SC; acc[1] *= SC; acc[2] *= SC; acc[3] *= SC; }
            int head = ((nt & 3) << 1) + (lg >> 1);
            int d0 = (lg & 1) * 4;
            PU o2;
            o2.h2[0] = __builtin_amdgcn_cvt_pkrtz(acc[0], acc[1]);
            o2.h2[1] = __builtin_amdgcn_cvt_pkrtz(acc[2], acc[3]);
            half_t* dst = (s == 0) ? qh : ((s == 1) ? kh : vh);
            *(half4v*)(dst + ((size_t)(bt * 8 + head) * 512 + v) * 8 + d0) = o2.h4;
        }
    } else {
        half_t* a_t = sbuf;
        half_t* b_t = sbuf + 64 * ATS;
        int fb = bidx - 384;
        int z = fb / 384, rem = fb - z * 384;
        int w0 = (rem & 7) * 64;
        int bt = rem >> 3;
        const half_t* A = z ? adjT2h : adjTh;
        half_t* outb = z ? x2h : x1h;
        f32x4 acc[4] = {zc, zc, zc, zc};
        for (int kc = 0; kc < 8; ++kc) {
#pragma unroll
            for (int i = 0; i < 2; ++i) {
                int g = tid + i * 256;
                int r = g >> 3, s = g & 7;
                *(float4*)&a_t[r * ATS + s * 8] =
                    *(const float4*)(A + (size_t)(w0 + r) * 512 + kc * 64 + s * 8);
            }
#pragma unroll
            for (int i = 0; i < 4; ++i) {
                int g = tid + i * 256;
                int vr = g >> 4, q = g & 15;
                float4 a = *(const float4*)(h + ((size_t)(bt * 512 + kc * 64 + vr)) * 64 + 4 * q);
                b_t[(4 * q + 0) * BTS + vr] = (half_t)a.x;
                b_t[(4 * q + 1) * BTS + vr] = (half_t)a.y;
                b_t[(4 * q + 2) * BTS + vr] = (half_t)a.z;
                b_t[(4 * q + 3) * BTS + vr] = (half_t)a.w;
            }
            __syncthreads();
#pragma unroll
            for (int k16 = 0; k16 < 4; ++k16) {
                half4v af = *(const half4v*)&a_t[(wave * 16 + lm) * ATS + k16 * 16 + lg * 4];
#pragma unroll
                for (int nt = 0; nt < 4; ++nt) {
                    half4v bf = *(const half4v*)&b_t[(nt * 16 + lm) * BTS + k16 * 16 + lg * 4];
                    acc[nt] = __builtin_amdgcn_mfma_f32_16x16x16f16(af, bf, acc[nt], 0, 0, 0);
                }
            }
            __syncthreads();
        }
#pragma unroll
        for (int nt = 0; nt < 4; ++nt)
#pragma unroll
            for (int r = 0; r < 4; ++r)
                outb[(size_t)(w0 + wave * 16 + lg * 4 + r) * 3072 + bt * 64 + nt * 16 + lm] =
                    (half_t)acc[nt][r];
    }
}

// ---------------- merged: attn (blocks 0..767) | gcn (blocks 768..1151) ----------------
__global__ __launch_bounds__(512) void k_ag(const half_t* __restrict__ qh,
                                            const half_t* __restrict__ kh,
                                            const half_t* __restrict__ vh,
                                            half_t* __restrict__ obh,
                                            const float* __restrict__ h,
                                            const half_t* __restrict__ x1h,
                                            const half_t* __restrict__ x2h,
                                            const half_t* __restrict__ Wh,
                                            const float* __restrict__ bias,
                                            float* __restrict__ gout) {
    __shared__ __align__(16) half_t sbuf[512 * KLS + 16 * VTS + 256 * QLS];  // 47232 B
    int tid = threadIdx.x;
    int bidx = blockIdx.x;
    const half4v zero4 = {(__fp16)0.f, (__fp16)0.f, (__fp16)0.f, (__fp16)0.f};
    const f32x4 zc = {0.f, 0.f, 0.f, 0.f};

    if (bidx < 768) {
        // ---- attention ----
        half_t* kl = sbuf;
        half_t* vt = sbuf + 512 * KLS;
        half_t* ql = sbuf + 512 * KLS + 16 * VTS;
        int bh = bidx >> 1;
        int half_ = bidx & 1;
        const half_t* kbase = kh + (size_t)bh * 4096;
        const half_t* vbase = vh + (size_t)bh * 4096;
        const half_t* qbase = qh + (size_t)bh * 4096 + half_ * 2048;

        if (tid < 256) {
#pragma unroll
            for (int kk = 0; kk < 2; ++kk) {
                int key = tid * 2 + kk;
                F4H u;
                u.f = *(const float4*)(kbase + key * 8);
                half4v* rowp = (half4v*)&kl[key * KLS];
                rowp[0] = u.h[0];
                rowp[1] = u.h[1];
                rowp[2] = zero4;
                rowp[3] = zero4;
            }
            {
                F4H u;
                u.f = *(const float4*)(qbase + tid * 8);
                half4v* rowp = (half4v*)&ql[tid * QLS];
                rowp[0] = u.h[0];
                rowp[1] = u.h[1];
                rowp[2] = zero4;
                rowp[3] = zero4;
            }
            {
                int k0 = tid * 2;
                F4H a, b;
                a.f = *(const float4*)(vbase + k0 * 8);
                b.f = *(const float4*)(vbase + k0 * 8 + 8);
#pragma unroll
                for (int d = 0; d < 8; ++d) {
                    half2v p = {a.h[d >> 2][d & 3], b.h[d >> 2][d & 3]};
                    *(half2v*)&vt[d * VTS + k0] = p;
                }
            }
        }
        for (int i = tid; i < 1032; i += 512)
            ((half4v*)(vt + 8 * VTS))[i] = zero4;
        __syncthreads();

        int wave = tid >> 6, lane = tid & 63;
        int lm = lane & 15, lg = lane >> 4;
        int bt = bh >> 3, head = bh & 7;

#pragma unroll 1
        for (int st = 0; st < 2; ++st) {
            int qrow0 = wave * 32 + st * 16;
            half4v qf = *(const half4v*)&ql[(qrow0 + lm) * QLS + lg * 4];
            f32x4 acc = zc;
            float l0 = 0.f, l1 = 0.f, l2 = 0.f, l3 = 0.f;
#pragma unroll 4
            for (int kt = 0; kt < 32; ++kt) {
                int key0 = kt * 16;
                half4v ka = *(const half4v*)&kl[(key0 + lm) * KLS + lg * 4];
                f32x4 c1 = __builtin_amdgcn_mfma_f32_16x16x16f16(ka, qf, zc, 0, 0, 0);
                float p0 = exp2f(fminf(c1[0], 12.f));
                float p1 = exp2f(fminf(c1[1], 12.f));
                float p2 = exp2f(fminf(c1[2], 12.f));
                float p3 = exp2f(fminf(c1[3], 12.f));
                l0 += p0; l1 += p1; l2 += p2; l3 += p3;
                PU pu;
                pu.h2[0] = __builtin_amdgcn_cvt_pkrtz(p0, p1);
                pu.h2[1] = __builtin_amdgcn_cvt_pkrtz(p2, p3);
                half4v va = *(const half4v*)&vt[lm * VTS + key0 + lg * 4];
                acc = __builtin_amdgcn_mfma_f32_16x16x16f16(va, pu.h4, acc, 0, 0, 0);
            }
            float lsum = (l0 + l1) + (l2 + l3);
            lsum += __shfl_xor(lsum, 16);
            lsum += __shfl_xor(lsum, 32);
            if (lg < 2) {
                float inv = 1.f / lsum;
                int rowg = half_ * 256 + qrow0 + lm;
                PU o2;
                o2.h2[0] = __builtin_amdgcn_cvt_pkrtz(acc[0] * inv, acc[1] * inv);
                o2.h2[1] = __builtin_amdgcn_cvt_pkrtz(acc[2] * inv, acc[3] * inv);
                *(half4v*)(obh + ((size_t)(bt * 512 + rowg)) * 64 + head * 8 + lg * 4) = o2.h4;
            }
        }
    } else {
        // ---- gcn (256 active threads; barriers at block-uniform points) ----
        half_t* a_t = sbuf;
        half_t* b_t = sbuf + 64 * ATS;
        int row0 = (bidx - 768) * 64;                 // row = v*48+bt
        int wave = tid >> 6, lane = tid & 63;
        int lm = lane & 15, lg = lane >> 4;
        f32x4 acc[4] = {zc, zc, zc, zc};

        for (int ch = 0; ch < 3; ++ch) {
            if (tid < 256) {
                if (ch == 0) {
#pragma unroll
                    for (int i = 0; i < 4; ++i) {
                        int g = tid + i * 256;
                        int r = g >> 4, q = g & 15;
                        int rowg = row0 + r;
                        int v = rowg / 48, bt = rowg - v * 48;
                        float4 a = *(const float4*)(h + ((size_t)(bt * 512 + v)) * 64 + 4 * q);
                        PU ua;
                        ua.h2[0] = __builtin_amdgcn_cvt_pkrtz(a.x, a.y);
                        ua.h2[1] = __builtin_amdgcn_cvt_pkrtz(a.z, a.w);
                        *(half4v*)&a_t[r * ATS + 4 * q] = ua.h4;
                    }
                } else {
                    const half_t* X = (ch == 1) ? x1h : x2h;
#pragma unroll
                    for (int i = 0; i < 2; ++i) {
                        int g = tid + i * 256;
                        int r = g >> 3, s = g & 7;
                        *(float4*)&a_t[r * ATS + s * 8] =
                            *(const float4*)(X + (size_t)(row0 + r) * 64 + s * 8);
                    }
                }
#pragma unroll
                for (int i = 0; i < 4; ++i) {
                    int g = tid + i * 256;
                    int r = g >> 4, q = g & 15;
                    *(half4v*)&b_t[r * BTS + 4 * q] =
                        *(const half4v*)(Wh + (size_t)r * 192 + ch * 64 + 4 * q);
                }
            }
            __syncthreads();
            if (tid < 256) {
#pragma unroll
                for (int k16 = 0; k16 < 4; ++k16) {
                    half4v af = *(const half4v*)&a_t[(wave * 16 + lm) * ATS + k16 * 16 + lg * 4];
#pragma unroll
                    for (int nt = 0; nt < 4; ++nt) {
                        half4v bf = *(const half4v*)&b_t[(nt * 16 + lm) * BTS + k16 * 16 + lg * 4];
                        acc[nt] = __builtin_amdgcn_mfma_f32_16x16x16f16(bf, af, acc[nt], 0, 0, 0);
                    }
                }
            }
            __syncthreads();
        }
        if (tid < 256) {
            int row = row0 + wave * 16 + lm;
            int v = row / 48, bt = row - v * 48;
            float* gp = gout + ((size_t)(bt * 512 + v)) * 64;
#pragma unroll
            for (int nt = 0; nt < 4; ++nt) {
                float4 bb = *(const float4*)(bias + nt * 16 + lg * 4);
                *(float4*)(gp + nt * 16 + lg * 4) =
                    make_float4(acc[nt][0] + bb.x, acc[nt][1] + bb.y,
                                acc[nt][2] + bb.z, acc[nt][3] + bb.w);
            }
        }
    }
}

// ---------------- fused proj + LN + FF + gout add ----------------
__global__ __launch_bounds__(128) void k_plf(const half_t* __restrict__ obh,
                                             const half_t* __restrict__ pwh,
                                             const float* __restrict__ pb,
                                             const float* __restrict__ g,
                                             const float* __restrict__ bln,
                                             const half_t* __restrict__ w1h,
                                             const float* __restrict__ b1,
                                             const half_t* __restrict__ w2h,
                                             const float* __restrict__ b2,
                                             const float* __restrict__ gout,
                                             float* __restrict__ h) {
    int wid = blockIdx.x * 2 + (threadIdx.x >> 6);    // 0..1535
    int lane = threadIdx.x & 63;
    int lm = lane & 15, lg = lane >> 4;
    int row = wid * 16 + lm;
    const f32x4 zc = {0.f, 0.f, 0.f, 0.f};

    half4v pf[4];
#pragma unroll
    for (int kc = 0; kc < 4; ++kc)
        pf[kc] = *(const half4v*)(pwh + (size_t)lm * 64 + kc * 16 + lg * 4);

    half4v of[4];
#pragma unroll
    for (int kc = 0; kc < 4; ++kc) {
        F2H u;
        u.f2 = *(const float2*)(obh + (size_t)row * 64 + kc * 16 + lg * 4);
        of[kc] = u.h4;
    }

    f32x4 hp[4];
#pragma unroll
    for (int nt = 0; nt < 4; ++nt) {
        half4v cw[4];
#pragma unroll
        for (int kc = 0; kc < 4; ++kc) cw[kc] = pf[kc];
        if (nt < 3) {
#pragma unroll
            for (int kc = 0; kc < 4; ++kc)
                pf[kc] = *(const half4v*)(pwh + (size_t)((nt + 1) * 16 + lm) * 64 + kc * 16 + lg * 4);
        }
        f32x4 c = zc;
#pragma unroll
        for (int kc = 0; kc < 4; ++kc)
            c = __builtin_amdgcn_mfma_f32_16x16x16f16(cw[kc], of[kc], c, 0, 0, 0);
        float4 ho = *(const float4*)(h + (size_t)row * 64 + nt * 16 + lg * 4);
        float4 bb = *(const float4*)(pb + nt * 16 + lg * 4);
        hp[nt][0] = c[0] + ho.x + bb.x;
        hp[nt][1] = c[1] + ho.y + bb.y;
        hp[nt][2] = c[2] + ho.z + bb.z;
        hp[nt][3] = c[3] + ho.w + bb.w;
    }

    float s = 0.f, s2 = 0.f;
#pragma unroll
    for (int nt = 0; nt < 4; ++nt)
#pragma unroll
        for (int r = 0; r < 4; ++r) {
            s += hp[nt][r];
            s2 += hp[nt][r] * hp[nt][r];
        }
    s += __shfl_xor(s, 16);  s2 += __shfl_xor(s2, 16);
    s += __shfl_xor(s, 32);  s2 += __shfl_xor(s2, 32);
    float mean = s * (1.f / 64.f);
    float var = s2 * (1.f / 64.f) - mean * mean;
    float rstd = rsqrtf(var + 1e-5f);

    half4v xf[4];
#pragma unroll
    for (int nt = 0; nt < 4; ++nt) {
        float4 gg = *(const float4*)(g + nt * 16 + lg * 4);
        float4 bb = *(const float4*)(bln + nt * 16 + lg * 4);
        float y0 = (hp[nt][0] - mean) * rstd * gg.x + bb.x;
        float y1 = (hp[nt][1] - mean) * rstd * gg.y + bb.y;
        float y2 = (hp[nt][2] - mean) * rstd * gg.z + bb.z;
        float y3 = (hp[nt][3] - mean) * rstd * gg.w + bb.w;
        PU u;
        u.h2[0] = __builtin_amdgcn_cvt_pkrtz(y0, y1);
        u.h2[1] = __builtin_amdgcn_cvt_pkrtz(y2, y3);
        xf[nt] = u.h4;
    }

    half4v w1f[4];
#pragma unroll
    for (int kc = 0; kc < 4; ++kc)
        w1f[kc] = *(const half4v*)(w1h + (size_t)lm * 64 + kc * 16 + lg * 4);

    f32x4 acc[4] = {zc, zc, zc, zc};
#pragma unroll 4
    for (int ht = 0; ht < 16; ++ht) {
        half4v cw[4];
#pragma unroll
        for (int kc = 0; kc < 4; ++kc) cw[kc] = w1f[kc];
        half4v w2f[4];
#pragma unroll
        for (int ot = 0; ot < 4; ++ot)
            w2f[ot] = *(const half4v*)(w2h + (size_t)(ot * 16 + lm) * 256 + ht * 16 + lg * 4);
        if (ht < 15) {
#pragma unroll
            for (int kc = 0; kc < 4; ++kc)
                w1f[kc] = *(const half4v*)(w1h + (size_t)((ht + 1) * 16 + lm) * 64 + kc * 16 + lg * 4);
        }
        f32x4 c1 = zc;
#pragma unroll
        for (int kc = 0; kc < 4; ++kc)
            c1 = __builtin_amdgcn_mfma_f32_16x16x16f16(cw[kc], xf[kc], c1, 0, 0, 0);
        float4 bb = *(const float4*)(b1 + ht * 16 + lg * 4);
        float y0 = c1[0] + bb.x;
        float y1 = c1[1] + bb.y;
        float y2 = c1[2] + bb.z;
        float y3 = c1[3] + bb.w;
        y0 = 0.5f * y0 * (1.0f + erff(y0 * 0.70710678118654752f));
        y1 = 0.5f * y1 * (1.0f + erff(y1 * 0.70710678118654752f));
        y2 = 0.5f * y2 * (1.0f + erff(y2 * 0.70710678118654752f));
        y3 = 0.5f * y3 * (1.0f + erff(y3 * 0.70710678118654752f));
        PU p;
        p.h2[0] = __builtin_amdgcn_cvt_pkrtz(y0, y1);
        p.h2[1] = __builtin_amdgcn_cvt_pkrtz(y2, y3);
#pragma unroll
        for (int ot = 0; ot < 4; ++ot)
            acc[ot] = __builtin_amdgcn_mfma_f32_16x16x16f16(w2f[ot], p.h4, acc[ot], 0, 0, 0);
    }

#pragma unroll
    for (int ot = 0; ot < 4; ++ot) {
        float4 bb = *(const float4*)(b2 + ot * 16 + lg * 4);
        float4 gv = *(const float4*)(gout + (size_t)row * 64 + ot * 16 + lg * 4);
        *(float4*)(h + (size_t)row * 64 + ot * 16 + lg * 4) =
            make_float4(hp[ot][0] + acc[ot][0] + bb.x + gv.x,
                        hp[ot][1] + acc[ot][1] + bb.y + gv.y,
                        hp[ot][2] + acc[ot][2] + bb.z + gv.z,
                        hp[ot][3] + acc[ot][3] + bb.w + gv.w);
    }
}

// ---------------- final: out[b,c,v,t] = h[(b*12+t)*512+v][c]  (LDS-tiled transpose) ----------------
__global__ __launch_bounds__(256) void k_out(const float* __restrict__ h,
                                             float* __restrict__ out) {
    __shared__ float t[64 * 65];
    int tid = threadIdx.x;
    int b = blockIdx.x / 96, vt0 = (blockIdx.x % 96) * 64;
#pragma unroll
    for (int i = 0; i < 4; ++i) {
        int g = tid + i * 256;
        int r = g >> 4, q = g & 15;               // r = vt-local, 4q = c
        int vt = vt0 + r;
        int v = vt / 12, tt = vt - v * 12;
        *(float4*)&t[r * 65 + 4 * q] =
            *(const float4*)(h + ((size_t)((b * 12 + tt) * 512 + v)) * 64 + 4 * q);
    }
    __syncthreads();
#pragma unroll
    for (int i = 0; i < 4; ++i) {
        int g = tid + i * 256;
        int r = g >> 4, q = g & 15;               // r = c-local, 4q = vt-local
        float4 o;
        o.x = t[(4 * q + 0) * 65 + r];
        o.y = t[(4 * q + 1) * 65 + r];
        o.z = t[(4 * q + 2) * 65 + r];
        o.w = t[(4 * q + 3) * 65 + r];
        *(float4*)(out + ((size_t)(b * 64 + r)) * 6144 + vt0 + 4 * q) = o;
    }
}

extern "C" void kernel_launch(void* const* d_in, const int* in_sizes, int n_in,
                              void* d_out, int out_size, void* d_ws, size_t ws_size,
                              hipStream_t stream) {
    const float* x      = (const float*)d_in[0];
    const float* adj    = (const float*)d_in[1];
    const float* pos    = (const float*)d_in[2];
    const float* qkv_w  = (const float*)d_in[3];
    const float* proj_w = (const float*)d_in[4];
    const float* proj_b = (const float*)d_in[5];
    const float* ln_g   = (const float*)d_in[6];
    const float* ln_b   = (const float*)d_in[7];
    const float* ff_w1  = (const float*)d_in[8];
    const float* ff_b1  = (const float*)d_in[9];
    const float* ff_w2  = (const float*)d_in[10];
    const float* ff_b2  = (const float*)d_in[11];
    const float* gcn_w  = (const float*)d_in[12];
    const float* gcn_b  = (const float*)d_in[13];
    float* out = (float*)d_out;

    const size_t SZ = 1572864;  // 48*512*64
    float* h    = (float*)d_ws;
    float* gout = h + SZ;
    half_t* x1h = (half_t*)(gout + SZ);
    half_t* x2h = x1h + SZ;
    half_t* qh  = x2h + SZ;
    half_t* kh  = qh + SZ;
    half_t* vh  = kh + SZ;
    half_t* obh = vh + SZ;
    half_t* adjTh  = obh + SZ;        // 262144
    half_t* adjT2h = adjTh + 262144;  // 262144
    half_t* wh     = adjT2h + 262144; // 122880
    half_t* qkv_wh  = wh;
    half_t* proj_wh = wh + 24576;
    half_t* ff_w1h  = wh + 32768;
    half_t* ff_w2h  = wh + 65536;
    half_t* gcn_wh  = wh + 98304;

    k_pre<<<928, 256, 0, stream>>>(x, pos, adj, qkv_w, proj_w, ff_w1, ff_w2, gcn_w,
                                   h, adjTh, wh);
    k_adj2<<<dim3(8, 8), 256, 0, stream>>>(adjTh, adjT2h);
    for (int l = 0; l < 2; ++l) {
        k_qd<<<1152, 256, 0, stream>>>(h, qkv_wh + l * 12288, qh, kh, vh,
                                       adjTh, adjT2h, x1h, x2h);
        k_ag<<<1152, 512, 0, stream>>>(qh, kh, vh, obh, h, x1h, x2h,
                                       gcn_wh + l * 12288, gcn_b + l * 64, gout);
        k_plf<<<768, 128, 0, stream>>>(obh, proj_wh + l * 4096, proj_b + l * 64,
                                       ln_g + l * 64, ln_b + l * 64,
                                       ff_w1h + l * 16384, ff_b1 + l * 256,
                                       ff_w2h + l * 16384, ff_b2 + l * 64, gout, h);
    }
    k_out<<<384, 256, 0, stream>>>(h, out);
}

// Round 16
// 280.262 us; speedup vs baseline: 1.4578x; 1.0276x over previous
//
#include <hip/hip_runtime.h>
#include <math.h>

// Sizes: b=4, t=12 (BT=48), n=512, c=64, heads=8, hd=8, FF hidden=256, depth=2

typedef __fp16 half_t;
typedef __attribute__((ext_vector_type(2))) __fp16 half2v;
typedef __attribute__((ext_vector_type(4))) __fp16 half4v;
typedef __attribute__((ext_vector_type(4))) float f32x4;

union PU  { half2v h2[2]; half4v h4; };
union F4H { float4 f; half4v h[2]; };
union F2H { float2 f2; half4v h4; };

#define ATS 72
#define BTS 68
#define KLS 20
#define QLS 20
#define VTS 516

// ---------------- merged prologue: init-transpose (h + hh) | adjt | weight-prep ----------------
__global__ __launch_bounds__(256) void k_pre(const float* __restrict__ x,
                                             const float* __restrict__ pos,
                                             const float* __restrict__ adj,
                                             const float* __restrict__ qkv_w,
                                             const float* __restrict__ proj_w,
                                             const float* __restrict__ ff_w1,
                                             const float* __restrict__ ff_w2,
                                             const float* __restrict__ gcn_w,
                                             float* __restrict__ h,
                                             half_t* __restrict__ hh,
                                             half_t* __restrict__ adjTh,
                                             half_t* __restrict__ wh) {
    __shared__ float t[64 * 65];
    int tid = threadIdx.x;
    int bidx = blockIdx.x;
    if (bidx < 384) {
        int b = bidx / 96, vt0 = (bidx % 96) * 64;
#pragma unroll
        for (int i = 0; i < 4; ++i) {
            int g = tid + i * 256;
            int r = g >> 4, q = g & 15;           // r = c-local, 4q = vt-local
            *(float4*)&t[r * 65 + 4 * q] =
                *(const float4*)(x + ((size_t)(b * 64 + r)) * 6144 + vt0 + 4 * q);
        }
        __syncthreads();
#pragma unroll
        for (int i = 0; i < 4; ++i) {
            int g = tid + i * 256;
            int r = g >> 4, q = g & 15;           // r = vt-local, 4q = c
            int vt = vt0 + r;
            int v = vt / 12, tt = vt - v * 12;
            float4 pv = *(const float4*)(pos + v * 64 + 4 * q);
            float4 o;
            o.x = t[(4 * q + 0) * 65 + r] + pv.x;
            o.y = t[(4 * q + 1) * 65 + r] + pv.y;
            o.z = t[(4 * q + 2) * 65 + r] + pv.z;
            o.w = t[(4 * q + 3) * 65 + r] + pv.w;
            size_t idx = ((size_t)((b * 12 + tt) * 512 + v)) * 64 + 4 * q;
            *(float4*)(h + idx) = o;
            PU u;
            u.h2[0] = __builtin_amdgcn_cvt_pkrtz(o.x, o.y);
            u.h2[1] = __builtin_amdgcn_cvt_pkrtz(o.z, o.w);
            *(half4v*)(hh + idx) = u.h4;
        }
    } else if (bidx < 448) {
        int fb = bidx - 384;
        int v0 = (fb & 7) * 64, w0 = (fb >> 3) * 64;
#pragma unroll
        for (int i = 0; i < 4; ++i) {
            int g = tid + i * 256;
            int r = g >> 4, q = g & 15;
            float4 a = *(const float4*)(adj + (size_t)(v0 + r) * 512 + w0 + 4 * q);
            t[(4 * q + 0) * 65 + r] = a.x;
            t[(4 * q + 1) * 65 + r] = a.y;
            t[(4 * q + 2) * 65 + r] = a.z;
            t[(4 * q + 3) * 65 + r] = a.w;
        }
        __syncthreads();
#pragma unroll
        for (int i = 0; i < 4; ++i) {
            int g = tid + i * 256;
            int rw = g >> 4, q = g & 15;
            const float* src = &t[rw * 65 + 4 * q];
            PU u;
            u.h2[0] = __builtin_amdgcn_cvt_pkrtz(src[0], src[1]);
            u.h2[1] = __builtin_amdgcn_cvt_pkrtz(src[2], src[3]);
            *(half4v*)(adjTh + (size_t)(w0 + rw) * 512 + v0 + 4 * q) = u.h4;
        }
    } else {
        int i = (bidx - 448) * 256 + tid;
        float v;
        if (i < 24576) v = qkv_w[i];
        else if (i < 32768) v = proj_w[i - 24576];
        else if (i < 65536) v = ff_w1[i - 32768];
        else if (i < 98304) v = ff_w2[i - 65536];
        else v = gcn_w[i - 98304];
        wh[i] = (half_t)v;
    }
}

// ---------------- one-time: adjT2h = adjTh @ adjTh ----------------
__global__ __launch_bounds__(256) void k_adj2(const half_t* __restrict__ adjTh,
                                              half_t* __restrict__ adjT2h) {
    __shared__ half_t a_t[64 * ATS];
    __shared__ half_t b_t[64 * BTS];
    int tid = threadIdx.x;
    int wave = tid >> 6, lane = tid & 63;
    int lm = lane & 15, lg = lane >> 4;
    int w0 = blockIdx.x * 64, v0 = blockIdx.y * 64;
    const f32x4 zc = {0.f, 0.f, 0.f, 0.f};
    f32x4 acc[4] = {zc, zc, zc, zc};

    for (int kc = 0; kc < 8; ++kc) {
#pragma unroll
        for (int i = 0; i < 2; ++i) {
            int g = tid + i * 256;
            int r = g >> 3, s = g & 7;
            *(float4*)&a_t[r * ATS + s * 8] =
                *(const float4*)(adjTh + (size_t)(w0 + r) * 512 + kc * 64 + s * 8);
        }
#pragma unroll
        for (int i = 0; i < 2; ++i) {
            int g = tid + i * 256;
            int ur = g >> 3, s = g & 7;
            F4H u;
            u.f = *(const float4*)(adjTh + (size_t)(kc * 64 + ur) * 512 + v0 + s * 8);
#pragma unroll
            for (int e = 0; e < 8; ++e)
                b_t[(s * 8 + e) * BTS + ur] = u.h[e >> 2][e & 3];
        }
        __syncthreads();
#pragma unroll
        for (int k16 = 0; k16 < 4; ++k16) {
            half4v af = *(const half4v*)&a_t[(wave * 16 + lm) * ATS + k16 * 16 + lg * 4];
#pragma unroll
            for (int nt = 0; nt < 4; ++nt) {
                half4v bf = *(const half4v*)&b_t[(nt * 16 + lm) * BTS + k16 * 16 + lg * 4];
                acc[nt] = __builtin_amdgcn_mfma_f32_16x16x16f16(af, bf, acc[nt], 0, 0, 0);
            }
        }
        __syncthreads();
    }
#pragma unroll
    for (int nt = 0; nt < 4; ++nt)
#pragma unroll
        for (int r = 0; r < 4; ++r)
            adjT2h[(size_t)(w0 + wave * 16 + lg * 4 + r) * 512 + v0 + nt * 16 + lm] =
                (half_t)acc[nt][r];
}

// ---------------- merged: qkv (blocks 0..383) | diff z-merged (blocks 384..767) ----------------
__global__ __launch_bounds__(256) void k_qd(const half_t* __restrict__ hh,
                                            const half_t* __restrict__ Wh,
                                            half_t* __restrict__ qh,
                                            half_t* __restrict__ kh,
                                            half_t* __restrict__ vh,
                                            const half_t* __restrict__ adjTh,
                                            const half_t* __restrict__ adjT2h,
                                            half_t* __restrict__ x1h,
                                            half_t* __restrict__ x2h) {
    __shared__ __align__(16) half_t sbuf[2 * 64 * ATS + 64 * BTS];   // 27136 B
    int tid = threadIdx.x;
    int bidx = blockIdx.x;
    int wave = tid >> 6, lane = tid & 63;
    int lm = lane & 15, lg = lane >> 4;
    const f32x4 zc = {0.f, 0.f, 0.f, 0.f};

    if (bidx < 384) {
        // ---- qkv: f16 activations, f16 weights, rotating prefetch ----
        int wid = bidx * 4 + wave;
        int row = wid * 16 + lm;
        half4v xf[4];
#pragma unroll
        for (int kc = 0; kc < 4; ++kc) {
            F2H u;
            u.f2 = *(const float2*)(hh + (size_t)row * 64 + kc * 16 + lg * 4);
            xf[kc] = u.h4;
        }
        const float SC = 0.35355339059327373f * 1.4426950408889634f;
        int bt = row >> 9, v = row & 511;
        half4v wf[4];
#pragma unroll
        for (int kc = 0; kc < 4; ++kc)
            wf[kc] = *(const half4v*)(Wh + (size_t)lm * 64 + kc * 16 + lg * 4);
#pragma unroll
        for (int nt = 0; nt < 12; ++nt) {
            half4v cw[4];
#pragma unroll
            for (int kc = 0; kc < 4; ++kc) cw[kc] = wf[kc];
            if (nt < 11) {
#pragma unroll
                for (int kc = 0; kc < 4; ++kc)
                    wf[kc] = *(const half4v*)(Wh + (size_t)((nt + 1) * 16 + lm) * 64 + kc * 16 + lg * 4);
            }
            f32x4 acc = zc;
#pragma unroll
            for (int kc = 0; kc < 4; ++kc)
                acc = __builtin_amdgcn_mfma_f32_16x16x16f16(cw[kc], xf[kc], acc, 0, 0, 0);
            int s = nt >> 2;
            if (s == 0) { acc[0] *= SC; acc[1] *= SC; acc[2] *= SC; acc[3] *= SC; }
            int head = ((nt & 3) << 1) + (lg >> 1);
            int d0 = (lg & 1) * 4;
            PU o2;
            o2.h2[0] = __builtin_amdgcn_cvt_pkrtz(acc[0], acc[1]);
            o2.h2[1] = __builtin_amdgcn_cvt_pkrtz(acc[2], acc[3]);
            half_t* dst = (s == 0) ? qh : ((s == 1) ? kh : vh);
            *(half4v*)(dst + ((size_t)(bt * 8 + head) * 512 + v) * 8 + d0) = o2.h4;
        }
    } else {
        // ---- diffusion, z-merged: shared B-tile, two A matrices, two outputs ----
        half_t* a_t  = sbuf;                    // adjTh tile
        half_t* a2_t = sbuf + 64 * ATS;         // adjT2h tile
        half_t* b_t  = sbuf + 2 * 64 * ATS;
        int fb = bidx - 384;                    // 0..383
        int w0 = (fb & 7) * 64;
        int bt = fb >> 3;
        f32x4 acc0[4] = {zc, zc, zc, zc};
        f32x4 acc1[4] = {zc, zc, zc, zc};
        for (int kc = 0; kc < 8; ++kc) {
#pragma unroll
            for (int i = 0; i < 4; ++i) {       // 1024 items: 512 adjTh + 512 adjT2h
                int g = tid + i * 256;
                if (g < 512) {
                    int r = g >> 3, s = g & 7;
                    *(float4*)&a_t[r * ATS + s * 8] =
                        *(const float4*)(adjTh + (size_t)(w0 + r) * 512 + kc * 64 + s * 8);
                } else {
                    int g2 = g - 512;
                    int r = g2 >> 3, s = g2 & 7;
                    *(float4*)&a2_t[r * ATS + s * 8] =
                        *(const float4*)(adjT2h + (size_t)(w0 + r) * 512 + kc * 64 + s * 8);
                }
            }
#pragma unroll
            for (int i = 0; i < 2; ++i) {       // 512 items: transpose-stage hh tile
                int g = tid + i * 256;
                int vr = g >> 3, s = g & 7;
                F4H u;
                u.f = *(const float4*)(hh + ((size_t)(bt * 512 + kc * 64 + vr)) * 64 + s * 8);
#pragma unroll
                for (int e = 0; e < 8; ++e)
                    b_t[(s * 8 + e) * BTS + vr] = u.h[e >> 2][e & 3];
            }
            __syncthreads();
#pragma unroll
            for (int k16 = 0; k16 < 4; ++k16) {
                half4v af0 = *(const half4v*)&a_t[(wave * 16 + lm) * ATS + k16 * 16 + lg * 4];
                half4v af1 = *(const half4v*)&a2_t[(wave * 16 + lm) * ATS + k16 * 16 + lg * 4];
#pragma unroll
                for (int nt = 0; nt < 4; ++nt) {
                    half4v bf = *(const half4v*)&b_t[(nt * 16 + lm) * BTS + k16 * 16 + lg * 4];
                    acc0[nt] = __builtin_amdgcn_mfma_f32_16x16x16f16(af0, bf, acc0[nt], 0, 0, 0);
                    acc1[nt] = __builtin_amdgcn_mfma_f32_16x16x16f16(af1, bf, acc1[nt], 0, 0, 0);
                }
            }
            __syncthreads();
        }
#pragma unroll
        for (int nt = 0; nt < 4; ++nt)
#pragma unroll
            for (int r = 0; r < 4; ++r) {
                size_t o = (size_t)(w0 + wave * 16 + lg * 4 + r) * 3072 + bt * 64 + nt * 16 + lm;
                x1h[o] = (half_t)acc0[nt][r];
                x2h[o] = (half_t)acc1[nt][r];
            }
    }
}

// ---------------- merged: attn (blocks 0..767) | gcn (blocks 768..1151) ----------------
__global__ __launch_bounds__(512) void k_ag(const half_t* __restrict__ qh,
                                            const half_t* __restrict__ kh,
                                            const half_t* __restrict__ vh,
                                            half_t* __restrict__ obh,
                                            const half_t* __restrict__ hh,
                                            const half_t* __restrict__ x1h,
                                            const half_t* __restrict__ x2h,
                                            const half_t* __restrict__ Wh,
                                            const float* __restrict__ bias,
                                            float* __restrict__ gout) {
    __shared__ __align__(16) half_t sbuf[512 * KLS + 16 * VTS + 256 * QLS];  // 47232 B
    int tid = threadIdx.x;
    int bidx = blockIdx.x;
    const half4v zero4 = {(__fp16)0.f, (__fp16)0.f, (__fp16)0.f, (__fp16)0.f};
    const f32x4 zc = {0.f, 0.f, 0.f, 0.f};

    if (bidx < 768) {
        // ---- attention ----
        half_t* kl = sbuf;
        half_t* vt = sbuf + 512 * KLS;
        half_t* ql = sbuf + 512 * KLS + 16 * VTS;
        int bh = bidx >> 1;
        int half_ = bidx & 1;
        const half_t* kbase = kh + (size_t)bh * 4096;
        const half_t* vbase = vh + (size_t)bh * 4096;
        const half_t* qbase = qh + (size_t)bh * 4096 + half_ * 2048;

        if (tid < 256) {
#pragma unroll
            for (int kk = 0; kk < 2; ++kk) {
                int key = tid * 2 + kk;
                F4H u;
                u.f = *(const float4*)(kbase + key * 8);
                half4v* rowp = (half4v*)&kl[key * KLS];
                rowp[0] = u.h[0];
                rowp[1] = u.h[1];
                rowp[2] = zero4;
                rowp[3] = zero4;
            }
            {
                F4H u;
                u.f = *(const float4*)(qbase + tid * 8);
                half4v* rowp = (half4v*)&ql[tid * QLS];
                rowp[0] = u.h[0];
                rowp[1] = u.h[1];
                rowp[2] = zero4;
                rowp[3] = zero4;
            }
            {
                int k0 = tid * 2;
                F4H a, b;
                a.f = *(const float4*)(vbase + k0 * 8);
                b.f = *(const float4*)(vbase + k0 * 8 + 8);
#pragma unroll
                for (int d = 0; d < 8; ++d) {
                    half2v p = {a.h[d >> 2][d & 3], b.h[d >> 2][d & 3]};
                    *(half2v*)&vt[d * VTS + k0] = p;
                }
            }
        }
        for (int i = tid; i < 1032; i += 512)
            ((half4v*)(vt + 8 * VTS))[i] = zero4;
        __syncthreads();

        int wave = tid >> 6, lane = tid & 63;
        int lm = lane & 15, lg = lane >> 4;
        int bt = bh >> 3, head = bh & 7;

#pragma unroll 1
        for (int st = 0; st < 2; ++st) {
            int qrow0 = wave * 32 + st * 16;
            half4v qf = *(const half4v*)&ql[(qrow0 + lm) * QLS + lg * 4];
            f32x4 acc = zc;
            float l0 = 0.f, l1 = 0.f, l2 = 0.f, l3 = 0.f;
#pragma unroll 4
            for (int kt = 0; kt < 32; ++kt) {
                int key0 = kt * 16;
                half4v ka = *(const half4v*)&kl[(key0 + lm) * KLS + lg * 4];
                f32x4 c1 = __builtin_amdgcn_mfma_f32_16x16x16f16(ka, qf, zc, 0, 0, 0);
                float p0 = exp2f(fminf(c1[0], 12.f));
                float p1 = exp2f(fminf(c1[1], 12.f));
                float p2 = exp2f(fminf(c1[2], 12.f));
                float p3 = exp2f(fminf(c1[3], 12.f));
                l0 += p0; l1 += p1; l2 += p2; l3 += p3;
                PU pu;
                pu.h2[0] = __builtin_amdgcn_cvt_pkrtz(p0, p1);
                pu.h2[1] = __builtin_amdgcn_cvt_pkrtz(p2, p3);
                half4v va = *(const half4v*)&vt[lm * VTS + key0 + lg * 4];
                acc = __builtin_amdgcn_mfma_f32_16x16x16f16(va, pu.h4, acc, 0, 0, 0);
            }
            float lsum = (l0 + l1) + (l2 + l3);
            lsum += __shfl_xor(lsum, 16);
            lsum += __shfl_xor(lsum, 32);
            if (lg < 2) {
                float inv = 1.f / lsum;
                int rowg = half_ * 256 + qrow0 + lm;
                PU o2;
                o2.h2[0] = __builtin_amdgcn_cvt_pkrtz(acc[0] * inv, acc[1] * inv);
                o2.h2[1] = __builtin_amdgcn_cvt_pkrtz(acc[2] * inv, acc[3] * inv);
                *(half4v*)(obh + ((size_t)(bt * 512 + rowg)) * 64 + head * 8 + lg * 4) = o2.h4;
            }
        }
    } else {
        // ---- gcn (256 active threads; barriers at block-uniform points) ----
        half_t* a_t = sbuf;
        half_t* b_t = sbuf + 64 * ATS;
        int row0 = (bidx - 768) * 64;                 // row = v*48+bt
        int wave = tid >> 6, lane = tid & 63;
        int lm = lane & 15, lg = lane >> 4;
        f32x4 acc[4] = {zc, zc, zc, zc};

        for (int ch = 0; ch < 3; ++ch) {
            if (tid < 256) {
                if (ch == 0) {
#pragma unroll
                    for (int i = 0; i < 2; ++i) {
                        int g = tid + i * 256;
                        int r = g >> 3, s = g & 7;
                        int rowg = row0 + r;
                        int v = rowg / 48, bt = rowg - v * 48;
                        *(float4*)&a_t[r * ATS + s * 8] =
                            *(const float4*)(hh + ((size_t)(bt * 512 + v)) * 64 + s * 8);
                    }
                } else {
                    const half_t* X = (ch == 1) ? x1h : x2h;
#pragma unroll
                    for (int i = 0; i < 2; ++i) {
                        int g = tid + i * 256;
                        int r = g >> 3, s = g & 7;
                        *(float4*)&a_t[r * ATS + s * 8] =
                            *(const float4*)(X + (size_t)(row0 + r) * 64 + s * 8);
                    }
                }
#pragma unroll
                for (int i = 0; i < 4; ++i) {
                    int g = tid + i * 256;
                    int r = g >> 4, q = g & 15;
                    *(half4v*)&b_t[r * BTS + 4 * q] =
                        *(const half4v*)(Wh + (size_t)r * 192 + ch * 64 + 4 * q);
                }
            }
            __syncthreads();
            if (tid < 256) {
#pragma unroll
                for (int k16 = 0; k16 < 4; ++k16) {
                    half4v af = *(const half4v*)&a_t[(wave * 16 + lm) * ATS + k16 * 16 + lg * 4];
#pragma unroll
                    for (int nt = 0; nt < 4; ++nt) {
                        half4v bf = *(const half4v*)&b_t[(nt * 16 + lm) * BTS + k16 * 16 + lg * 4];
                        acc[nt] = __builtin_amdgcn_mfma_f32_16x16x16f16(bf, af, acc[nt], 0, 0, 0);
                    }
                }
            }
            __syncthreads();
        }
        if (tid < 256) {
            int row = row0 + wave * 16 + lm;
            int v = row / 48, bt = row - v * 48;
            float* gp = gout + ((size_t)(bt * 512 + v)) * 64;
#pragma unroll
            for (int nt = 0; nt < 4; ++nt) {
                float4 bb = *(const float4*)(bias + nt * 16 + lg * 4);
                *(float4*)(gp + nt * 16 + lg * 4) =
                    make_float4(acc[nt][0] + bb.x, acc[nt][1] + bb.y,
                                acc[nt][2] + bb.z, acc[nt][3] + bb.w);
            }
        }
    }
}

// ---------------- fused proj + LN + FF + gout add; writes h and hh ----------------
__global__ __launch_bounds__(128) void k_plf(const half_t* __restrict__ obh,
                                             const half_t* __restrict__ pwh,
                                             const float* __restrict__ pb,
                                             const float* __restrict__ g,
                                             const float* __restrict__ bln,
                                             const half_t* __restrict__ w1h,
                                             const float* __restrict__ b1,
                                             const half_t* __restrict__ w2h,
                                             const float* __restrict__ b2,
                                             const float* __restrict__ gout,
                                             float* __restrict__ h,
                                             half_t* __restrict__ hh) {
    int wid = blockIdx.x * 2 + (threadIdx.x >> 6);    // 0..1535
    int lane = threadIdx.x & 63;
    int lm = lane & 15, lg = lane >> 4;
    int row = wid * 16 + lm;
    const f32x4 zc = {0.f, 0.f, 0.f, 0.f};

    half4v pf[4];
#pragma unroll
    for (int kc = 0; kc < 4; ++kc)
        pf[kc] = *(const half4v*)(pwh + (size_t)lm * 64 + kc * 16 + lg * 4);

    half4v of[4];
#pragma unroll
    for (int kc = 0; kc < 4; ++kc) {
        F2H u;
        u.f2 = *(const float2*)(obh + (size_t)row * 64 + kc * 16 + lg * 4);
        of[kc] = u.h4;
    }

    f32x4 hp[4];
#pragma unroll
    for (int nt = 0; nt < 4; ++nt) {
        half4v cw[4];
#pragma unroll
        for (int kc = 0; kc < 4; ++kc) cw[kc] = pf[kc];
        if (nt < 3) {
#pragma unroll
            for (int kc = 0; kc < 4; ++kc)
                pf[kc] = *(const half4v*)(pwh + (size_t)((nt + 1) * 16 + lm) * 64 + kc * 16 + lg * 4);
        }
        f32x4 c = zc;
#pragma unroll
        for (int kc = 0; kc < 4; ++kc)
            c = __builtin_amdgcn_mfma_f32_16x16x16f16(cw[kc], of[kc], c, 0, 0, 0);
        float4 ho = *(const float4*)(h + (size_t)row * 64 + nt * 16 + lg * 4);
        float4 bb = *(const float4*)(pb + nt * 16 + lg * 4);
        hp[nt][0] = c[0] + ho.x + bb.x;
        hp[nt][1] = c[1] + ho.y + bb.y;
        hp[nt][2] = c[2] + ho.z + bb.z;
        hp[nt][3] = c[3] + ho.w + bb.w;
    }

    float s = 0.f, s2 = 0.f;
#pragma unroll
    for (int nt = 0; nt < 4; ++nt)
#pragma unroll
        for (int r = 0; r < 4; ++r) {
            s += hp[nt][r];
            s2 += hp[nt][r] * hp[nt][r];
        }
    s += __shfl_xor(s, 16);  s2 += __shfl_xor(s2, 16);
    s += __shfl_xor(s, 32);  s2 += __shfl_xor(s2, 32);
    float mean = s * (1.f / 64.f);
    float var = s2 * (1.f / 64.f) - mean * mean;
    float rstd = rsqrtf(var + 1e-5f);

    half4v xf[4];
#pragma unroll
    for (int nt = 0; nt < 4; ++nt) {
        float4 gg = *(const float4*)(g + nt * 16 + lg * 4);
        float4 bb = *(const float4*)(bln + nt * 16 + lg * 4);
        float y0 = (hp[nt][0] - mean) * rstd * gg.x + bb.x;
        float y1 = (hp[nt][1] - mean) * rstd * gg.y + bb.y;
        float y2 = (hp[nt][2] - mean) * rstd * gg.z + bb.z;
        float y3 = (hp[nt][3] - mean) * rstd * gg.w + bb.w;
        PU u;
        u.h2[0] = __builtin_amdgcn_cvt_pkrtz(y0, y1);
        u.h2[1] = __builtin_amdgcn_cvt_pkrtz(y2, y3);
        xf[nt] = u.h4;
    }

    half4v w1f[4];
#pragma unroll
    for (int kc = 0; kc < 4; ++kc)
        w1f[kc] = *(const half4v*)(w1h + (size_t)lm * 64 + kc * 16 + lg * 4);

    f32x4 acc[4] = {zc, zc, zc, zc};
#pragma unroll 4
    for (int ht = 0; ht < 16; ++ht) {
        half4v cw[4];
#pragma unroll
        for (int kc = 0; kc < 4; ++kc) cw[kc] = w1f[kc];
        half4v w2f[4];
#pragma unroll
        for (int ot = 0; ot < 4; ++ot)
            w2f[ot] = *(const half4v*)(w2h + (size_t)(ot * 16 + lm) * 256 + ht * 16 + lg * 4);
        if (ht < 15) {
#pragma unroll
            for (int kc = 0; kc < 4; ++kc)
                w1f[kc] = *(const half4v*)(w1h + (size_t)((ht + 1) * 16 + lm) * 64 + kc * 16 + lg * 4);
        }
        f32x4 c1 = zc;
#pragma unroll
        for (int kc = 0; kc < 4; ++kc)
            c1 = __builtin_amdgcn_mfma_f32_16x16x16f16(cw[kc], xf[kc], c1, 0, 0, 0);
        float4 bb = *(const float4*)(b1 + ht * 16 + lg * 4);
        float y0 = c1[0] + bb.x;
        float y1 = c1[1] + bb.y;
        float y2 = c1[2] + bb.z;
        float y3 = c1[3] + bb.w;
        y0 = 0.5f * y0 * (1.0f + erff(y0 * 0.70710678118654752f));
        y1 = 0.5f * y1 * (1.0f + erff(y1 * 0.70710678118654752f));
        y2 = 0.5f * y2 * (1.0f + erff(y2 * 0.70710678118654752f));
        y3 = 0.5f * y3 * (1.0f + erff(y3 * 0.70710678118654752f));
        PU p;
        p.h2[0] = __builtin_amdgcn_cvt_pkrtz(y0, y1);
        p.h2[1] = __builtin_amdgcn_cvt_pkrtz(y2, y3);
#pragma unroll
        for (int ot = 0; ot < 4; ++ot)
            acc[ot] = __builtin_amdgcn_mfma_f32_16x16x16f16(w2f[ot], p.h4, acc[ot], 0, 0, 0);
    }

#pragma unroll
    for (int ot = 0; ot < 4; ++ot) {
        float4 bb = *(const float4*)(b2 + ot * 16 + lg * 4);
        float4 gv = *(const float4*)(gout + (size_t)row * 64 + ot * 16 + lg * 4);
        float4 fv = make_float4(hp[ot][0] + acc[ot][0] + bb.x + gv.x,
                                hp[ot][1] + acc[ot][1] + bb.y + gv.y,
                                hp[ot][2] + acc[ot][2] + bb.z + gv.z,
                                hp[ot][3] + acc[ot][3] + bb.w + gv.w);
        size_t idx = (size_t)row * 64 + ot * 16 + lg * 4;
        *(float4*)(h + idx) = fv;
        PU u;
        u.h2[0] = __builtin_amdgcn_cvt_pkrtz(fv.x, fv.y);
        u.h2[1] = __builtin_amdgcn_cvt_pkrtz(fv.z, fv.w);
        *(half4v*)(hh + idx) = u.h4;
    }
}

// ---------------- final: out[b,c,v,t] = h[(b*12+t)*512+v][c]  (LDS-tiled transpose) ----------------
__global__ __launch_bounds__(256) void k_out(const float* __restrict__ h,
                                             float* __restrict__ out) {
    __shared__ float t[64 * 65];
    int tid = threadIdx.x;
    int b = blockIdx.x / 96, vt0 = (blockIdx.x % 96) * 64;
#pragma unroll
    for (int i = 0; i < 4; ++i) {
        int g = tid + i * 256;
        int r = g >> 4, q = g & 15;               // r = vt-local, 4q = c
        int vt = vt0 + r;
        int v = vt / 12, tt = vt - v * 12;
        *(float4*)&t[r * 65 + 4 * q] =
            *(const float4*)(h + ((size_t)((b * 12 + tt) * 512 + v)) * 64 + 4 * q);
    }
    __syncthreads();
#pragma unroll
    for (int i = 0; i < 4; ++i) {
        int g = tid + i * 256;
        int r = g >> 4, q = g & 15;               // r = c-local, 4q = vt-local
        float4 o;
        o.x = t[(4 * q + 0) * 65 + r];
        o.y = t[(4 * q + 1) * 65 + r];
        o.z = t[(4 * q + 2) * 65 + r];
        o.w = t[(4 * q + 3) * 65 + r];
        *(float4*)(out + ((size_t)(b * 64 + r)) * 6144 + vt0 + 4 * q) = o;
    }
}

extern "C" void kernel_launch(void* const* d_in, const int* in_sizes, int n_in,
                              void* d_out, int out_size, void* d_ws, size_t ws_size,
                              hipStream_t stream) {
    const float* x      = (const float*)d_in[0];
    const float* adj    = (const float*)d_in[1];
    const float* pos    = (const float*)d_in[2];
    const float* qkv_w  = (const float*)d_in[3];
    const float* proj_w = (const float*)d_in[4];
    const float* proj_b = (const float*)d_in[5];
    const float* ln_g   = (const float*)d_in[6];
    const float* ln_b   = (const float*)d_in[7];
    const float* ff_w1  = (const float*)d_in[8];
    const float* ff_b1  = (const float*)d_in[9];
    const float* ff_w2  = (const float*)d_in[10];
    const float* ff_b2  = (const float*)d_in[11];
    const float* gcn_w  = (const float*)d_in[12];
    const float* gcn_b  = (const float*)d_in[13];
    float* out = (float*)d_out;

    const size_t SZ = 1572864;  // 48*512*64
    float* h    = (float*)d_ws;
    float* gout = h + SZ;
    half_t* hh  = (half_t*)(gout + SZ);
    half_t* x1h = hh + SZ;
    half_t* x2h = x1h + SZ;
    half_t* qh  = x2h + SZ;
    half_t* kh  = qh + SZ;
    half_t* vh  = kh + SZ;
    half_t* obh = vh + SZ;
    half_t* adjTh  = obh + SZ;        // 262144
    half_t* adjT2h = adjTh + 262144;  // 262144
    half_t* wh     = adjT2h + 262144; // 122880
    half_t* qkv_wh  = wh;
    half_t* proj_wh = wh + 24576;
    half_t* ff_w1h  = wh + 32768;
    half_t* ff_w2h  = wh + 65536;
    half_t* gcn_wh  = wh + 98304;

    k_pre<<<928, 256, 0, stream>>>(x, pos, adj, qkv_w, proj_w, ff_w1, ff_w2, gcn_w,
                                   h, hh, adjTh, wh);
    k_adj2<<<dim3(8, 8), 256, 0, stream>>>(adjTh, adjT2h);
    for (int l = 0; l < 2; ++l) {
        k_qd<<<768, 256, 0, stream>>>(hh, qkv_wh + l * 12288, qh, kh, vh,
                                      adjTh, adjT2h, x1h, x2h);
        k_ag<<<1152, 512, 0, stream>>>(qh, kh, vh, obh, hh, x1h, x2h,
                                       gcn_wh + l * 12288, gcn_b + l * 64, gout);
        k_plf<<<768, 128, 0, stream>>>(obh, proj_wh + l * 4096, proj_b + l * 64,
                                       ln_g + l * 64, ln_b + l * 64,
                                       ff_w1h + l * 16384, ff_b1 + l * 256,
                                       ff_w2h + l * 16384, ff_b2 + l * 64, gout, h, hh);
    }
    k_out<<<384, 256, 0, stream>>>(h, out);
}

// Round 18
// 275.867 us; speedup vs baseline: 1.4810x; 1.0159x over previous
//
#include <hip/hip_runtime.h>
#include <math.h>

// Sizes: b=4, t=12 (BT=48), n=512, c=64, heads=8, hd=8, FF hidden=256, depth=2

typedef __fp16 half_t;
typedef __attribute__((ext_vector_type(2))) __fp16 half2v;
typedef __attribute__((ext_vector_type(4))) __fp16 half4v;
typedef __attribute__((ext_vector_type(4))) float f32x4;

union PU  { half2v h2[2]; half4v h4; };
union F4H { float4 f; half4v h[2]; };
union F2H { float2 f2; half4v h4; };

#define ATS 72
#define BTS 68
#define KLS 20
#define QLS 20
#define VTS 516

// ---------------- merged prologue: init-transpose (h+hh) | adjt | weight-prep | adj^2 ----------------
// blocks 0..383: h/hh init transpose; 384..447: adjTh; 448..927: weights; 928..991: adjT2h
__global__ __launch_bounds__(256) void k_pre(const float* __restrict__ x,
                                             const float* __restrict__ pos,
                                             const float* __restrict__ adj,
                                             const float* __restrict__ qkv_w,
                                             const float* __restrict__ proj_w,
                                             const float* __restrict__ ff_w1,
                                             const float* __restrict__ ff_w2,
                                             const float* __restrict__ gcn_w,
                                             float* __restrict__ h,
                                             half_t* __restrict__ hh,
                                             half_t* __restrict__ adjTh,
                                             half_t* __restrict__ wh,
                                             half_t* __restrict__ adjT2h) {
    __shared__ __align__(16) char smem[17920];
    float* t = (float*)smem;                          // 64*65 floats = 16640 B
    int tid = threadIdx.x;
    int bidx = blockIdx.x;
    if (bidx < 384) {
        int b = bidx / 96, vt0 = (bidx % 96) * 64;
#pragma unroll
        for (int i = 0; i < 4; ++i) {
            int g = tid + i * 256;
            int r = g >> 4, q = g & 15;
            *(float4*)&t[r * 65 + 4 * q] =
                *(const float4*)(x + ((size_t)(b * 64 + r)) * 6144 + vt0 + 4 * q);
        }
        __syncthreads();
#pragma unroll
        for (int i = 0; i < 4; ++i) {
            int g = tid + i * 256;
            int r = g >> 4, q = g & 15;
            int vt = vt0 + r;
            int v = vt / 12, tt = vt - v * 12;
            float4 pv = *(const float4*)(pos + v * 64 + 4 * q);
            float4 o;
            o.x = t[(4 * q + 0) * 65 + r] + pv.x;
            o.y = t[(4 * q + 1) * 65 + r] + pv.y;
            o.z = t[(4 * q + 2) * 65 + r] + pv.z;
            o.w = t[(4 * q + 3) * 65 + r] + pv.w;
            size_t idx = ((size_t)((b * 12 + tt) * 512 + v)) * 64 + 4 * q;
            *(float4*)(h + idx) = o;
            PU u;
            u.h2[0] = __builtin_amdgcn_cvt_pkrtz(o.x, o.y);
            u.h2[1] = __builtin_amdgcn_cvt_pkrtz(o.z, o.w);
            *(half4v*)(hh + idx) = u.h4;
        }
    } else if (bidx < 448) {
        int fb = bidx - 384;
        int v0 = (fb & 7) * 64, w0 = (fb >> 3) * 64;
#pragma unroll
        for (int i = 0; i < 4; ++i) {
            int g = tid + i * 256;
            int r = g >> 4, q = g & 15;
            float4 a = *(const float4*)(adj + (size_t)(v0 + r) * 512 + w0 + 4 * q);
            t[(4 * q + 0) * 65 + r] = a.x;
            t[(4 * q + 1) * 65 + r] = a.y;
            t[(4 * q + 2) * 65 + r] = a.z;
            t[(4 * q + 3) * 65 + r] = a.w;
        }
        __syncthreads();
#pragma unroll
        for (int i = 0; i < 4; ++i) {
            int g = tid + i * 256;
            int rw = g >> 4, q = g & 15;
            const float* src = &t[rw * 65 + 4 * q];
            PU u;
            u.h2[0] = __builtin_amdgcn_cvt_pkrtz(src[0], src[1]);
            u.h2[1] = __builtin_amdgcn_cvt_pkrtz(src[2], src[3]);
            *(half4v*)(adjTh + (size_t)(w0 + rw) * 512 + v0 + 4 * q) = u.h4;
        }
    } else if (bidx < 928) {
        int i = (bidx - 448) * 256 + tid;
        float v;
        if (i < 24576) v = qkv_w[i];
        else if (i < 32768) v = proj_w[i - 24576];
        else if (i < 65536) v = ff_w1[i - 32768];
        else if (i < 98304) v = ff_w2[i - 65536];
        else v = gcn_w[i - 98304];
        wh[i] = (half_t)v;
    } else {
        // ---- adjT2h tile (w0,v0) = (A^T @ A^T)[w0:,v0:] directly from raw fp32 adj ----
        half_t* a_t = (half_t*)smem;                  // [w-local][u-local], stride ATS
        half_t* b_t = (half_t*)smem + 64 * ATS;       // [v-local][u-local], stride BTS
        int fb = bidx - 928;
        int w0 = (fb & 7) * 64, v0 = (fb >> 3) * 64;
        int wave = tid >> 6, lane = tid & 63;
        int lm = lane & 15, lg = lane >> 4;
        const f32x4 zc = {0.f, 0.f, 0.f, 0.f};
        f32x4 acc[4] = {zc, zc, zc, zc};
        for (int kc = 0; kc < 8; ++kc) {
            // A-tile: a_t[r][uu] = adj[kc*64+uu][w0+r]  (transpose-stage)
#pragma unroll
            for (int i = 0; i < 4; ++i) {
                int g = tid + i * 256;
                int uu = g >> 4, q = g & 15;
                float4 a = *(const float4*)(adj + (size_t)(kc * 64 + uu) * 512 + w0 + 4 * q);
                a_t[(4 * q + 0) * ATS + uu] = (half_t)a.x;
                a_t[(4 * q + 1) * ATS + uu] = (half_t)a.y;
                a_t[(4 * q + 2) * ATS + uu] = (half_t)a.z;
                a_t[(4 * q + 3) * ATS + uu] = (half_t)a.w;
            }
            // B-tile: b_t[c][uu] = adj[v0+c][kc*64+uu]  (row copy + cvt)
#pragma unroll
            for (int i = 0; i < 4; ++i) {
                int g = tid + i * 256;
                int c = g >> 4, q = g & 15;
                float4 a = *(const float4*)(adj + (size_t)(v0 + c) * 512 + kc * 64 + 4 * q);
                PU u;
                u.h2[0] = __builtin_amdgcn_cvt_pkrtz(a.x, a.y);
                u.h2[1] = __builtin_amdgcn_cvt_pkrtz(a.z, a.w);
                *(half4v*)&b_t[c * BTS + 4 * q] = u.h4;
            }
            __syncthreads();
#pragma unroll
            for (int k16 = 0; k16 < 4; ++k16) {
                half4v af = *(const half4v*)&a_t[(wave * 16 + lm) * ATS + k16 * 16 + lg * 4];
#pragma unroll
                for (int nt = 0; nt < 4; ++nt) {
                    half4v bf = *(const half4v*)&b_t[(nt * 16 + lm) * BTS + k16 * 16 + lg * 4];
                    acc[nt] = __builtin_amdgcn_mfma_f32_16x16x16f16(af, bf, acc[nt], 0, 0, 0);
                }
            }
            __syncthreads();
        }
#pragma unroll
        for (int nt = 0; nt < 4; ++nt)
#pragma unroll
            for (int r = 0; r < 4; ++r)
                adjT2h[(size_t)(w0 + wave * 16 + lg * 4 + r) * 512 + v0 + nt * 16 + lm] =
                    (half_t)acc[nt][r];
    }
}

// ---------------- merged: qkv (blocks 0..383) | diff z-merged (blocks 384..767) ----------------
__global__ __launch_bounds__(256) void k_qd(const half_t* __restrict__ hh,
                                            const half_t* __restrict__ Wh,
                                            half_t* __restrict__ qh,
                                            half_t* __restrict__ kh,
                                            half_t* __restrict__ vh,
                                            const half_t* __restrict__ adjTh,
                                            const half_t* __restrict__ adjT2h,
                                            half_t* __restrict__ x1h,
                                            half_t* __restrict__ x2h) {
    __shared__ __align__(16) half_t sbuf[2 * 64 * ATS + 64 * BTS];   // 27136 B
    int tid = threadIdx.x;
    int bidx = blockIdx.x;
    int wave = tid >> 6, lane = tid & 63;
    int lm = lane & 15, lg = lane >> 4;
    const f32x4 zc = {0.f, 0.f, 0.f, 0.f};

    if (bidx < 384) {
        int wid = bidx * 4 + wave;
        int row = wid * 16 + lm;
        half4v xf[4];
#pragma unroll
        for (int kc = 0; kc < 4; ++kc) {
            F2H u;
            u.f2 = *(const float2*)(hh + (size_t)row * 64 + kc * 16 + lg * 4);
            xf[kc] = u.h4;
        }
        const float SC = 0.35355339059327373f * 1.4426950408889634f;
        int bt = row >> 9, v = row & 511;
        half4v wf[4];
#pragma unroll
        for (int kc = 0; kc < 4; ++kc)
            wf[kc] = *(const half4v*)(Wh + (size_t)lm * 64 + kc * 16 + lg * 4);
#pragma unroll
        for (int nt = 0; nt < 12; ++nt) {
            half4v cw[4];
#pragma unroll
            for (int kc = 0; kc < 4; ++kc) cw[kc] = wf[kc];
            if (nt < 11) {
#pragma unroll
                for (int kc = 0; kc < 4; ++kc)
                    wf[kc] = *(const half4v*)(Wh + (size_t)((nt + 1) * 16 + lm) * 64 + kc * 16 + lg * 4);
            }
            f32x4 acc = zc;
#pragma unroll
            for (int kc = 0; kc < 4; ++kc)
                acc = __builtin_amdgcn_mfma_f32_16x16x16f16(cw[kc], xf[kc], acc, 0, 0, 0);
            int s = nt >> 2;
            if (s == 0) { acc[0] *= SC; acc[1] *= SC; acc[2] *= SC; acc[3] *= SC; }
            int head = ((nt & 3) << 1) + (lg >> 1);
            int d0 = (lg & 1) * 4;
            PU o2;
            o2.h2[0] = __builtin_amdgcn_cvt_pkrtz(acc[0], acc[1]);
            o2.h2[1] = __builtin_amdgcn_cvt_pkrtz(acc[2], acc[3]);
            half_t* dst = (s == 0) ? qh : ((s == 1) ? kh : vh);
            *(half4v*)(dst + ((size_t)(bt * 8 + head) * 512 + v) * 8 + d0) = o2.h4;
        }
    } else {
        half_t* a_t  = sbuf;
        half_t* a2_t = sbuf + 64 * ATS;
        half_t* b_t  = sbuf + 2 * 64 * ATS;
        int fb = bidx - 384;                    // 0..383
        int w0 = (fb & 7) * 64;
        int bt = fb >> 3;
        f32x4 acc0[4] = {zc, zc, zc, zc};
        f32x4 acc1[4] = {zc, zc, zc, zc};
        for (int kc = 0; kc < 8; ++kc) {
#pragma unroll
            for (int i = 0; i < 4; ++i) {       // 1024 items: 512 adjTh + 512 adjT2h
                int g = tid + i * 256;
                if (g < 512) {
                    int r = g >> 3, s = g & 7;
                    *(float4*)&a_t[r * ATS + s * 8] =
                        *(const float4*)(adjTh + (size_t)(w0 + r) * 512 + kc * 64 + s * 8);
                } else {
                    int g2 = g - 512;
                    int r = g2 >> 3, s = g2 & 7;
                    *(float4*)&a2_t[r * ATS + s * 8] =
                        *(const float4*)(adjT2h + (size_t)(w0 + r) * 512 + kc * 64 + s * 8);
                }
            }
#pragma unroll
            for (int i = 0; i < 2; ++i) {       // 512 items: transpose-stage hh tile
                int g = tid + i * 256;
                int vr = g >> 3, s = g & 7;
                F4H u;
                u.f = *(const float4*)(hh + ((size_t)(bt * 512 + kc * 64 + vr)) * 64 + s * 8);
#pragma unroll
                for (int e = 0; e < 8; ++e)
                    b_t[(s * 8 + e) * BTS + vr] = u.h[e >> 2][e & 3];
            }
            __syncthreads();
#pragma unroll
            for (int k16 = 0; k16 < 4; ++k16) {
                half4v af0 = *(const half4v*)&a_t[(wave * 16 + lm) * ATS + k16 * 16 + lg * 4];
                half4v af1 = *(const half4v*)&a2_t[(wave * 16 + lm) * ATS + k16 * 16 + lg * 4];
#pragma unroll
                for (int nt = 0; nt < 4; ++nt) {
                    half4v bf = *(const half4v*)&b_t[(nt * 16 + lm) * BTS + k16 * 16 + lg * 4];
                    acc0[nt] = __builtin_amdgcn_mfma_f32_16x16x16f16(af0, bf, acc0[nt], 0, 0, 0);
                    acc1[nt] = __builtin_amdgcn_mfma_f32_16x16x16f16(af1, bf, acc1[nt], 0, 0, 0);
                }
            }
            __syncthreads();
        }
#pragma unroll
        for (int nt = 0; nt < 4; ++nt)
#pragma unroll
            for (int r = 0; r < 4; ++r) {
                size_t o = (size_t)(w0 + wave * 16 + lg * 4 + r) * 3072 + bt * 64 + nt * 16 + lm;
                x1h[o] = (half_t)acc0[nt][r];
                x2h[o] = (half_t)acc1[nt][r];
            }
    }
}

// ---------------- merged: attn (blocks 0..767) | gcn (blocks 768..1151) ----------------
__global__ __launch_bounds__(512) void k_ag(const half_t* __restrict__ qh,
                                            const half_t* __restrict__ kh,
                                            const half_t* __restrict__ vh,
                                            half_t* __restrict__ obh,
                                            const half_t* __restrict__ hh,
                                            const half_t* __restrict__ x1h,
                                            const half_t* __restrict__ x2h,
                                            const half_t* __restrict__ Wh,
                                            const float* __restrict__ bias,
                                            float* __restrict__ gout) {
    __shared__ __align__(16) half_t sbuf[512 * KLS + 16 * VTS + 256 * QLS];  // 47232 B
    int tid = threadIdx.x;
    int bidx = blockIdx.x;
    const half4v zero4 = {(__fp16)0.f, (__fp16)0.f, (__fp16)0.f, (__fp16)0.f};
    const f32x4 zc = {0.f, 0.f, 0.f, 0.f};

    if (bidx < 768) {
        half_t* kl = sbuf;
        half_t* vt = sbuf + 512 * KLS;
        half_t* ql = sbuf + 512 * KLS + 16 * VTS;
        int bh = bidx >> 1;
        int half_ = bidx & 1;
        const half_t* kbase = kh + (size_t)bh * 4096;
        const half_t* vbase = vh + (size_t)bh * 4096;
        const half_t* qbase = qh + (size_t)bh * 4096 + half_ * 2048;

        if (tid < 256) {
#pragma unroll
            for (int kk = 0; kk < 2; ++kk) {
                int key = tid * 2 + kk;
                F4H u;
                u.f = *(const float4*)(kbase + key * 8);
                half4v* rowp = (half4v*)&kl[key * KLS];
                rowp[0] = u.h[0];
                rowp[1] = u.h[1];
                rowp[2] = zero4;
                rowp[3] = zero4;
            }
            {
                F4H u;
                u.f = *(const float4*)(qbase + tid * 8);
                half4v* rowp = (half4v*)&ql[tid * QLS];
                rowp[0] = u.h[0];
                rowp[1] = u.h[1];
                rowp[2] = zero4;
                rowp[3] = zero4;
            }
            {
                int k0 = tid * 2;
                F4H a, b;
                a.f = *(const float4*)(vbase + k0 * 8);
                b.f = *(const float4*)(vbase + k0 * 8 + 8);
#pragma unroll
                for (int d = 0; d < 8; ++d) {
                    half2v p = {a.h[d >> 2][d & 3], b.h[d >> 2][d & 3]};
                    *(half2v*)&vt[d * VTS + k0] = p;
                }
            }
        }
        for (int i = tid; i < 1032; i += 512)
            ((half4v*)(vt + 8 * VTS))[i] = zero4;
        __syncthreads();

        int wave = tid >> 6, lane = tid & 63;
        int lm = lane & 15, lg = lane >> 4;
        int bt = bh >> 3, head = bh & 7;

#pragma unroll 1
        for (int st = 0; st < 2; ++st) {
            int qrow0 = wave * 32 + st * 16;
            half4v qf = *(const half4v*)&ql[(qrow0 + lm) * QLS + lg * 4];
            f32x4 acc = zc;
            float l0 = 0.f, l1 = 0.f, l2 = 0.f, l3 = 0.f;
#pragma unroll 4
            for (int kt = 0; kt < 32; ++kt) {
                int key0 = kt * 16;
                half4v ka = *(const half4v*)&kl[(key0 + lm) * KLS + lg * 4];
                f32x4 c1 = __builtin_amdgcn_mfma_f32_16x16x16f16(ka, qf, zc, 0, 0, 0);
                float p0 = exp2f(fminf(c1[0], 12.f));
                float p1 = exp2f(fminf(c1[1], 12.f));
                float p2 = exp2f(fminf(c1[2], 12.f));
                float p3 = exp2f(fminf(c1[3], 12.f));
                l0 += p0; l1 += p1; l2 += p2; l3 += p3;
                PU pu;
                pu.h2[0] = __builtin_amdgcn_cvt_pkrtz(p0, p1);
                pu.h2[1] = __builtin_amdgcn_cvt_pkrtz(p2, p3);
                half4v va = *(const half4v*)&vt[lm * VTS + key0 + lg * 4];
                acc = __builtin_amdgcn_mfma_f32_16x16x16f16(va, pu.h4, acc, 0, 0, 0);
            }
            float lsum = (l0 + l1) + (l2 + l3);
            lsum += __shfl_xor(lsum, 16);
            lsum += __shfl_xor(lsum, 32);
            if (lg < 2) {
                float inv = 1.f / lsum;
                int rowg = half_ * 256 + qrow0 + lm;
                PU o2;
                o2.h2[0] = __builtin_amdgcn_cvt_pkrtz(acc[0] * inv, acc[1] * inv);
                o2.h2[1] = __builtin_amdgcn_cvt_pkrtz(acc[2] * inv, acc[3] * inv);
                *(half4v*)(obh + ((size_t)(bt * 512 + rowg)) * 64 + head * 8 + lg * 4) = o2.h4;
            }
        }
    } else {
        half_t* a_t = sbuf;
        half_t* b_t = sbuf + 64 * ATS;
        int row0 = (bidx - 768) * 64;
        int wave = tid >> 6, lane = tid & 63;
        int lm = lane & 15, lg = lane >> 4;
        f32x4 acc[4] = {zc, zc, zc, zc};

        for (int ch = 0; ch < 3; ++ch) {
            if (tid < 256) {
                if (ch == 0) {
#pragma unroll
                    for (int i = 0; i < 2; ++i) {
                        int g = tid + i * 256;
                        int r = g >> 3, s = g & 7;
                        int rowg = row0 + r;
                        int v = rowg / 48, bt = rowg - v * 48;
                        *(float4*)&a_t[r * ATS + s * 8] =
                            *(const float4*)(hh + ((size_t)(bt * 512 + v)) * 64 + s * 8);
                    }
                } else {
                    const half_t* X = (ch == 1) ? x1h : x2h;
#pragma unroll
                    for (int i = 0; i < 2; ++i) {
                        int g = tid + i * 256;
                        int r = g >> 3, s = g & 7;
                        *(float4*)&a_t[r * ATS + s * 8] =
                            *(const float4*)(X + (size_t)(row0 + r) * 64 + s * 8);
                    }
                }
#pragma unroll
                for (int i = 0; i < 4; ++i) {
                    int g = tid + i * 256;
                    int r = g >> 4, q = g & 15;
                    *(half4v*)&b_t[r * BTS + 4 * q] =
                        *(const half4v*)(Wh + (size_t)r * 192 + ch * 64 + 4 * q);
                }
            }
            __syncthreads();
            if (tid < 256) {
#pragma unroll
                for (int k16 = 0; k16 < 4; ++k16) {
                    half4v af = *(const half4v*)&a_t[(wave * 16 + lm) * ATS + k16 * 16 + lg * 4];
#pragma unroll
                    for (int nt = 0; nt < 4; ++nt) {
                        half4v bf = *(const half4v*)&b_t[(nt * 16 + lm) * BTS + k16 * 16 + lg * 4];
                        acc[nt] = __builtin_amdgcn_mfma_f32_16x16x16f16(bf, af, acc[nt], 0, 0, 0);
                    }
                }
            }
            __syncthreads();
        }
        if (tid < 256) {
            int row = row0 + wave * 16 + lm;
            int v = row / 48, bt = row - v * 48;
            float* gp = gout + ((size_t)(bt * 512 + v)) * 64;
#pragma unroll
            for (int nt = 0; nt < 4; ++nt) {
                float4 bb = *(const float4*)(bias + nt * 16 + lg * 4);
                *(float4*)(gp + nt * 16 + lg * 4) =
                    make_float4(acc[nt][0] + bb.x, acc[nt][1] + bb.y,
                                acc[nt][2] + bb.z, acc[nt][3] + bb.w);
            }
        }
    }
}

// ---------------- fused proj + LN + FF + gout add; writes h and hh ----------------
__global__ __launch_bounds__(128) void k_plf(const half_t* __restrict__ obh,
                                             const half_t* __restrict__ pwh,
                                             const float* __restrict__ pb,
                                             const float* __restrict__ g,
                                             const float* __restrict__ bln,
                                             const half_t* __restrict__ w1h,
                                             const float* __restrict__ b1,
                                             const half_t* __restrict__ w2h,
                                             const float* __restrict__ b2,
                                             const float* __restrict__ gout,
                                             float* __restrict__ h,
                                             half_t* __restrict__ hh) {
    int wid = blockIdx.x * 2 + (threadIdx.x >> 6);    // 0..1535
    int lane = threadIdx.x & 63;
    int lm = lane & 15, lg = lane >> 4;
    int row = wid * 16 + lm;
    const f32x4 zc = {0.f, 0.f, 0.f, 0.f};

    half4v pf[4];
#pragma unroll
    for (int kc = 0; kc < 4; ++kc)
        pf[kc] = *(const half4v*)(pwh + (size_t)lm * 64 + kc * 16 + lg * 4);

    half4v of[4];
#pragma unroll
    for (int kc = 0; kc < 4; ++kc) {
        F2H u;
        u.f2 = *(const float2*)(obh + (size_t)row * 64 + kc * 16 + lg * 4);
        of[kc] = u.h4;
    }

    f32x4 hp[4];
#pragma unroll
    for (int nt = 0; nt < 4; ++nt) {
        half4v cw[4];
#pragma unroll
        for (int kc = 0; kc < 4; ++kc) cw[kc] = pf[kc];
        if (nt < 3) {
#pragma unroll
            for (int kc = 0; kc < 4; ++kc)
                pf[kc] = *(const half4v*)(pwh + (size_t)((nt + 1) * 16 + lm) * 64 + kc * 16 + lg * 4);
        }
        f32x4 c = zc;
#pragma unroll
        for (int kc = 0; kc < 4; ++kc)
            c = __builtin_amdgcn_mfma_f32_16x16x16f16(cw[kc], of[kc], c, 0, 0, 0);
        float4 ho = *(const float4*)(h + (size_t)row * 64 + nt * 16 + lg * 4);
        float4 bb = *(const float4*)(pb + nt * 16 + lg * 4);
        hp[nt][0] = c[0] + ho.x + bb.x;
        hp[nt][1] = c[1] + ho.y + bb.y;
        hp[nt][2] = c[2] + ho.z + bb.z;
        hp[nt][3] = c[3] + ho.w + bb.w;
    }

    float s = 0.f, s2 = 0.f;
#pragma unroll
    for (int nt = 0; nt < 4; ++nt)
#pragma unroll
        for (int r = 0; r < 4; ++r) {
            s += hp[nt][r];
            s2 += hp[nt][r] * hp[nt][r];
        }
    s += __shfl_xor(s, 16);  s2 += __shfl_xor(s2, 16);
    s += __shfl_xor(s, 32);  s2 += __shfl_xor(s2, 32);
    float mean = s * (1.f / 64.f);
    float var = s2 * (1.f / 64.f) - mean * mean;
    float rstd = rsqrtf(var + 1e-5f);

    half4v xf[4];
#pragma unroll
    for (int nt = 0; nt < 4; ++nt) {
        float4 gg = *(const float4*)(g + nt * 16 + lg * 4);
        float4 bb = *(const float4*)(bln + nt * 16 + lg * 4);
        float y0 = (hp[nt][0] - mean) * rstd * gg.x + bb.x;
        float y1 = (hp[nt][1] - mean) * rstd * gg.y + bb.y;
        float y2 = (hp[nt][2] - mean) * rstd * gg.z + bb.z;
        float y3 = (hp[nt][3] - mean) * rstd * gg.w + bb.w;
        PU u;
        u.h2[0] = __builtin_amdgcn_cvt_pkrtz(y0, y1);
        u.h2[1] = __builtin_amdgcn_cvt_pkrtz(y2, y3);
        xf[nt] = u.h4;
    }

    half4v w1f[4];
#pragma unroll
    for (int kc = 0; kc < 4; ++kc)
        w1f[kc] = *(const half4v*)(w1h + (size_t)lm * 64 + kc * 16 + lg * 4);

    f32x4 acc[4] = {zc, zc, zc, zc};
#pragma unroll 4
    for (int ht = 0; ht < 16; ++ht) {
        half4v cw[4];
#pragma unroll
        for (int kc = 0; kc < 4; ++kc) cw[kc] = w1f[kc];
        half4v w2f[4];
#pragma unroll
        for (int ot = 0; ot < 4; ++ot)
            w2f[ot] = *(const half4v*)(w2h + (size_t)(ot * 16 + lm) * 256 + ht * 16 + lg * 4);
        if (ht < 15) {
#pragma unroll
            for (int kc = 0; kc < 4; ++kc)
                w1f[kc] = *(const half4v*)(w1h + (size_t)((ht + 1) * 16 + lm) * 64 + kc * 16 + lg * 4);
        }
        f32x4 c1 = zc;
#pragma unroll
        for (int kc = 0; kc < 4; ++kc)
            c1 = __builtin_amdgcn_mfma_f32_16x16x16f16(cw[kc], xf[kc], c1, 0, 0, 0);
        float4 bb = *(const float4*)(b1 + ht * 16 + lg * 4);
        float y0 = c1[0] + bb.x;
        float y1 = c1[1] + bb.y;
        float y2 = c1[2] + bb.z;
        float y3 = c1[3] + bb.w;
        y0 = 0.5f * y0 * (1.0f + erff(y0 * 0.70710678118654752f));
        y1 = 0.5f * y1 * (1.0f + erff(y1 * 0.70710678118654752f));
        y2 = 0.5f * y2 * (1.0f + erff(y2 * 0.70710678118654752f));
        y3 = 0.5f * y3 * (1.0f + erff(y3 * 0.70710678118654752f));
        PU p;
        p.h2[0] = __builtin_amdgcn_cvt_pkrtz(y0, y1);
        p.h2[1] = __builtin_amdgcn_cvt_pkrtz(y2, y3);
#pragma unroll
        for (int ot = 0; ot < 4; ++ot)
            acc[ot] = __builtin_amdgcn_mfma_f32_16x16x16f16(w2f[ot], p.h4, acc[ot], 0, 0, 0);
    }

#pragma unroll
    for (int ot = 0; ot < 4; ++ot) {
        float4 bb = *(const float4*)(b2 + ot * 16 + lg * 4);
        float4 gv = *(const float4*)(gout + (size_t)row * 64 + ot * 16 + lg * 4);
        float4 fv = make_float4(hp[ot][0] + acc[ot][0] + bb.x + gv.x,
                                hp[ot][1] + acc[ot][1] + bb.y + gv.y,
                                hp[ot][2] + acc[ot][2] + bb.z + gv.z,
                                hp[ot][3] + acc[ot][3] + bb.w + gv.w);
        size_t idx = (size_t)row * 64 + ot * 16 + lg * 4;
        *(float4*)(h + idx) = fv;
        PU u;
        u.h2[0] = __builtin_amdgcn_cvt_pkrtz(fv.x, fv.y);
        u.h2[1] = __builtin_amdgcn_cvt_pkrtz(fv.z, fv.w);
        *(half4v*)(hh + idx) = u.h4;
    }
}

// ---------------- final: out[b,c,v,t] = h[(b*12+t)*512+v][c]  (LDS-tiled transpose) ----------------
__global__ __launch_bounds__(256) void k_out(const float* __restrict__ h,
                                             float* __restrict__ out) {
    __shared__ float t[64 * 65];
    int tid = threadIdx.x;
    int b = blockIdx.x / 96, vt0 = (blockIdx.x % 96) * 64;
#pragma unroll
    for (int i = 0; i < 4; ++i) {
        int g = tid + i * 256;
        int r = g >> 4, q = g & 15;
        int vt = vt0 + r;
        int v = vt / 12, tt = vt - v * 12;
        *(float4*)&t[r * 65 + 4 * q] =
            *(const float4*)(h + ((size_t)((b * 12 + tt) * 512 + v)) * 64 + 4 * q);
    }
    __syncthreads();
#pragma unroll
    for (int i = 0; i < 4; ++i) {
        int g = tid + i * 256;
        int r = g >> 4, q = g & 15;
        float4 o;
        o.x = t[(4 * q + 0) * 65 + r];
        o.y = t[(4 * q + 1) * 65 + r];
        o.z = t[(4 * q + 2) * 65 + r];
        o.w = t[(4 * q + 3) * 65 + r];
        *(float4*)(out + ((size_t)(b * 64 + r)) * 6144 + vt0 + 4 * q) = o;
    }
}

extern "C" void kernel_launch(void* const* d_in, const int* in_sizes, int n_in,
                              void* d_out, int out_size, void* d_ws, size_t ws_size,
                              hipStream_t stream) {
    const float* x      = (const float*)d_in[0];
    const float* adj    = (const float*)d_in[1];
    const float* pos    = (const float*)d_in[2];
    const float* qkv_w  = (const float*)d_in[3];
    const float* proj_w = (const float*)d_in[4];
    const float* proj_b = (const float*)d_in[5];
    const float* ln_g   = (const float*)d_in[6];
    const float* ln_b   = (const float*)d_in[7];
    const float* ff_w1  = (const float*)d_in[8];
    const float* ff_b1  = (const float*)d_in[9];
    const float* ff_w2  = (const float*)d_in[10];
    const float* ff_b2  = (const float*)d_in[11];
    const float* gcn_w  = (const float*)d_in[12];
    const float* gcn_b  = (const float*)d_in[13];
    float* out = (float*)d_out;

    const size_t SZ = 1572864;  // 48*512*64
    float* h    = (float*)d_ws;
    float* gout = h + SZ;
    half_t* hh  = (half_t*)(gout + SZ);
    half_t* x1h = hh + SZ;
    half_t* x2h = x1h + SZ;
    half_t* qh  = x2h + SZ;
    half_t* kh  = qh + SZ;
    half_t* vh  = kh + SZ;
    half_t* obh = vh + SZ;
    half_t* adjTh  = obh + SZ;        // 262144
    half_t* adjT2h = adjTh + 262144;  // 262144
    half_t* wh     = adjT2h + 262144; // 122880
    half_t* qkv_wh  = wh;
    half_t* proj_wh = wh + 24576;
    half_t* ff_w1h  = wh + 32768;
    half_t* ff_w2h  = wh + 65536;
    half_t* gcn_wh  = wh + 98304;

    k_pre<<<992, 256, 0, stream>>>(x, pos, adj, qkv_w, proj_w, ff_w1, ff_w2, gcn_w,
                                   h, hh, adjTh, wh, adjT2h);
    for (int l = 0; l < 2; ++l) {
        k_qd<<<768, 256, 0, stream>>>(hh, qkv_wh + l * 12288, qh, kh, vh,
                                      adjTh, adjT2h, x1h, x2h);
        k_ag<<<1152, 512, 0, stream>>>(qh, kh, vh, obh, hh, x1h, x2h,
                                       gcn_wh + l * 12288, gcn_b + l * 64, gout);
        k_plf<<<768, 128, 0, stream>>>(obh, proj_wh + l * 4096, proj_b + l * 64,
                                       ln_g + l * 64, ln_b + l * 64,
                                       ff_w1h + l * 16384, ff_b1 + l * 256,
                                       ff_w2h + l * 16384, ff_b2 + l * 64, gout, h, hh);
    }
    k_out<<<384, 256, 0, stream>>>(h, out);
}

// Round 19
// 275.043 us; speedup vs baseline: 1.4854x; 1.0030x over previous
//
#include <hip/hip_runtime.h>
#include <math.h>

// Sizes: b=4, t=12 (BT=48), n=512, c=64, heads=8, hd=8, FF hidden=256, depth=2

typedef __fp16 half_t;
typedef __attribute__((ext_vector_type(2))) __fp16 half2v;
typedef __attribute__((ext_vector_type(4))) __fp16 half4v;
typedef __attribute__((ext_vector_type(4))) float f32x4;

union PU  { half2v h2[2]; half4v h4; };
union F4H { float4 f; half4v h[2]; };
union F2H { float2 f2; half4v h4; };

#define ATS 72
#define BTS 68
#define KLS 20
#define QLS 20
#define VTS 516

// ---------------- merged prologue: init-transpose (h+hh) | adjt | weight-prep | adj^2 ----------------
__global__ __launch_bounds__(256) void k_pre(const float* __restrict__ x,
                                             const float* __restrict__ pos,
                                             const float* __restrict__ adj,
                                             const float* __restrict__ qkv_w,
                                             const float* __restrict__ proj_w,
                                             const float* __restrict__ ff_w1,
                                             const float* __restrict__ ff_w2,
                                             const float* __restrict__ gcn_w,
                                             float* __restrict__ h,
                                             half_t* __restrict__ hh,
                                             half_t* __restrict__ adjTh,
                                             half_t* __restrict__ wh,
                                             half_t* __restrict__ adjT2h) {
    __shared__ __align__(16) char smem[17920];
    float* t = (float*)smem;                          // 64*65 floats = 16640 B
    int tid = threadIdx.x;
    int bidx = blockIdx.x;
    if (bidx < 384) {
        int b = bidx / 96, vt0 = (bidx % 96) * 64;
#pragma unroll
        for (int i = 0; i < 4; ++i) {
            int g = tid + i * 256;
            int r = g >> 4, q = g & 15;
            *(float4*)&t[r * 65 + 4 * q] =
                *(const float4*)(x + ((size_t)(b * 64 + r)) * 6144 + vt0 + 4 * q);
        }
        __syncthreads();
#pragma unroll
        for (int i = 0; i < 4; ++i) {
            int g = tid + i * 256;
            int r = g >> 4, q = g & 15;
            int vt = vt0 + r;
            int v = vt / 12, tt = vt - v * 12;
            float4 pv = *(const float4*)(pos + v * 64 + 4 * q);
            float4 o;
            o.x = t[(4 * q + 0) * 65 + r] + pv.x;
            o.y = t[(4 * q + 1) * 65 + r] + pv.y;
            o.z = t[(4 * q + 2) * 65 + r] + pv.z;
            o.w = t[(4 * q + 3) * 65 + r] + pv.w;
            size_t idx = ((size_t)((b * 12 + tt) * 512 + v)) * 64 + 4 * q;
            *(float4*)(h + idx) = o;
            PU u;
            u.h2[0] = __builtin_amdgcn_cvt_pkrtz(o.x, o.y);
            u.h2[1] = __builtin_amdgcn_cvt_pkrtz(o.z, o.w);
            *(half4v*)(hh + idx) = u.h4;
        }
    } else if (bidx < 448) {
        int fb = bidx - 384;
        int v0 = (fb & 7) * 64, w0 = (fb >> 3) * 64;
#pragma unroll
        for (int i = 0; i < 4; ++i) {
            int g = tid + i * 256;
            int r = g >> 4, q = g & 15;
            float4 a = *(const float4*)(adj + (size_t)(v0 + r) * 512 + w0 + 4 * q);
            t[(4 * q + 0) * 65 + r] = a.x;
            t[(4 * q + 1) * 65 + r] = a.y;
            t[(4 * q + 2) * 65 + r] = a.z;
            t[(4 * q + 3) * 65 + r] = a.w;
        }
        __syncthreads();
#pragma unroll
        for (int i = 0; i < 4; ++i) {
            int g = tid + i * 256;
            int rw = g >> 4, q = g & 15;
            const float* src = &t[rw * 65 + 4 * q];
            PU u;
            u.h2[0] = __builtin_amdgcn_cvt_pkrtz(src[0], src[1]);
            u.h2[1] = __builtin_amdgcn_cvt_pkrtz(src[2], src[3]);
            *(half4v*)(adjTh + (size_t)(w0 + rw) * 512 + v0 + 4 * q) = u.h4;
        }
    } else if (bidx < 928) {
        int i = (bidx - 448) * 256 + tid;
        float v;
        if (i < 24576) v = qkv_w[i];
        else if (i < 32768) v = proj_w[i - 24576];
        else if (i < 65536) v = ff_w1[i - 32768];
        else if (i < 98304) v = ff_w2[i - 65536];
        else v = gcn_w[i - 98304];
        wh[i] = (half_t)v;
    } else {
        half_t* a_t = (half_t*)smem;
        half_t* b_t = (half_t*)smem + 64 * ATS;
        int fb = bidx - 928;
        int w0 = (fb & 7) * 64, v0 = (fb >> 3) * 64;
        int wave = tid >> 6, lane = tid & 63;
        int lm = lane & 15, lg = lane >> 4;
        const f32x4 zc = {0.f, 0.f, 0.f, 0.f};
        f32x4 acc[4] = {zc, zc, zc, zc};
        for (int kc = 0; kc < 8; ++kc) {
#pragma unroll
            for (int i = 0; i < 4; ++i) {
                int g = tid + i * 256;
                int uu = g >> 4, q = g & 15;
                float4 a = *(const float4*)(adj + (size_t)(kc * 64 + uu) * 512 + w0 + 4 * q);
                a_t[(4 * q + 0) * ATS + uu] = (half_t)a.x;
                a_t[(4 * q + 1) * ATS + uu] = (half_t)a.y;
                a_t[(4 * q + 2) * ATS + uu] = (half_t)a.z;
                a_t[(4 * q + 3) * ATS + uu] = (half_t)a.w;
            }
#pragma unroll
            for (int i = 0; i < 4; ++i) {
                int g = tid + i * 256;
                int c = g >> 4, q = g & 15;
                float4 a = *(const float4*)(adj + (size_t)(v0 + c) * 512 + kc * 64 + 4 * q);
                PU u;
                u.h2[0] = __builtin_amdgcn_cvt_pkrtz(a.x, a.y);
                u.h2[1] = __builtin_amdgcn_cvt_pkrtz(a.z, a.w);
                *(half4v*)&b_t[c * BTS + 4 * q] = u.h4;
            }
            __syncthreads();
#pragma unroll
            for (int k16 = 0; k16 < 4; ++k16) {
                half4v af = *(const half4v*)&a_t[(wave * 16 + lm) * ATS + k16 * 16 + lg * 4];
#pragma unroll
                for (int nt = 0; nt < 4; ++nt) {
                    half4v bf = *(const half4v*)&b_t[(nt * 16 + lm) * BTS + k16 * 16 + lg * 4];
                    acc[nt] = __builtin_amdgcn_mfma_f32_16x16x16f16(af, bf, acc[nt], 0, 0, 0);
                }
            }
            __syncthreads();
        }
#pragma unroll
        for (int nt = 0; nt < 4; ++nt)
#pragma unroll
            for (int r = 0; r < 4; ++r)
                adjT2h[(size_t)(w0 + wave * 16 + lg * 4 + r) * 512 + v0 + nt * 16 + lm] =
                    (half_t)acc[nt][r];
    }
}

// ---------------- merged: qkv (blocks 0..383) | diff z-merged (blocks 384..767) ----------------
__global__ __launch_bounds__(256) void k_qd(const half_t* __restrict__ hh,
                                            const half_t* __restrict__ Wh,
                                            half_t* __restrict__ qh,
                                            half_t* __restrict__ kh,
                                            half_t* __restrict__ vh,
                                            const half_t* __restrict__ adjTh,
                                            const half_t* __restrict__ adjT2h,
                                            half_t* __restrict__ x1h,
                                            half_t* __restrict__ x2h) {
    __shared__ __align__(16) half_t sbuf[2 * 64 * ATS + 64 * BTS];   // 27136 B
    int tid = threadIdx.x;
    int bidx = blockIdx.x;
    int wave = tid >> 6, lane = tid & 63;
    int lm = lane & 15, lg = lane >> 4;
    const f32x4 zc = {0.f, 0.f, 0.f, 0.f};

    if (bidx < 384) {
        int wid = bidx * 4 + wave;
        int row = wid * 16 + lm;
        half4v xf[4];
#pragma unroll
        for (int kc = 0; kc < 4; ++kc) {
            F2H u;
            u.f2 = *(const float2*)(hh + (size_t)row * 64 + kc * 16 + lg * 4);
            xf[kc] = u.h4;
        }
        const float SC = 0.35355339059327373f * 1.4426950408889634f;
        int bt = row >> 9, v = row & 511;
        half4v wf[4];
#pragma unroll
        for (int kc = 0; kc < 4; ++kc)
            wf[kc] = *(const half4v*)(Wh + (size_t)lm * 64 + kc * 16 + lg * 4);
#pragma unroll
        for (int nt = 0; nt < 12; ++nt) {
            half4v cw[4];
#pragma unroll
            for (int kc = 0; kc < 4; ++kc) cw[kc] = wf[kc];
            if (nt < 11) {
#pragma unroll
                for (int kc = 0; kc < 4; ++kc)
                    wf[kc] = *(const half4v*)(Wh + (size_t)((nt + 1) * 16 + lm) * 64 + kc * 16 + lg * 4);
            }
            f32x4 acc = zc;
#pragma unroll
            for (int kc = 0; kc < 4; ++kc)
                acc = __builtin_amdgcn_mfma_f32_16x16x16f16(cw[kc], xf[kc], acc, 0, 0, 0);
            int s = nt >> 2;
            if (s == 0) { acc[0] *= SC; acc[1] *= SC; acc[2] *= SC; acc[3] *= SC; }
            int head = ((nt & 3) << 1) + (lg >> 1);
            int d0 = (lg & 1) * 4;
            PU o2;
            o2.h2[0] = __builtin_amdgcn_cvt_pkrtz(acc[0], acc[1]);
            o2.h2[1] = __builtin_amdgcn_cvt_pkrtz(acc[2], acc[3]);
            half_t* dst = (s == 0) ? qh : ((s == 1) ? kh : vh);
            *(half4v*)(dst + ((size_t)(bt * 8 + head) * 512 + v) * 8 + d0) = o2.h4;
        }
    } else {
        half_t* a_t  = sbuf;
        half_t* a2_t = sbuf + 64 * ATS;
        half_t* b_t  = sbuf + 2 * 64 * ATS;
        int fb = bidx - 384;                    // 0..383
        int w0 = (fb & 7) * 64;
        int bt = fb >> 3;
        f32x4 acc0[4] = {zc, zc, zc, zc};
        f32x4 acc1[4] = {zc, zc, zc, zc};
        for (int kc = 0; kc < 8; ++kc) {
#pragma unroll
            for (int i = 0; i < 4; ++i) {       // 1024 items: 512 adjTh + 512 adjT2h
                int g = tid + i * 256;
                if (g < 512) {
                    int r = g >> 3, s = g & 7;
                    *(float4*)&a_t[r * ATS + s * 8] =
                        *(const float4*)(adjTh + (size_t)(w0 + r) * 512 + kc * 64 + s * 8);
                } else {
                    int g2 = g - 512;
                    int r = g2 >> 3, s = g2 & 7;
                    *(float4*)&a2_t[r * ATS + s * 8] =
                        *(const float4*)(adjT2h + (size_t)(w0 + r) * 512 + kc * 64 + s * 8);
                }
            }
#pragma unroll
            for (int i = 0; i < 2; ++i) {       // 512 items: transpose-stage hh tile
                int g = tid + i * 256;
                int vr = g >> 3, s = g & 7;
                F4H u;
                u.f = *(const float4*)(hh + ((size_t)(bt * 512 + kc * 64 + vr)) * 64 + s * 8);
#pragma unroll
                for (int e = 0; e < 8; ++e)
                    b_t[(s * 8 + e) * BTS + vr] = u.h[e >> 2][e & 3];
            }
            __syncthreads();
#pragma unroll
            for (int k16 = 0; k16 < 4; ++k16) {
                half4v af0 = *(const half4v*)&a_t[(wave * 16 + lm) * ATS + k16 * 16 + lg * 4];
                half4v af1 = *(const half4v*)&a2_t[(wave * 16 + lm) * ATS + k16 * 16 + lg * 4];
#pragma unroll
                for (int nt = 0; nt < 4; ++nt) {
                    half4v bf = *(const half4v*)&b_t[(nt * 16 + lm) * BTS + k16 * 16 + lg * 4];
                    acc0[nt] = __builtin_amdgcn_mfma_f32_16x16x16f16(af0, bf, acc0[nt], 0, 0, 0);
                    acc1[nt] = __builtin_amdgcn_mfma_f32_16x16x16f16(af1, bf, acc1[nt], 0, 0, 0);
                }
            }
            __syncthreads();
        }
#pragma unroll
        for (int nt = 0; nt < 4; ++nt)
#pragma unroll
            for (int r = 0; r < 4; ++r) {
                size_t o = (size_t)(w0 + wave * 16 + lg * 4 + r) * 3072 + bt * 64 + nt * 16 + lm;
                x1h[o] = (half_t)acc0[nt][r];
                x2h[o] = (half_t)acc1[nt][r];
            }
    }
}

// ---------------- merged: attn (blocks 0..767) | gcn (blocks 768..1151) ----------------
__global__ __launch_bounds__(512) void k_ag(const half_t* __restrict__ qh,
                                            const half_t* __restrict__ kh,
                                            const half_t* __restrict__ vh,
                                            half_t* __restrict__ obh,
                                            const half_t* __restrict__ hh,
                                            const half_t* __restrict__ x1h,
                                            const half_t* __restrict__ x2h,
                                            const half_t* __restrict__ Wh,
                                            const float* __restrict__ bias,
                                            float* __restrict__ gout) {
    __shared__ __align__(16) half_t sbuf[512 * KLS + 16 * VTS + 256 * QLS];  // 47232 B
    int tid = threadIdx.x;
    int bidx = blockIdx.x;
    const half4v zero4 = {(__fp16)0.f, (__fp16)0.f, (__fp16)0.f, (__fp16)0.f};
    const f32x4 zc = {0.f, 0.f, 0.f, 0.f};

    if (bidx < 768) {
        half_t* kl = sbuf;
        half_t* vt = sbuf + 512 * KLS;
        half_t* ql = sbuf + 512 * KLS + 16 * VTS;
        int bh = bidx >> 1;
        int half_ = bidx & 1;
        const half_t* kbase = kh + (size_t)bh * 4096;
        const half_t* vbase = vh + (size_t)bh * 4096;
        const half_t* qbase = qh + (size_t)bh * 4096 + half_ * 2048;

        if (tid < 256) {
#pragma unroll
            for (int kk = 0; kk < 2; ++kk) {
                int key = tid * 2 + kk;
                F4H u;
                u.f = *(const float4*)(kbase + key * 8);
                half4v* rowp = (half4v*)&kl[key * KLS];
                rowp[0] = u.h[0];
                rowp[1] = u.h[1];
                rowp[2] = zero4;
                rowp[3] = zero4;
            }
            {
                F4H u;
                u.f = *(const float4*)(qbase + tid * 8);
                half4v* rowp = (half4v*)&ql[tid * QLS];
                rowp[0] = u.h[0];
                rowp[1] = u.h[1];
                rowp[2] = zero4;
                rowp[3] = zero4;
            }
            {
                int k0 = tid * 2;
                F4H a, b;
                a.f = *(const float4*)(vbase + k0 * 8);
                b.f = *(const float4*)(vbase + k0 * 8 + 8);
#pragma unroll
                for (int d = 0; d < 8; ++d) {
                    half2v p = {a.h[d >> 2][d & 3], b.h[d >> 2][d & 3]};
                    *(half2v*)&vt[d * VTS + k0] = p;
                }
            }
        }
        for (int i = tid; i < 1032; i += 512)
            ((half4v*)(vt + 8 * VTS))[i] = zero4;
        __syncthreads();

        int wave = tid >> 6, lane = tid & 63;
        int lm = lane & 15, lg = lane >> 4;
        int bt = bh >> 3, head = bh & 7;

#pragma unroll 1
        for (int st = 0; st < 2; ++st) {
            int qrow0 = wave * 32 + st * 16;
            half4v qf = *(const half4v*)&ql[(qrow0 + lm) * QLS + lg * 4];
            f32x4 acc = zc;
            float l0 = 0.f, l1 = 0.f, l2 = 0.f, l3 = 0.f;
#pragma unroll 4
            for (int kt = 0; kt < 32; ++kt) {
                int key0 = kt * 16;
                half4v ka = *(const half4v*)&kl[(key0 + lm) * KLS + lg * 4];
                f32x4 c1 = __builtin_amdgcn_mfma_f32_16x16x16f16(ka, qf, zc, 0, 0, 0);
                float p0 = exp2f(fminf(c1[0], 12.f));
                float p1 = exp2f(fminf(c1[1], 12.f));
                float p2 = exp2f(fminf(c1[2], 12.f));
                float p3 = exp2f(fminf(c1[3], 12.f));
                l0 += p0; l1 += p1; l2 += p2; l3 += p3;
                PU pu;
                pu.h2[0] = __builtin_amdgcn_cvt_pkrtz(p0, p1);
                pu.h2[1] = __builtin_amdgcn_cvt_pkrtz(p2, p3);
                half4v va = *(const half4v*)&vt[lm * VTS + key0 + lg * 4];
                acc = __builtin_amdgcn_mfma_f32_16x16x16f16(va, pu.h4, acc, 0, 0, 0);
            }
            float lsum = (l0 + l1) + (l2 + l3);
            lsum += __shfl_xor(lsum, 16);
            lsum += __shfl_xor(lsum, 32);
            if (lg < 2) {
                float inv = 1.f / lsum;
                int rowg = half_ * 256 + qrow0 + lm;
                PU o2;
                o2.h2[0] = __builtin_amdgcn_cvt_pkrtz(acc[0] * inv, acc[1] * inv);
                o2.h2[1] = __builtin_amdgcn_cvt_pkrtz(acc[2] * inv, acc[3] * inv);
                *(half4v*)(obh + ((size_t)(bt * 512 + rowg)) * 64 + head * 8 + lg * 4) = o2.h4;
            }
        }
    } else {
        half_t* a_t = sbuf;
        half_t* b_t = sbuf + 64 * ATS;
        int row0 = (bidx - 768) * 64;
        int wave = tid >> 6, lane = tid & 63;
        int lm = lane & 15, lg = lane >> 4;
        f32x4 acc[4] = {zc, zc, zc, zc};

        for (int ch = 0; ch < 3; ++ch) {
            if (tid < 256) {
                if (ch == 0) {
#pragma unroll
                    for (int i = 0; i < 2; ++i) {
                        int g = tid + i * 256;
                        int r = g >> 3, s = g & 7;
                        int rowg = row0 + r;
                        int v = rowg / 48, bt = rowg - v * 48;
                        *(float4*)&a_t[r * ATS + s * 8] =
                            *(const float4*)(hh + ((size_t)(bt * 512 + v)) * 64 + s * 8);
                    }
                } else {
                    const half_t* X = (ch == 1) ? x1h : x2h;
#pragma unroll
                    for (int i = 0; i < 2; ++i) {
                        int g = tid + i * 256;
                        int r = g >> 3, s = g & 7;
                        *(float4*)&a_t[r * ATS + s * 8] =
                            *(const float4*)(X + (size_t)(row0 + r) * 64 + s * 8);
                    }
                }
#pragma unroll
                for (int i = 0; i < 4; ++i) {
                    int g = tid + i * 256;
                    int r = g >> 4, q = g & 15;
                    *(half4v*)&b_t[r * BTS + 4 * q] =
                        *(const half4v*)(Wh + (size_t)r * 192 + ch * 64 + 4 * q);
                }
            }
            __syncthreads();
            if (tid < 256) {
#pragma unroll
                for (int k16 = 0; k16 < 4; ++k16) {
                    half4v af = *(const half4v*)&a_t[(wave * 16 + lm) * ATS + k16 * 16 + lg * 4];
#pragma unroll
                    for (int nt = 0; nt < 4; ++nt) {
                        half4v bf = *(const half4v*)&b_t[(nt * 16 + lm) * BTS + k16 * 16 + lg * 4];
                        acc[nt] = __builtin_amdgcn_mfma_f32_16x16x16f16(bf, af, acc[nt], 0, 0, 0);
                    }
                }
            }
            __syncthreads();
        }
        if (tid < 256) {
            int row = row0 + wave * 16 + lm;
            int v = row / 48, bt = row - v * 48;
            float* gp = gout + ((size_t)(bt * 512 + v)) * 64;
#pragma unroll
            for (int nt = 0; nt < 4; ++nt) {
                float4 bb = *(const float4*)(bias + nt * 16 + lg * 4);
                *(float4*)(gp + nt * 16 + lg * 4) =
                    make_float4(acc[nt][0] + bb.x, acc[nt][1] + bb.y,
                                acc[nt][2] + bb.z, acc[nt][3] + bb.w);
            }
        }
    }
}

// ---------------- fused proj + LN + FF + gout add; writes h/hh (l=0) or out (l=1) ----------------
__global__ __launch_bounds__(128) void k_plf(const half_t* __restrict__ obh,
                                             const half_t* __restrict__ pwh,
                                             const float* __restrict__ pb,
                                             const float* __restrict__ g,
                                             const float* __restrict__ bln,
                                             const half_t* __restrict__ w1h,
                                             const float* __restrict__ b1,
                                             const half_t* __restrict__ w2h,
                                             const float* __restrict__ b2,
                                             const float* __restrict__ gout,
                                             float* __restrict__ h,
                                             half_t* __restrict__ hh,
                                             float* __restrict__ out,
                                             int last) {
    int wid = blockIdx.x * 2 + (threadIdx.x >> 6);    // 0..1535
    int lane = threadIdx.x & 63;
    int lm = lane & 15, lg = lane >> 4;
    int row = wid * 16 + lm;
    const f32x4 zc = {0.f, 0.f, 0.f, 0.f};

    half4v pf[4];
#pragma unroll
    for (int kc = 0; kc < 4; ++kc)
        pf[kc] = *(const half4v*)(pwh + (size_t)lm * 64 + kc * 16 + lg * 4);

    half4v of[4];
#pragma unroll
    for (int kc = 0; kc < 4; ++kc) {
        F2H u;
        u.f2 = *(const float2*)(obh + (size_t)row * 64 + kc * 16 + lg * 4);
        of[kc] = u.h4;
    }

    f32x4 hp[4];
#pragma unroll
    for (int nt = 0; nt < 4; ++nt) {
        half4v cw[4];
#pragma unroll
        for (int kc = 0; kc < 4; ++kc) cw[kc] = pf[kc];
        if (nt < 3) {
#pragma unroll
            for (int kc = 0; kc < 4; ++kc)
                pf[kc] = *(const half4v*)(pwh + (size_t)((nt + 1) * 16 + lm) * 64 + kc * 16 + lg * 4);
        }
        f32x4 c = zc;
#pragma unroll
        for (int kc = 0; kc < 4; ++kc)
            c = __builtin_amdgcn_mfma_f32_16x16x16f16(cw[kc], of[kc], c, 0, 0, 0);
        float4 ho = *(const float4*)(h + (size_t)row * 64 + nt * 16 + lg * 4);
        float4 bb = *(const float4*)(pb + nt * 16 + lg * 4);
        hp[nt][0] = c[0] + ho.x + bb.x;
        hp[nt][1] = c[1] + ho.y + bb.y;
        hp[nt][2] = c[2] + ho.z + bb.z;
        hp[nt][3] = c[3] + ho.w + bb.w;
    }

    float s = 0.f, s2 = 0.f;
#pragma unroll
    for (int nt = 0; nt < 4; ++nt)
#pragma unroll
        for (int r = 0; r < 4; ++r) {
            s += hp[nt][r];
            s2 += hp[nt][r] * hp[nt][r];
        }
    s += __shfl_xor(s, 16);  s2 += __shfl_xor(s2, 16);
    s += __shfl_xor(s, 32);  s2 += __shfl_xor(s2, 32);
    float mean = s * (1.f / 64.f);
    float var = s2 * (1.f / 64.f) - mean * mean;
    float rstd = rsqrtf(var + 1e-5f);

    half4v xf[4];
#pragma unroll
    for (int nt = 0; nt < 4; ++nt) {
        float4 gg = *(const float4*)(g + nt * 16 + lg * 4);
        float4 bb = *(const float4*)(bln + nt * 16 + lg * 4);
        float y0 = (hp[nt][0] - mean) * rstd * gg.x + bb.x;
        float y1 = (hp[nt][1] - mean) * rstd * gg.y + bb.y;
        float y2 = (hp[nt][2] - mean) * rstd * gg.z + bb.z;
        float y3 = (hp[nt][3] - mean) * rstd * gg.w + bb.w;
        PU u;
        u.h2[0] = __builtin_amdgcn_cvt_pkrtz(y0, y1);
        u.h2[1] = __builtin_amdgcn_cvt_pkrtz(y2, y3);
        xf[nt] = u.h4;
    }

    half4v w1f[4];
#pragma unroll
    for (int kc = 0; kc < 4; ++kc)
        w1f[kc] = *(const half4v*)(w1h + (size_t)lm * 64 + kc * 16 + lg * 4);

    f32x4 acc[4] = {zc, zc, zc, zc};
#pragma unroll 4
    for (int ht = 0; ht < 16; ++ht) {
        half4v cw[4];
#pragma unroll
        for (int kc = 0; kc < 4; ++kc) cw[kc] = w1f[kc];
        half4v w2f[4];
#pragma unroll
        for (int ot = 0; ot < 4; ++ot)
            w2f[ot] = *(const half4v*)(w2h + (size_t)(ot * 16 + lm) * 256 + ht * 16 + lg * 4);
        if (ht < 15) {
#pragma unroll
            for (int kc = 0; kc < 4; ++kc)
                w1f[kc] = *(const half4v*)(w1h + (size_t)((ht + 1) * 16 + lm) * 64 + kc * 16 + lg * 4);
        }
        f32x4 c1 = zc;
#pragma unroll
        for (int kc = 0; kc < 4; ++kc)
            c1 = __builtin_amdgcn_mfma_f32_16x16x16f16(cw[kc], xf[kc], c1, 0, 0, 0);
        float4 bb = *(const float4*)(b1 + ht * 16 + lg * 4);
        float y0 = c1[0] + bb.x;
        float y1 = c1[1] + bb.y;
        float y2 = c1[2] + bb.z;
        float y3 = c1[3] + bb.w;
        y0 = 0.5f * y0 * (1.0f + erff(y0 * 0.70710678118654752f));
        y1 = 0.5f * y1 * (1.0f + erff(y1 * 0.70710678118654752f));
        y2 = 0.5f * y2 * (1.0f + erff(y2 * 0.70710678118654752f));
        y3 = 0.5f * y3 * (1.0f + erff(y3 * 0.70710678118654752f));
        PU p;
        p.h2[0] = __builtin_amdgcn_cvt_pkrtz(y0, y1);
        p.h2[1] = __builtin_amdgcn_cvt_pkrtz(y2, y3);
#pragma unroll
        for (int ot = 0; ot < 4; ++ot)
            acc[ot] = __builtin_amdgcn_mfma_f32_16x16x16f16(w2f[ot], p.h4, acc[ot], 0, 0, 0);
    }

    if (!last) {
#pragma unroll
        for (int ot = 0; ot < 4; ++ot) {
            float4 bb = *(const float4*)(b2 + ot * 16 + lg * 4);
            float4 gv = *(const float4*)(gout + (size_t)row * 64 + ot * 16 + lg * 4);
            float4 fv = make_float4(hp[ot][0] + acc[ot][0] + bb.x + gv.x,
                                    hp[ot][1] + acc[ot][1] + bb.y + gv.y,
                                    hp[ot][2] + acc[ot][2] + bb.z + gv.z,
                                    hp[ot][3] + acc[ot][3] + bb.w + gv.w);
            size_t idx = (size_t)row * 64 + ot * 16 + lg * 4;
            *(float4*)(h + idx) = fv;
            PU u;
            u.h2[0] = __builtin_amdgcn_cvt_pkrtz(fv.x, fv.y);
            u.h2[1] = __builtin_amdgcn_cvt_pkrtz(fv.z, fv.w);
            *(half4v*)(hh + idx) = u.h4;
        }
    } else {
        // direct transposed output: out[((b*64+c)*512+v)*12+t], row = (b*12+t)*512+v
        int bt = row >> 9, v = row & 511;
        int b = bt / 12, t = bt - b * 12;
        float* op = out + (size_t)b * 393216 + v * 12 + t;   // + c*6144
#pragma unroll
        for (int ot = 0; ot < 4; ++ot) {
            float4 bb = *(const float4*)(b2 + ot * 16 + lg * 4);
            float4 gv = *(const float4*)(gout + (size_t)row * 64 + ot * 16 + lg * 4);
            int c0 = ot * 16 + lg * 4;
            op[(size_t)(c0 + 0) * 6144] = hp[ot][0] + acc[ot][0] + bb.x + gv.x;
            op[(size_t)(c0 + 1) * 6144] = hp[ot][1] + acc[ot][1] + bb.y + gv.y;
            op[(size_t)(c0 + 2) * 6144] = hp[ot][2] + acc[ot][2] + bb.z + gv.z;
            op[(size_t)(c0 + 3) * 6144] = hp[ot][3] + acc[ot][3] + bb.w + gv.w;
        }
    }
}

extern "C" void kernel_launch(void* const* d_in, const int* in_sizes, int n_in,
                              void* d_out, int out_size, void* d_ws, size_t ws_size,
                              hipStream_t stream) {
    const float* x      = (const float*)d_in[0];
    const float* adj    = (const float*)d_in[1];
    const float* pos    = (const float*)d_in[2];
    const float* qkv_w  = (const float*)d_in[3];
    const float* proj_w = (const float*)d_in[4];
    const float* proj_b = (const float*)d_in[5];
    const float* ln_g   = (const float*)d_in[6];
    const float* ln_b   = (const float*)d_in[7];
    const float* ff_w1  = (const float*)d_in[8];
    const float* ff_b1  = (const float*)d_in[9];
    const float* ff_w2  = (const float*)d_in[10];
    const float* ff_b2  = (const float*)d_in[11];
    const float* gcn_w  = (const float*)d_in[12];
    const float* gcn_b  = (const float*)d_in[13];
    float* out = (float*)d_out;

    const size_t SZ = 1572864;  // 48*512*64
    float* h    = (float*)d_ws;
    float* gout = h + SZ;
    half_t* hh  = (half_t*)(gout + SZ);
    half_t* x1h = hh + SZ;
    half_t* x2h = x1h + SZ;
    half_t* qh  = x2h + SZ;
    half_t* kh  = qh + SZ;
    half_t* vh  = kh + SZ;
    half_t* obh = vh + SZ;
    half_t* adjTh  = obh + SZ;        // 262144
    half_t* adjT2h = adjTh + 262144;  // 262144
    half_t* wh     = adjT2h + 262144; // 122880
    half_t* qkv_wh  = wh;
    half_t* proj_wh = wh + 24576;
    half_t* ff_w1h  = wh + 32768;
    half_t* ff_w2h  = wh + 65536;
    half_t* gcn_wh  = wh + 98304;

    k_pre<<<992, 256, 0, stream>>>(x, pos, adj, qkv_w, proj_w, ff_w1, ff_w2, gcn_w,
                                   h, hh, adjTh, wh, adjT2h);
    for (int l = 0; l < 2; ++l) {
        k_qd<<<768, 256, 0, stream>>>(hh, qkv_wh + l * 12288, qh, kh, vh,
                                      adjTh, adjT2h, x1h, x2h);
        k_ag<<<1152, 512, 0, stream>>>(qh, kh, vh, obh, hh, x1h, x2h,
                                       gcn_wh + l * 12288, gcn_b + l * 64, gout);
        k_plf<<<768, 128, 0, stream>>>(obh, proj_wh + l * 4096, proj_b + l * 64,
                                       ln_g + l * 64, ln_b + l * 64,
                                       ff_w1h + l * 16384, ff_b1 + l * 256,
                                       ff_w2h + l * 16384, ff_b2 + l * 64, gout, h, hh,
                                       out, l);
    }
}